// Round 14
// baseline (366.399 us; speedup 1.0000x reference)
//
#include <hip/hip_runtime.h>
#include <cstdint>

typedef unsigned long long u64;

#define TPB 256
#define MARGIN 5e-4
#define FCAP (1 << 20)

typedef __bf16 bf16x8 __attribute__((ext_vector_type(8)));
typedef __bf16 bf16x4 __attribute__((ext_vector_type(4)));
typedef float f32x4 __attribute__((ext_vector_type(4)));

// ---------------------------------------------------------------------------
__global__ void pow_kernel(double* __restrict__ pw) {
    int h = threadIdx.x;
    if (h < 8) {
        double gamma = 1.0 - ldexp(1.0, -5 - h);
        double p = 1.0;
        for (int i = 0; i < 512; ++i) { pw[h * 512 + i] = p; p *= gamma; }
    }
}

__global__ void zero_counters(int* __restrict__ ctr) {
    if (threadIdx.x < 8) ctr[threadIdx.x] = 0;
}

// ---------------------------------------------------------------------------
// fp32 -> bf16 hi/lo split (precompute pass).
__global__ void split_f32(const float* __restrict__ in, __bf16* __restrict__ hi,
                          __bf16* __restrict__ lo, int n) {
    int i = (blockIdx.x * 256 + threadIdx.x) * 4;
    if (i >= n) return;
    float4 v = *(const float4*)(in + i);
    bf16x4 h, l;
    #pragma unroll
    for (int e = 0; e < 4; ++e) {
        float f = (&v.x)[e];
        __bf16 hh = (__bf16)f;
        h[e] = hh;
        l[e] = (__bf16)(f - (float)hh);
    }
    *(bf16x4*)(hi + i) = h;
    *(bf16x4*)(lo + i) = l;
}

// fp32 {0,1} -> bf16 (exact), hi only.
__global__ void split_bin(const float* __restrict__ in, __bf16* __restrict__ hi, int n) {
    int i = (blockIdx.x * 256 + threadIdx.x) * 4;
    if (i >= n) return;
    float4 v = *(const float4*)(in + i);
    bf16x4 h;
    #pragma unroll
    for (int e = 0; e < 4; ++e) h[e] = (__bf16)(&v.x)[e];
    *(bf16x4*)(hi + i) = h;
}

// ---------------------------------------------------------------------------
// MFMA GEMM + BN on pre-split bf16 inputs.  128x128 tile, 4 waves (2x2).
// asplit=1: acc = AhBh + AhBl + AlBh (3 passes).  asplit=0: A exact (binary),
// acc = AhBh + AhBl (2 passes).
__global__ __launch_bounds__(256) void gemm_bn_mfma2(
    const __bf16* __restrict__ Ahg, const __bf16* __restrict__ Alg,
    const __bf16* __restrict__ Whg, const __bf16* __restrict__ Wlg,
    const float* __restrict__ bias,
    const float* __restrict__ bnw, const float* __restrict__ bnb,
    const float* __restrict__ bnm, const float* __restrict__ bnv,
    float* __restrict__ out, int asplit)
{
    __shared__ __bf16 AhS[128][40];   // 80B rows: 16B aligned, 2-way banks
    __shared__ __bf16 AlS[128][40];
    __shared__ __bf16 WhS[128][40];
    __shared__ __bf16 WlS[128][40];

    const int tid = threadIdx.x;
    const int m0 = blockIdx.x * 128;
    const int d0 = blockIdx.y * 128;
    const int wv = tid >> 6;
    const int wm = wv >> 1;
    const int wd = wv & 1;
    const int lane = tid & 63;
    const int fr = lane & 15;
    const int fg = lane >> 4;
    const int srow = tid >> 1;
    const int sseg = (tid & 1) * 16;

    f32x4 acc[4][4];
    #pragma unroll
    for (int i = 0; i < 4; ++i)
        #pragma unroll
        for (int j = 0; j < 4; ++j)
            acc[i][j] = (f32x4){0.f, 0.f, 0.f, 0.f};

    for (int k0 = 0; k0 < 512; k0 += 32) {
        __syncthreads();
        {
            const __bf16* pa = Ahg + (size_t)(m0 + srow) * 512 + k0 + sseg;
            *(bf16x8*)&AhS[srow][sseg]     = *(const bf16x8*)pa;
            *(bf16x8*)&AhS[srow][sseg + 8] = *(const bf16x8*)(pa + 8);
            if (asplit) {
                const __bf16* pl = Alg + (size_t)(m0 + srow) * 512 + k0 + sseg;
                *(bf16x8*)&AlS[srow][sseg]     = *(const bf16x8*)pl;
                *(bf16x8*)&AlS[srow][sseg + 8] = *(const bf16x8*)(pl + 8);
            }
            const __bf16* pwh = Whg + (size_t)(d0 + srow) * 512 + k0 + sseg;
            const __bf16* pwl = Wlg + (size_t)(d0 + srow) * 512 + k0 + sseg;
            *(bf16x8*)&WhS[srow][sseg]     = *(const bf16x8*)pwh;
            *(bf16x8*)&WhS[srow][sseg + 8] = *(const bf16x8*)(pwh + 8);
            *(bf16x8*)&WlS[srow][sseg]     = *(const bf16x8*)pwl;
            *(bf16x8*)&WlS[srow][sseg + 8] = *(const bf16x8*)(pwl + 8);
        }
        __syncthreads();

        bf16x8 ah[4], bh[4], bl[4];
        #pragma unroll
        for (int i = 0; i < 4; ++i)
            ah[i] = *(const bf16x8*)&AhS[wm * 64 + i * 16 + fr][fg * 8];
        #pragma unroll
        for (int j = 0; j < 4; ++j) {
            bh[j] = *(const bf16x8*)&WhS[wd * 64 + j * 16 + fr][fg * 8];
            bl[j] = *(const bf16x8*)&WlS[wd * 64 + j * 16 + fr][fg * 8];
        }
        #pragma unroll
        for (int i = 0; i < 4; ++i)
            #pragma unroll
            for (int j = 0; j < 4; ++j) {
                acc[i][j] = __builtin_amdgcn_mfma_f32_16x16x32_bf16(ah[i], bh[j], acc[i][j], 0, 0, 0);
                acc[i][j] = __builtin_amdgcn_mfma_f32_16x16x32_bf16(ah[i], bl[j], acc[i][j], 0, 0, 0);
            }
        if (asplit) {
            bf16x8 al[4];
            #pragma unroll
            for (int i = 0; i < 4; ++i)
                al[i] = *(const bf16x8*)&AlS[wm * 64 + i * 16 + fr][fg * 8];
            #pragma unroll
            for (int i = 0; i < 4; ++i)
                #pragma unroll
                for (int j = 0; j < 4; ++j)
                    acc[i][j] = __builtin_amdgcn_mfma_f32_16x16x32_bf16(al[i], bh[j], acc[i][j], 0, 0, 0);
        }
    }

    #pragma unroll
    for (int j = 0; j < 4; ++j) {
        int d = d0 + wd * 64 + j * 16 + fr;
        double inv = (double)bnw[d] / sqrt((double)bnv[d] + 1e-5);
        double sh  = (double)bnb[d] - (double)bnm[d] * inv;
        double bs  = (double)bias[d];
        #pragma unroll
        for (int i = 0; i < 4; ++i) {
            #pragma unroll
            for (int reg = 0; reg < 4; ++reg) {
                int m = m0 + wm * 64 + i * 16 + fg * 4 + reg;
                out[(size_t)m * 512 + d] = (float)(((double)acc[i][j][reg] + bs) * inv + sh);
            }
        }
    }
}

// ---------------------------------------------------------------------------
// Fallback (R12-proven): fp32-input split-bf16 MFMA GEMM. 128m x 64d block.
__global__ __launch_bounds__(256) void gemm_bn_mfma(
    const float* __restrict__ A, const float* __restrict__ W,
    const float* __restrict__ bias,
    const float* __restrict__ bnw, const float* __restrict__ bnb,
    const float* __restrict__ bnm, const float* __restrict__ bnv,
    float* __restrict__ out)
{
    __shared__ __bf16 Ah[128][36];
    __shared__ __bf16 Al[128][36];
    __shared__ __bf16 Wh[64][36];
    __shared__ __bf16 Wl[64][36];

    const int tid = threadIdx.x;
    const int m0 = blockIdx.x * 128;
    const int d0 = blockIdx.y * 64;
    const int wv = tid >> 6;
    const int wm = wv >> 1;
    const int wd = wv & 1;
    const int lane = tid & 63;
    const int fr = lane & 15;
    const int fg = lane >> 4;
    const int srow = tid >> 3;
    const int scol = (tid & 7) * 4;

    f32x4 acc[4][2];
    #pragma unroll
    for (int i = 0; i < 4; ++i)
        #pragma unroll
        for (int j = 0; j < 2; ++j)
            acc[i][j] = (f32x4){0.f, 0.f, 0.f, 0.f};

    for (int k0 = 0; k0 < 512; k0 += 32) {
        __syncthreads();
        #pragma unroll
        for (int rep = 0; rep < 4; ++rep) {
            int row = srow + 32 * rep;
            float4 va = *(const float4*)(A + (size_t)(m0 + row) * 512 + k0 + scol);
            #pragma unroll
            for (int e = 0; e < 4; ++e) {
                float f = (&va.x)[e];
                __bf16 h = (__bf16)f;
                Ah[row][scol + e] = h;
                Al[row][scol + e] = (__bf16)(f - (float)h);
            }
        }
        #pragma unroll
        for (int rep = 0; rep < 2; ++rep) {
            int row = srow + 32 * rep;
            float4 vw = *(const float4*)(W + (size_t)(d0 + row) * 512 + k0 + scol);
            #pragma unroll
            for (int e = 0; e < 4; ++e) {
                float f = (&vw.x)[e];
                __bf16 h = (__bf16)f;
                Wh[row][scol + e] = h;
                Wl[row][scol + e] = (__bf16)(f - (float)h);
            }
        }
        __syncthreads();

        union FU { bf16x8 v8; struct { __bf16 a[4], b[4]; } s; };
        bf16x8 ah[4], al[4], bh[2], bl[2];
        #pragma unroll
        for (int i = 0; i < 4; ++i) {
            int row = wm * 64 + i * 16 + fr;
            FU u1, u2;
            *(double*)&u1.s.a[0] = *(const double*)&Ah[row][fg * 8];
            *(double*)&u1.s.b[0] = *(const double*)&Ah[row][fg * 8 + 4];
            *(double*)&u2.s.a[0] = *(const double*)&Al[row][fg * 8];
            *(double*)&u2.s.b[0] = *(const double*)&Al[row][fg * 8 + 4];
            ah[i] = u1.v8; al[i] = u2.v8;
        }
        #pragma unroll
        for (int j = 0; j < 2; ++j) {
            int row = wd * 32 + j * 16 + fr;
            FU u1, u2;
            *(double*)&u1.s.a[0] = *(const double*)&Wh[row][fg * 8];
            *(double*)&u1.s.b[0] = *(const double*)&Wh[row][fg * 8 + 4];
            *(double*)&u2.s.a[0] = *(const double*)&Wl[row][fg * 8];
            *(double*)&u2.s.b[0] = *(const double*)&Wl[row][fg * 8 + 4];
            bh[j] = u1.v8; bl[j] = u2.v8;
        }
        #pragma unroll
        for (int i = 0; i < 4; ++i)
            #pragma unroll
            for (int j = 0; j < 2; ++j) {
                acc[i][j] = __builtin_amdgcn_mfma_f32_16x16x32_bf16(ah[i], bh[j], acc[i][j], 0, 0, 0);
                acc[i][j] = __builtin_amdgcn_mfma_f32_16x16x32_bf16(ah[i], bl[j], acc[i][j], 0, 0, 0);
                acc[i][j] = __builtin_amdgcn_mfma_f32_16x16x32_bf16(al[i], bh[j], acc[i][j], 0, 0, 0);
            }
    }

    #pragma unroll
    for (int j = 0; j < 2; ++j) {
        int d = d0 + wd * 32 + j * 16 + fr;
        double inv = (double)bnw[d] / sqrt((double)bnv[d] + 1e-5);
        double sh  = (double)bnb[d] - (double)bnm[d] * inv;
        double bs  = (double)bias[d];
        #pragma unroll
        for (int i = 0; i < 4; ++i) {
            #pragma unroll
            for (int reg = 0; reg < 4; ++reg) {
                int m = m0 + wm * 64 + i * 16 + fg * 4 + reg;
                out[(size_t)m * 512 + d] = (float)(((double)acc[i][j][reg] + bs) * inv + sh);
            }
        }
    }
}

// ---------------------------------------------------------------------------
__global__ void lif_mask_flag(const float* __restrict__ Y, u64* __restrict__ msk,
                              int* __restrict__ ctr, int* __restrict__ list, int slot) {
    int g = blockIdx.x * TPB + threadIdx.x;
    int c = g & 511, n = (g >> 9) & 511, b = g >> 18;
    int h = c >> 6;
    int lane = threadIdx.x & 63;
    double v = 0.0;
    bool flag = false;
    for (int t = 0; t < 4; ++t) {
        float y = Y[((size_t)((t * 8 + b) * 512 + n) << 9) + c];
        double hh = v + ((double)y - v) * 0.5;
        flag |= fabs(hh - 1.0) < MARGIN;
        bool s = hh >= 1.0;
        u64 mk = __ballot(s);
        if (lane == 0) msk[((t * 8 + b) * 8 + h) * 512 + n] = mk;
        v = s ? 0.0 : hh;
    }
    if (flag) {
        int idx = atomicAdd(ctr + slot, 1);
        if (idx < FCAP) list[idx] = g;
    }
}

__global__ void fix_mask(const float* __restrict__ x, const float* __restrict__ w,
                         const float* __restrict__ bias,
                         const float* __restrict__ bnw, const float* __restrict__ bnb,
                         const float* __restrict__ bnm, const float* __restrict__ bnv,
                         u64* __restrict__ msk, const int* __restrict__ ctr,
                         const int* __restrict__ list, int slot) {
    int cnt = ctr[slot]; if (cnt > FCAP) cnt = FCAP;
    int wv = (blockIdx.x * blockDim.x + threadIdx.x) >> 6;
    int nw = (gridDim.x * blockDim.x) >> 6;
    int lane = threadIdx.x & 63;
    for (int i = wv; i < cnt; i += nw) {
        int g = list[i];
        int c = g & 511, n = (g >> 9) & 511, b = g >> 18;
        int h = c >> 6;
        const float* wr = w + (size_t)c * 512;
        double dot[4];
        #pragma unroll
        for (int t = 0; t < 4; ++t) {
            const float* xr = x + ((size_t)((t * 8 + b) * 512 + n) << 9);
            double p = 0.0;
            #pragma unroll
            for (int j = 0; j < 8; ++j)
                p += (double)xr[lane + 64 * j] * (double)wr[lane + 64 * j];
            dot[t] = p;
        }
        #pragma unroll
        for (int off = 32; off; off >>= 1) {
            #pragma unroll
            for (int t = 0; t < 4; ++t)
                dot[t] += __shfl_xor(dot[t], off, 64);
        }
        if (lane == 0) {
            double inv = (double)bnw[c] / sqrt((double)bnv[c] + 1e-5);
            double sh  = (double)bnb[c] - (double)bnm[c] * inv;
            double bs  = (double)bias[c];
            double v = 0.0;
            u64 bit = 1ull << (c & 63);
            for (int t = 0; t < 4; ++t) {
                double y = (dot[t] + bs) * inv + sh;
                double hh = v + (y - v) * 0.5;
                bool s = hh >= 1.0;
                u64* wp_ = &msk[((t * 8 + b) * 8 + h) * 512 + n];
                if (s) atomicOr(wp_, bit); else atomicAnd(wp_, ~bit);
                v = s ? 0.0 : hh;
            }
        }
    }
}

// ---------------------------------------------------------------------------
// Fused retention (R12-proven).
__global__ __launch_bounds__(256) void ret_fused(
    const u64* __restrict__ qm, const u64* __restrict__ km,
    const u64* __restrict__ vm, const double* __restrict__ pw,
    float* __restrict__ O)
{
    int bid = blockIdx.x;
    int tbh = bid >> 3;
    int n0 = (bid & 7) * 64;
    int h = tbh & 7;
    int tb = tbh >> 3;
    int tid = threadIdx.x;
    int wv = tid >> 6, lane = tid & 63, fr = lane & 15, fg = lane >> 4;
    int wn = wv * 16;

    __shared__ __bf16 Qs[64][72];
    __shared__ __bf16 Ks[64][72];
    __shared__ __bf16 VsT[64][72];
    __shared__ __bf16 Sh[4][16][72];
    __shared__ __bf16 Sl[4][16][72];
    __shared__ u64 vmc[64];
    __shared__ float pwf[512];

    int base = tbh * 512;

    for (int i = tid; i < 512; i += 256) pwf[i] = (float)pw[h * 512 + i] * 0.125f;

    {
        int row = tid >> 2, q4 = (tid & 3) * 16;
        u64 qw = qm[base + n0 + row];
        #pragma unroll
        for (int s = 0; s < 4; ++s) {
            int e0 = q4 + s * 4;
            u64 pq = 0;
            #pragma unroll
            for (int e = 0; e < 4; ++e)
                if ((qw >> (e0 + e)) & 1ull) pq |= 0x3F80ull << (16 * e);
            *(u64*)&Qs[row][e0] = pq;
        }
    }

    f32x4 acc_o[4];
    #pragma unroll
    for (int j = 0; j < 4; ++j) acc_o[j] = (f32x4){0.f, 0.f, 0.f, 0.f};

    for (int mc = 0; mc < 8; ++mc) {
        __syncthreads();
        {
            int row = tid >> 2, q4 = (tid & 3) * 16;
            u64 kw = km[base + mc * 64 + row];
            #pragma unroll
            for (int s = 0; s < 4; ++s) {
                int e0 = q4 + s * 4;
                u64 pk = 0;
                #pragma unroll
                for (int e = 0; e < 4; ++e)
                    if ((kw >> (e0 + e)) & 1ull) pk |= 0x3F80ull << (16 * e);
                *(u64*)&Ks[row][e0] = pk;
            }
        }
        if (tid < 64) vmc[tid] = vm[base + mc * 64 + tid];
        __syncthreads();
        {
            int d = tid >> 2, mg = (tid & 3) * 16;
            #pragma unroll
            for (int s4 = 0; s4 < 4; ++s4) {
                u64 pk = 0;
                #pragma unroll
                for (int e = 0; e < 4; ++e)
                    if ((vmc[mg + s4 * 4 + e] >> d) & 1ull) pk |= 0x3F80ull << (16 * e);
                *(u64*)&VsT[d][mg + s4 * 4] = pk;
            }
        }
        f32x4 acc_s[4];
        #pragma unroll
        for (int j = 0; j < 4; ++j) acc_s[j] = (f32x4){0.f, 0.f, 0.f, 0.f};
        #pragma unroll
        for (int ks = 0; ks < 2; ++ks) {
            bf16x8 qa = *(const bf16x8*)&Qs[wn + fr][ks * 32 + fg * 8];
            bf16x8 kb[4];
            #pragma unroll
            for (int j = 0; j < 4; ++j)
                kb[j] = *(const bf16x8*)&Ks[j * 16 + fr][ks * 32 + fg * 8];
            #pragma unroll
            for (int j = 0; j < 4; ++j)
                acc_s[j] = __builtin_amdgcn_mfma_f32_16x16x32_bf16(qa, kb[j], acc_s[j], 0, 0, 0);
        }
        __syncthreads();
        #pragma unroll
        for (int j = 0; j < 4; ++j) {
            #pragma unroll
            for (int reg = 0; reg < 4; ++reg) {
                int nl = fg * 4 + reg;
                int ng = n0 + wn + nl;
                int mg = mc * 64 + j * 16 + fr;
                int dist = ng - mg; if (dist < 0) dist = -dist;
                float a = acc_s[j][reg] * pwf[dist];
                __bf16 hp = (__bf16)a;
                __bf16 lp = (__bf16)(a - (float)hp);
                Sh[wv][nl][j * 16 + fr] = hp;
                Sl[wv][nl][j * 16 + fr] = lp;
            }
        }
        __syncthreads();
        #pragma unroll
        for (int ks = 0; ks < 2; ++ks) {
            bf16x8 af = *(const bf16x8*)&Sh[wv][fr][ks * 32 + fg * 8];
            bf16x8 al = *(const bf16x8*)&Sl[wv][fr][ks * 32 + fg * 8];
            bf16x8 vb[4];
            #pragma unroll
            for (int j = 0; j < 4; ++j)
                vb[j] = *(const bf16x8*)&VsT[j * 16 + fr][ks * 32 + fg * 8];
            #pragma unroll
            for (int j = 0; j < 4; ++j) {
                acc_o[j] = __builtin_amdgcn_mfma_f32_16x16x32_bf16(af, vb[j], acc_o[j], 0, 0, 0);
                acc_o[j] = __builtin_amdgcn_mfma_f32_16x16x32_bf16(al, vb[j], acc_o[j], 0, 0, 0);
            }
        }
    }

    #pragma unroll
    for (int j = 0; j < 4; ++j) {
        int c = h * 64 + j * 16 + fr;
        #pragma unroll
        for (int reg = 0; reg < 4; ++reg) {
            int n = n0 + wn + fg * 4 + reg;
            O[((size_t)(tb * 512 + n) << 9) + c] = acc_o[j][reg];
        }
    }
}

// ---------------------------------------------------------------------------
__global__ void lif_ret(float* __restrict__ OR, int* __restrict__ ctr,
                        int* __restrict__ list) {
    int g = blockIdx.x * TPB + threadIdx.x;
    int c = g & 511, n = (g >> 9) & 511, b = g >> 18;
    double v = 0.0, eb = 0.0;
    bool flag = false;
    for (int t = 0; t < 4; ++t) {
        size_t idx = ((size_t)((t * 8 + b) * 512 + n) << 9) + c;
        double x = (double)OR[idx];
        double hh = v + (x - v) * 0.5;
        eb = 0.5 * eb + 0.5 * (fabs(x) * 1e-4);
        flag |= fabs(hh - 0.5) <= eb + 1e-9;
        bool s = hh >= 0.5;
        OR[idx] = s ? 1.0f : 0.0f;
        v = s ? 0.0 : hh;
        if (s) eb = 0.0;
    }
    if (flag) {
        int i2 = atomicAdd(ctr + 4, 1);
        if (i2 < FCAP) list[i2] = g;
    }
}

__global__ void repair_ret(const u64* __restrict__ qm, const u64* __restrict__ km,
                           const u64* __restrict__ vm, const double* __restrict__ pw,
                           const int* __restrict__ ctr, const int* __restrict__ list,
                           float* __restrict__ r) {
    int cnt = ctr[4]; if (cnt > FCAP) cnt = FCAP;
    int wv = (blockIdx.x * blockDim.x + threadIdx.x) >> 6;
    int nw = (gridDim.x * blockDim.x) >> 6;
    int lane = threadIdx.x & 63;
    for (int i = wv; i < cnt; i += nw) {
        int g = list[i];
        int c = g & 511, n = (g >> 9) & 511, b = g >> 18;
        int h = c >> 6, d = c & 63;
        double acc_t[4];
        for (int t = 0; t < 4; ++t) {
            int base = ((t * 8 + b) * 8 + h) * 512;
            u64 qw = qm[base + n];
            double p = 0.0;
            for (int j = 0; j < 8; ++j) {
                int m = j * 64 + lane;
                u64 kk = km[base + m];
                u64 vv = vm[base + m];
                if ((vv >> d) & 1ull) {
                    int dist = n - m; if (dist < 0) dist = -dist;
                    p += (double)__popcll(qw & kk) * pw[h * 512 + dist];
                }
            }
            acc_t[t] = p;
        }
        #pragma unroll
        for (int off = 32; off; off >>= 1) {
            #pragma unroll
            for (int t = 0; t < 4; ++t) acc_t[t] += __shfl_xor(acc_t[t], off, 64);
        }
        if (lane == 0) {
            double v = 0.0;
            for (int t = 0; t < 4; ++t) {
                double x = acc_t[t] * 0.125;
                double hh = v + (x - v) * 0.5;
                bool s = hh >= 0.5;
                r[((size_t)((t * 8 + b) * 512 + n) << 9) + c] = s ? 1.0f : 0.0f;
                v = s ? 0.0 : hh;
            }
        }
    }
}

// ---------------------------------------------------------------------------
__global__ void final_flag(const float* __restrict__ Y, int* __restrict__ ctr,
                           int* __restrict__ list) {
    int g = blockIdx.x * TPB + threadIdx.x;
    int c = g & 511, n = (g >> 9) & 511, b = g >> 18;
    double v = 0.0;
    bool flag = false;
    for (int t = 0; t < 4; ++t) {
        float y = Y[((size_t)((t * 8 + b) * 512 + n) << 9) + c];
        double hh = v + ((double)y - v) * 0.5;
        flag |= fabs(hh - 1.0) < MARGIN;
        bool s = hh >= 1.0;
        v = s ? 0.0 : hh;
    }
    if (flag) {
        int idx = atomicAdd(ctr + 3, 1);
        if (idx < FCAP) list[idx] = g;
    }
}

__global__ void fix_final(const float* __restrict__ rr, const float* __restrict__ w,
                          const float* __restrict__ bias,
                          const float* __restrict__ bnw, const float* __restrict__ bnb,
                          const float* __restrict__ bnm, const float* __restrict__ bnv,
                          const int* __restrict__ ctr, int* __restrict__ list) {
    int cnt = ctr[3]; if (cnt > FCAP) cnt = FCAP;
    int wv = (blockIdx.x * blockDim.x + threadIdx.x) >> 6;
    int nw = (gridDim.x * blockDim.x) >> 6;
    int lane = threadIdx.x & 63;
    for (int i = wv; i < cnt; i += nw) {
        int g = list[i] & 0x00FFFFFF;
        int c = g & 511, n = (g >> 9) & 511, b = g >> 18;
        const float* wr = w + (size_t)c * 512;
        double dot[4];
        #pragma unroll
        for (int t = 0; t < 4; ++t) {
            const float* xr = rr + ((size_t)((t * 8 + b) * 512 + n) << 9);
            double p = 0.0;
            #pragma unroll
            for (int j = 0; j < 8; ++j)
                p += (double)xr[lane + 64 * j] * (double)wr[lane + 64 * j];
            dot[t] = p;
        }
        #pragma unroll
        for (int off = 32; off; off >>= 1) {
            #pragma unroll
            for (int t = 0; t < 4; ++t)
                dot[t] += __shfl_xor(dot[t], off, 64);
        }
        if (lane == 0) {
            double inv = (double)bnw[c] / sqrt((double)bnv[c] + 1e-5);
            double sh  = (double)bnb[c] - (double)bnm[c] * inv;
            double bs  = (double)bias[c];
            double v = 0.0;
            int sp = 0;
            for (int t = 0; t < 4; ++t) {
                double y = (dot[t] + bs) * inv + sh;
                double hh = v + (y - v) * 0.5;
                bool s = hh >= 1.0;
                sp |= (s ? 1 : 0) << t;
                v = s ? 0.0 : hh;
            }
            list[i] = g | (sp << 24);
        }
    }
}

__global__ void final_write(const float* __restrict__ Y, float* __restrict__ out) {
    int g = blockIdx.x * TPB + threadIdx.x;
    int c = g & 511, n = (g >> 9) & 511, b = g >> 18;
    double v = 0.0;
    for (int t = 0; t < 4; ++t) {
        size_t idx = ((size_t)((t * 8 + b) * 512 + n) << 9) + c;
        float y = Y[idx];
        double hh = v + ((double)y - v) * 0.5;
        bool s = hh >= 1.0;
        out[idx] = s ? 1.0f : 0.0f;
        v = s ? 0.0 : hh;
    }
}

__global__ void fix_scatter(const int* __restrict__ ctr, const int* __restrict__ list,
                            float* __restrict__ out) {
    int cnt = ctr[3]; if (cnt > FCAP) cnt = FCAP;
    int i = blockIdx.x * blockDim.x + threadIdx.x;
    if (i >= cnt) return;
    int e = list[i];
    int g = e & 0x00FFFFFF, sp = (e >> 24) & 0xF;
    int c = g & 511, n = (g >> 9) & 511, b = g >> 18;
    for (int t = 0; t < 4; ++t)
        out[((size_t)((t * 8 + b) * 512 + n) << 9) + c] = ((sp >> t) & 1) ? 1.0f : 0.0f;
}

// ---------------------------------------------------------------------------
extern "C" void kernel_launch(void* const* d_in, const int* in_sizes, int n_in,
                              void* d_out, int out_size, void* d_ws, size_t ws_size,
                              hipStream_t stream) {
    const float* x = (const float*)d_in[0];
    const float *w[4], *bi[4], *bnw[4], *bnb[4], *bnm[4], *bnv[4];
    for (int br = 0; br < 4; ++br) {
        int base = 1 + br * 6;
        w[br]   = (const float*)d_in[base + 0];
        bi[br]  = (const float*)d_in[base + 1];
        bnw[br] = (const float*)d_in[base + 2];
        bnb[br] = (const float*)d_in[base + 3];
        bnm[br] = (const float*)d_in[base + 4];
        bnv[br] = (const float*)d_in[base + 5];
    }

    const size_t NX = (size_t)16384 * 512;   // 8.4M elements
    char* p = (char*)d_ws;
    double* pw = (double*)p;  p += 8 * 512 * sizeof(double);
    u64* qm = (u64*)p;        p += 131072 * sizeof(u64);
    u64* km = (u64*)p;        p += 131072 * sizeof(u64);
    u64* vm = (u64*)p;        p += 131072 * sizeof(u64);
    int* ctr = (int*)p;       p += 1024;
    int* list = (int*)p;      p += (size_t)FCAP * sizeof(int);
    float* Y = (float*)p;     p += NX * 4;                      // ~40.6 MB so far
    __bf16* Xh = (__bf16*)p;  p += NX * 2;                      // 16.8 MB
    __bf16* Xl = (__bf16*)p;  p += NX * 2;                      // 16.8 MB
    __bf16* Wsp = (__bf16*)p; p += (size_t)4 * 2 * 262144 * 2;  // 4 MB
    size_t need_fast = (size_t)(p - (char*)d_ws);
    int fast = ws_size >= need_fast;
    float* r = (float*)d_out;

    zero_counters<<<1, 64, 0, stream>>>(ctr);
    pow_kernel<<<1, 64, 0, stream>>>(pw);

    if (fast) {
        split_f32<<<8192, 256, 0, stream>>>(x, Xh, Xl, (int)NX);
        for (int br = 0; br < 4; ++br)
            split_f32<<<256, 256, 0, stream>>>(w[br], Wsp + (size_t)br * 524288,
                                               Wsp + (size_t)br * 524288 + 262144, 262144);
    }

    dim3 g2(128, 4);   // fast gemm grid (128x128 tiles)
    dim3 gg(128, 8);   // fallback gemm grid (128x64 tiles)

    for (int br = 0; br < 3; ++br) {
        u64* msk = br == 0 ? qm : (br == 1 ? km : vm);
        if (fast)
            gemm_bn_mfma2<<<g2, 256, 0, stream>>>(Xh, Xl,
                Wsp + (size_t)br * 524288, Wsp + (size_t)br * 524288 + 262144,
                bi[br], bnw[br], bnb[br], bnm[br], bnv[br], Y, 1);
        else
            gemm_bn_mfma<<<gg, 256, 0, stream>>>(x, w[br], bi[br], bnw[br], bnb[br],
                                                 bnm[br], bnv[br], Y);
        lif_mask_flag<<<8192, TPB, 0, stream>>>(Y, msk, ctr, list, br);
        fix_mask<<<128, 256, 0, stream>>>(x, w[br], bi[br], bnw[br], bnb[br],
                                          bnm[br], bnv[br], msk, ctr, list, br);
    }

    // fused retention -> O in d_out -> LIF in place -> exact repair
    ret_fused<<<2048, 256, 0, stream>>>(qm, km, vm, pw, (float*)d_out);
    lif_ret<<<8192, TPB, 0, stream>>>((float*)d_out, ctr, list);
    repair_ret<<<256, 256, 0, stream>>>(qm, km, vm, pw, ctr, list, (float*)d_out);

    // p projection: r is binary -> exact bf16 A, 2-pass gemm
    if (fast) {
        split_bin<<<8192, 256, 0, stream>>>(r, Xh, (int)NX);
        gemm_bn_mfma2<<<g2, 256, 0, stream>>>(Xh, Xh,
            Wsp + (size_t)3 * 524288, Wsp + (size_t)3 * 524288 + 262144,
            bi[3], bnw[3], bnb[3], bnm[3], bnv[3], Y, 0);
    } else {
        gemm_bn_mfma<<<gg, 256, 0, stream>>>(r, w[3], bi[3], bnw[3], bnb[3],
                                             bnm[3], bnv[3], Y);
    }
    final_flag<<<8192, TPB, 0, stream>>>(Y, ctr, list);
    fix_final<<<128, 256, 0, stream>>>(r, w[3], bi[3], bnw[3], bnb[3], bnm[3], bnv[3], ctr, list);
    final_write<<<8192, TPB, 0, stream>>>(Y, (float*)d_out);
    fix_scatter<<<4096, 256, 0, stream>>>(ctr, list, (float*)d_out);
}

// Round 15
// 326.899 us; speedup vs baseline: 1.1208x; 1.1208x over previous
//
#include <hip/hip_runtime.h>
#include <cstdint>

typedef unsigned long long u64;

#define TPB 256
#define MARGIN 5e-4
#define FCAP (1 << 20)

typedef __bf16 bf16x8 __attribute__((ext_vector_type(8)));
typedef __bf16 bf16x4 __attribute__((ext_vector_type(4)));
typedef float f32x4 __attribute__((ext_vector_type(4)));

// ---------------------------------------------------------------------------
__global__ void init_kernel(double* __restrict__ pw, int* __restrict__ ctr) {
    int h = threadIdx.x;
    if (h < 8) {
        double gamma = 1.0 - ldexp(1.0, -5 - h);
        double p = 1.0;
        for (int i = 0; i < 512; ++i) { pw[h * 512 + i] = p; p *= gamma; }
        ctr[h] = 0;
    }
}

// ---------------------------------------------------------------------------
// Combined split: x (8192 blocks) + 4 weights (256 blocks each).
__global__ void split_all(const float* __restrict__ x,
                          const float* __restrict__ w0, const float* __restrict__ w1,
                          const float* __restrict__ w2, const float* __restrict__ w3,
                          __bf16* __restrict__ Xh, __bf16* __restrict__ Xl,
                          __bf16* __restrict__ Wsp) {
    int blk = blockIdx.x;
    const float* src; __bf16 *hi, *lo; size_t off;
    if (blk < 8192) {
        src = x; hi = Xh; lo = Xl; off = (size_t)blk * 1024;
    } else {
        int wb = blk - 8192;
        int br = wb >> 8;                       // 256 blocks per weight
        const float* ws[4] = {w0, w1, w2, w3};
        src = ws[br];
        hi = Wsp + (size_t)br * 524288;
        lo = hi + 262144;
        off = (size_t)(wb & 255) * 1024;
    }
    size_t i = off + threadIdx.x * 4;
    float4 v = *(const float4*)(src + i);
    bf16x4 h4, l4;
    #pragma unroll
    for (int e = 0; e < 4; ++e) {
        float f = (&v.x)[e];
        __bf16 hh = (__bf16)f;
        h4[e] = hh;
        l4[e] = (__bf16)(f - (float)hh);
    }
    *(bf16x4*)(hi + i) = h4;
    *(bf16x4*)(lo + i) = l4;
}

// ---------------------------------------------------------------------------
// MFMA GEMM + BN on pre-split bf16 inputs (R14-proven). 128x128, 4 waves.
__global__ __launch_bounds__(256) void gemm_bn_mfma2(
    const __bf16* __restrict__ Ahg, const __bf16* __restrict__ Alg,
    const __bf16* __restrict__ Whg, const __bf16* __restrict__ Wlg,
    const float* __restrict__ bias,
    const float* __restrict__ bnw, const float* __restrict__ bnb,
    const float* __restrict__ bnm, const float* __restrict__ bnv,
    float* __restrict__ out, int asplit)
{
    __shared__ __bf16 AhS[128][40];
    __shared__ __bf16 AlS[128][40];
    __shared__ __bf16 WhS[128][40];
    __shared__ __bf16 WlS[128][40];

    const int tid = threadIdx.x;
    const int m0 = blockIdx.x * 128;
    const int d0 = blockIdx.y * 128;
    const int wv = tid >> 6;
    const int wm = wv >> 1;
    const int wd = wv & 1;
    const int lane = tid & 63;
    const int fr = lane & 15;
    const int fg = lane >> 4;
    const int srow = tid >> 1;
    const int sseg = (tid & 1) * 16;

    f32x4 acc[4][4];
    #pragma unroll
    for (int i = 0; i < 4; ++i)
        #pragma unroll
        for (int j = 0; j < 4; ++j)
            acc[i][j] = (f32x4){0.f, 0.f, 0.f, 0.f};

    for (int k0 = 0; k0 < 512; k0 += 32) {
        __syncthreads();
        {
            const __bf16* pa = Ahg + (size_t)(m0 + srow) * 512 + k0 + sseg;
            *(bf16x8*)&AhS[srow][sseg]     = *(const bf16x8*)pa;
            *(bf16x8*)&AhS[srow][sseg + 8] = *(const bf16x8*)(pa + 8);
            if (asplit) {
                const __bf16* pl = Alg + (size_t)(m0 + srow) * 512 + k0 + sseg;
                *(bf16x8*)&AlS[srow][sseg]     = *(const bf16x8*)pl;
                *(bf16x8*)&AlS[srow][sseg + 8] = *(const bf16x8*)(pl + 8);
            }
            const __bf16* pwh = Whg + (size_t)(d0 + srow) * 512 + k0 + sseg;
            const __bf16* pwl = Wlg + (size_t)(d0 + srow) * 512 + k0 + sseg;
            *(bf16x8*)&WhS[srow][sseg]     = *(const bf16x8*)pwh;
            *(bf16x8*)&WhS[srow][sseg + 8] = *(const bf16x8*)(pwh + 8);
            *(bf16x8*)&WlS[srow][sseg]     = *(const bf16x8*)pwl;
            *(bf16x8*)&WlS[srow][sseg + 8] = *(const bf16x8*)(pwl + 8);
        }
        __syncthreads();

        bf16x8 ah[4], bh[4], bl[4];
        #pragma unroll
        for (int i = 0; i < 4; ++i)
            ah[i] = *(const bf16x8*)&AhS[wm * 64 + i * 16 + fr][fg * 8];
        #pragma unroll
        for (int j = 0; j < 4; ++j) {
            bh[j] = *(const bf16x8*)&WhS[wd * 64 + j * 16 + fr][fg * 8];
            bl[j] = *(const bf16x8*)&WlS[wd * 64 + j * 16 + fr][fg * 8];
        }
        #pragma unroll
        for (int i = 0; i < 4; ++i)
            #pragma unroll
            for (int j = 0; j < 4; ++j) {
                acc[i][j] = __builtin_amdgcn_mfma_f32_16x16x32_bf16(ah[i], bh[j], acc[i][j], 0, 0, 0);
                acc[i][j] = __builtin_amdgcn_mfma_f32_16x16x32_bf16(ah[i], bl[j], acc[i][j], 0, 0, 0);
            }
        if (asplit) {
            bf16x8 al[4];
            #pragma unroll
            for (int i = 0; i < 4; ++i)
                al[i] = *(const bf16x8*)&AlS[wm * 64 + i * 16 + fr][fg * 8];
            #pragma unroll
            for (int i = 0; i < 4; ++i)
                #pragma unroll
                for (int j = 0; j < 4; ++j)
                    acc[i][j] = __builtin_amdgcn_mfma_f32_16x16x32_bf16(al[i], bh[j], acc[i][j], 0, 0, 0);
        }
    }

    #pragma unroll
    for (int j = 0; j < 4; ++j) {
        int d = d0 + wd * 64 + j * 16 + fr;
        double inv = (double)bnw[d] / sqrt((double)bnv[d] + 1e-5);
        double sh  = (double)bnb[d] - (double)bnm[d] * inv;
        double bs  = (double)bias[d];
        #pragma unroll
        for (int i = 0; i < 4; ++i) {
            #pragma unroll
            for (int reg = 0; reg < 4; ++reg) {
                int m = m0 + wm * 64 + i * 16 + fg * 4 + reg;
                out[(size_t)m * 512 + d] = (float)(((double)acc[i][j][reg] + bs) * inv + sh);
            }
        }
    }
}

// ---------------------------------------------------------------------------
// Fallback fp32-input GEMM (R12-proven). 128m x 64d block.
__global__ __launch_bounds__(256) void gemm_bn_mfma(
    const float* __restrict__ A, const float* __restrict__ W,
    const float* __restrict__ bias,
    const float* __restrict__ bnw, const float* __restrict__ bnb,
    const float* __restrict__ bnm, const float* __restrict__ bnv,
    float* __restrict__ out)
{
    __shared__ __bf16 Ah[128][36];
    __shared__ __bf16 Al[128][36];
    __shared__ __bf16 Wh[64][36];
    __shared__ __bf16 Wl[64][36];

    const int tid = threadIdx.x;
    const int m0 = blockIdx.x * 128;
    const int d0 = blockIdx.y * 64;
    const int wv = tid >> 6;
    const int wm = wv >> 1;
    const int wd = wv & 1;
    const int lane = tid & 63;
    const int fr = lane & 15;
    const int fg = lane >> 4;
    const int srow = tid >> 3;
    const int scol = (tid & 7) * 4;

    f32x4 acc[4][2];
    #pragma unroll
    for (int i = 0; i < 4; ++i)
        #pragma unroll
        for (int j = 0; j < 2; ++j)
            acc[i][j] = (f32x4){0.f, 0.f, 0.f, 0.f};

    for (int k0 = 0; k0 < 512; k0 += 32) {
        __syncthreads();
        #pragma unroll
        for (int rep = 0; rep < 4; ++rep) {
            int row = srow + 32 * rep;
            float4 va = *(const float4*)(A + (size_t)(m0 + row) * 512 + k0 + scol);
            #pragma unroll
            for (int e = 0; e < 4; ++e) {
                float f = (&va.x)[e];
                __bf16 h = (__bf16)f;
                Ah[row][scol + e] = h;
                Al[row][scol + e] = (__bf16)(f - (float)h);
            }
        }
        #pragma unroll
        for (int rep = 0; rep < 2; ++rep) {
            int row = srow + 32 * rep;
            float4 vw = *(const float4*)(W + (size_t)(d0 + row) * 512 + k0 + scol);
            #pragma unroll
            for (int e = 0; e < 4; ++e) {
                float f = (&vw.x)[e];
                __bf16 h = (__bf16)f;
                Wh[row][scol + e] = h;
                Wl[row][scol + e] = (__bf16)(f - (float)h);
            }
        }
        __syncthreads();

        union FU { bf16x8 v8; struct { __bf16 a[4], b[4]; } s; };
        bf16x8 ah[4], al[4], bh[2], bl[2];
        #pragma unroll
        for (int i = 0; i < 4; ++i) {
            int row = wm * 64 + i * 16 + fr;
            FU u1, u2;
            *(double*)&u1.s.a[0] = *(const double*)&Ah[row][fg * 8];
            *(double*)&u1.s.b[0] = *(const double*)&Ah[row][fg * 8 + 4];
            *(double*)&u2.s.a[0] = *(const double*)&Al[row][fg * 8];
            *(double*)&u2.s.b[0] = *(const double*)&Al[row][fg * 8 + 4];
            ah[i] = u1.v8; al[i] = u2.v8;
        }
        #pragma unroll
        for (int j = 0; j < 2; ++j) {
            int row = wd * 32 + j * 16 + fr;
            FU u1, u2;
            *(double*)&u1.s.a[0] = *(const double*)&Wh[row][fg * 8];
            *(double*)&u1.s.b[0] = *(const double*)&Wh[row][fg * 8 + 4];
            *(double*)&u2.s.a[0] = *(const double*)&Wl[row][fg * 8];
            *(double*)&u2.s.b[0] = *(const double*)&Wl[row][fg * 8 + 4];
            bh[j] = u1.v8; bl[j] = u2.v8;
        }
        #pragma unroll
        for (int i = 0; i < 4; ++i)
            #pragma unroll
            for (int j = 0; j < 2; ++j) {
                acc[i][j] = __builtin_amdgcn_mfma_f32_16x16x32_bf16(ah[i], bh[j], acc[i][j], 0, 0, 0);
                acc[i][j] = __builtin_amdgcn_mfma_f32_16x16x32_bf16(ah[i], bl[j], acc[i][j], 0, 0, 0);
                acc[i][j] = __builtin_amdgcn_mfma_f32_16x16x32_bf16(al[i], bh[j], acc[i][j], 0, 0, 0);
            }
    }

    #pragma unroll
    for (int j = 0; j < 2; ++j) {
        int d = d0 + wd * 32 + j * 16 + fr;
        double inv = (double)bnw[d] / sqrt((double)bnv[d] + 1e-5);
        double sh  = (double)bnb[d] - (double)bnm[d] * inv;
        double bs  = (double)bias[d];
        #pragma unroll
        for (int i = 0; i < 4; ++i) {
            #pragma unroll
            for (int reg = 0; reg < 4; ++reg) {
                int m = m0 + wm * 64 + i * 16 + fg * 4 + reg;
                out[(size_t)m * 512 + d] = (float)(((double)acc[i][j][reg] + bs) * inv + sh);
            }
        }
    }
}

// ---------------------------------------------------------------------------
__global__ void lif_mask_flag(const float* __restrict__ Y, u64* __restrict__ msk,
                              int* __restrict__ ctr, int* __restrict__ list, int slot) {
    int g = blockIdx.x * TPB + threadIdx.x;
    int c = g & 511, n = (g >> 9) & 511, b = g >> 18;
    int h = c >> 6;
    int lane = threadIdx.x & 63;
    double v = 0.0;
    bool flag = false;
    for (int t = 0; t < 4; ++t) {
        float y = Y[((size_t)((t * 8 + b) * 512 + n) << 9) + c];
        double hh = v + ((double)y - v) * 0.5;
        flag |= fabs(hh - 1.0) < MARGIN;
        bool s = hh >= 1.0;
        u64 mk = __ballot(s);
        if (lane == 0) msk[((t * 8 + b) * 8 + h) * 512 + n] = mk;
        v = s ? 0.0 : hh;
    }
    if (flag) {
        int idx = atomicAdd(ctr + slot, 1);
        if (idx < FCAP) list[idx] = g;
    }
}

__global__ void fix_mask(const float* __restrict__ x, const float* __restrict__ w,
                         const float* __restrict__ bias,
                         const float* __restrict__ bnw, const float* __restrict__ bnb,
                         const float* __restrict__ bnm, const float* __restrict__ bnv,
                         u64* __restrict__ msk, const int* __restrict__ ctr,
                         const int* __restrict__ list, int slot) {
    int cnt = ctr[slot]; if (cnt > FCAP) cnt = FCAP;
    int wv = (blockIdx.x * blockDim.x + threadIdx.x) >> 6;
    int nw = (gridDim.x * blockDim.x) >> 6;
    int lane = threadIdx.x & 63;
    for (int i = wv; i < cnt; i += nw) {
        int g = list[i];
        int c = g & 511, n = (g >> 9) & 511, b = g >> 18;
        int h = c >> 6;
        const float* wr = w + (size_t)c * 512;
        double dot[4];
        #pragma unroll
        for (int t = 0; t < 4; ++t) {
            const float* xr = x + ((size_t)((t * 8 + b) * 512 + n) << 9);
            double p = 0.0;
            #pragma unroll
            for (int j = 0; j < 8; ++j)
                p += (double)xr[lane + 64 * j] * (double)wr[lane + 64 * j];
            dot[t] = p;
        }
        #pragma unroll
        for (int off = 32; off; off >>= 1) {
            #pragma unroll
            for (int t = 0; t < 4; ++t)
                dot[t] += __shfl_xor(dot[t], off, 64);
        }
        if (lane == 0) {
            double inv = (double)bnw[c] / sqrt((double)bnv[c] + 1e-5);
            double sh  = (double)bnb[c] - (double)bnm[c] * inv;
            double bs  = (double)bias[c];
            double v = 0.0;
            u64 bit = 1ull << (c & 63);
            for (int t = 0; t < 4; ++t) {
                double y = (dot[t] + bs) * inv + sh;
                double hh = v + (y - v) * 0.5;
                bool s = hh >= 1.0;
                u64* wp_ = &msk[((t * 8 + b) * 8 + h) * 512 + n];
                if (s) atomicOr(wp_, bit); else atomicAnd(wp_, ~bit);
                v = s ? 0.0 : hh;
            }
        }
    }
}

// ---------------------------------------------------------------------------
// Fused retention v2: S^T via mfma(K, Q-in-regs) -> packed u64 split ->
// PV with packed V^T.  All LDS accesses phase-conflict-free (see analysis).
__global__ __launch_bounds__(256) void ret_fused2(
    const u64* __restrict__ qm, const u64* __restrict__ km,
    const u64* __restrict__ vm, const double* __restrict__ pw,
    float* __restrict__ O)
{
    int bid = blockIdx.x;          // 2048 = tbh(256) * ntile(8)
    int tbh = bid >> 3;
    int n0 = (bid & 7) * 64;
    int h = tbh & 7;
    int tb = tbh >> 3;
    int tid = threadIdx.x;
    int wv = tid >> 6, lane = tid & 63, fr = lane & 15, fg = lane >> 4;
    int wn = wv * 16;

    __shared__ __bf16 Ks[64][72];      // K rows (m x e), 9.2 KB
    __shared__ u64 VsTg[16][66];       // packed V^T [m/4][d], 8.4 KB
    __shared__ u64 ShTg[4][16][17];    // per-wave packed S rows [mg][n], 8.7 KB
    __shared__ u64 SlTg[4][16][17];    // 8.7 KB
    __shared__ u64 vmc[64];
    __shared__ float pwf[512];         // gamma^dist / 8

    int base = tbh * 512;
    for (int i = tid; i < 512; i += 256) pwf[i] = (float)pw[h * 512 + i] * 0.125f;

    union U8 { u64 q[2]; bf16x8 v; };

    // Q B-fragments in registers: lane fr -> Q row n = n0+wn+fr, k = ks*32+fg*8..+7
    u64 qw = qm[base + n0 + wn + fr];
    bf16x8 qf[2];
    #pragma unroll
    for (int ks = 0; ks < 2; ++ks) {
        int e0 = ks * 32 + fg * 8;
        u64 plo = 0, phi = 0;
        #pragma unroll
        for (int e = 0; e < 4; ++e) {
            if ((qw >> (e0 + e)) & 1ull)     plo |= 0x3F80ull << (16 * e);
            if ((qw >> (e0 + 4 + e)) & 1ull) phi |= 0x3F80ull << (16 * e);
        }
        U8 u; u.q[0] = plo; u.q[1] = phi; qf[ks] = u.v;
    }

    f32x4 acc_o[4];
    #pragma unroll
    for (int j = 0; j < 4; ++j) acc_o[j] = (f32x4){0.f, 0.f, 0.f, 0.f};

    int nglob = n0 + wn + fr;

    for (int mc = 0; mc < 8; ++mc) {
        __syncthreads();   // S1: prior-iter reads of Ks/VsTg done
        {   // stage K chunk (64 m x 64 e)
            int row = tid >> 2, q4 = (tid & 3) * 16;
            u64 kw = km[base + mc * 64 + row];
            #pragma unroll
            for (int s = 0; s < 4; ++s) {
                int e0 = q4 + s * 4;
                u64 pk = 0;
                #pragma unroll
                for (int e = 0; e < 4; ++e)
                    if ((kw >> (e0 + e)) & 1ull) pk |= 0x3F80ull << (16 * e);
                *(u64*)&Ks[row][e0] = pk;
            }
        }
        if (tid < 64) vmc[tid] = vm[base + mc * 64 + tid];
        __syncthreads();   // S2: Ks + vmc visible
        {   // build packed V^T: d = lane, mg = wv*4+c (wave-uniform vmc reads)
            #pragma unroll
            for (int c = 0; c < 4; ++c) {
                int mg = wv * 4 + c;
                u64 pk = 0;
                #pragma unroll
                for (int e = 0; e < 4; ++e)
                    if ((vmc[mg * 4 + e] >> lane) & 1ull) pk |= 0x3F80ull << (16 * e);
                VsTg[mg][lane] = pk;
            }
        }
        // QK -> S^T tiles: rows m (4 j-tiles), cols n (this wave's 16)
        f32x4 accs[4];
        #pragma unroll
        for (int j = 0; j < 4; ++j) accs[j] = (f32x4){0.f, 0.f, 0.f, 0.f};
        #pragma unroll
        for (int ks = 0; ks < 2; ++ks) {
            #pragma unroll
            for (int j = 0; j < 4; ++j) {
                bf16x8 ka = *(const bf16x8*)&Ks[j * 16 + fr][ks * 32 + fg * 8];
                accs[j] = __builtin_amdgcn_mfma_f32_16x16x32_bf16(ka, qf[ks], accs[j], 0, 0, 0);
            }
        }
        // scale + split + pack -> own-wave ShTg/SlTg (1 b64 write per j per buf)
        #pragma unroll
        for (int j = 0; j < 4; ++j) {
            u64 ph = 0, pl = 0;
            #pragma unroll
            for (int reg = 0; reg < 4; ++reg) {
                int m = mc * 64 + j * 16 + fg * 4 + reg;
                int dist = nglob - m; if (dist < 0) dist = -dist;
                float a = accs[j][reg] * pwf[dist];
                __bf16 hp = (__bf16)a;
                __bf16 lp = (__bf16)(a - (float)hp);
                ph |= (u64)__builtin_bit_cast(unsigned short, hp) << (16 * reg);
                pl |= (u64)__builtin_bit_cast(unsigned short, lp) << (16 * reg);
            }
            ShTg[wv][j * 4 + fg][fr] = ph;
            SlTg[wv][j * 4 + fg][fr] = pl;
        }
        __syncthreads();   // S3: VsTg + ShTg visible
        // PV: acc_o += (Sh + Sl) @ V^T
        #pragma unroll
        for (int ks2 = 0; ks2 < 2; ++ks2) {
            int mga = ks2 * 8 + fg * 2;
            U8 ua, ul;
            ua.q[0] = ShTg[wv][mga][fr];  ua.q[1] = ShTg[wv][mga + 1][fr];
            ul.q[0] = SlTg[wv][mga][fr];  ul.q[1] = SlTg[wv][mga + 1][fr];
            #pragma unroll
            for (int j2 = 0; j2 < 4; ++j2) {
                U8 uv;
                uv.q[0] = VsTg[mga][j2 * 16 + fr];
                uv.q[1] = VsTg[mga + 1][j2 * 16 + fr];
                acc_o[j2] = __builtin_amdgcn_mfma_f32_16x16x32_bf16(ua.v, uv.v, acc_o[j2], 0, 0, 0);
                acc_o[j2] = __builtin_amdgcn_mfma_f32_16x16x32_bf16(ul.v, uv.v, acc_o[j2], 0, 0, 0);
            }
        }
    }

    #pragma unroll
    for (int j2 = 0; j2 < 4; ++j2) {
        int c = h * 64 + j2 * 16 + fr;
        #pragma unroll
        for (int reg = 0; reg < 4; ++reg) {
            int n = n0 + wn + fg * 4 + reg;
            O[((size_t)(tb * 512 + n) << 9) + c] = acc_o[j2][reg];
        }
    }
}

// ---------------------------------------------------------------------------
// Retention LIF reading O from Y; writes bf16 spikes to Rb; relative flag.
__global__ void lif_ret_bf(const float* __restrict__ Y, __bf16* __restrict__ Rb,
                           int* __restrict__ ctr, int* __restrict__ list) {
    int g = blockIdx.x * TPB + threadIdx.x;
    int c = g & 511, n = (g >> 9) & 511, b = g >> 18;
    double v = 0.0, eb = 0.0;
    bool flag = false;
    for (int t = 0; t < 4; ++t) {
        size_t idx = ((size_t)((t * 8 + b) * 512 + n) << 9) + c;
        double x = (double)Y[idx];
        double hh = v + (x - v) * 0.5;
        eb = 0.5 * eb + 0.5 * (fabs(x) * 1e-4);
        flag |= fabs(hh - 0.5) <= eb + 1e-9;
        bool s = hh >= 0.5;
        Rb[idx] = s ? (__bf16)1.0f : (__bf16)0.0f;
        v = s ? 0.0 : hh;
        if (s) eb = 0.0;
    }
    if (flag) {
        int i2 = atomicAdd(ctr + 4, 1);
        if (i2 < FCAP) list[i2] = g;
    }
}

// fallback: float spikes in-place on d_out (R14 behavior)
__global__ void lif_ret_f(const float* __restrict__ Y, float* __restrict__ R,
                          int* __restrict__ ctr, int* __restrict__ list) {
    int g = blockIdx.x * TPB + threadIdx.x;
    int c = g & 511, n = (g >> 9) & 511, b = g >> 18;
    double v = 0.0, eb = 0.0;
    bool flag = false;
    for (int t = 0; t < 4; ++t) {
        size_t idx = ((size_t)((t * 8 + b) * 512 + n) << 9) + c;
        double x = (double)Y[idx];
        double hh = v + (x - v) * 0.5;
        eb = 0.5 * eb + 0.5 * (fabs(x) * 1e-4);
        flag |= fabs(hh - 0.5) <= eb + 1e-9;
        bool s = hh >= 0.5;
        R[idx] = s ? 1.0f : 0.0f;
        v = s ? 0.0 : hh;
        if (s) eb = 0.0;
    }
    if (flag) {
        int i2 = atomicAdd(ctr + 4, 1);
        if (i2 < FCAP) list[i2] = g;
    }
}

// Exact fp64 recompute of flagged retention neurons; writes bf16 (fast).
__global__ void repair_ret_bf(const u64* __restrict__ qm, const u64* __restrict__ km,
                              const u64* __restrict__ vm, const double* __restrict__ pw,
                              const int* __restrict__ ctr, const int* __restrict__ list,
                              __bf16* __restrict__ Rb) {
    int cnt = ctr[4]; if (cnt > FCAP) cnt = FCAP;
    int wv = (blockIdx.x * blockDim.x + threadIdx.x) >> 6;
    int nw = (gridDim.x * blockDim.x) >> 6;
    int lane = threadIdx.x & 63;
    for (int i = wv; i < cnt; i += nw) {
        int g = list[i];
        int c = g & 511, n = (g >> 9) & 511, b = g >> 18;
        int h = c >> 6, d = c & 63;
        double acc_t[4];
        for (int t = 0; t < 4; ++t) {
            int base = ((t * 8 + b) * 8 + h) * 512;
            u64 qw = qm[base + n];
            double p = 0.0;
            for (int j = 0; j < 8; ++j) {
                int m = j * 64 + lane;
                u64 kk = km[base + m];
                u64 vvm = vm[base + m];
                if ((vvm >> d) & 1ull) {
                    int dist = n - m; if (dist < 0) dist = -dist;
                    p += (double)__popcll(qw & kk) * pw[h * 512 + dist];
                }
            }
            acc_t[t] = p;
        }
        #pragma unroll
        for (int off = 32; off; off >>= 1) {
            #pragma unroll
            for (int t = 0; t < 4; ++t) acc_t[t] += __shfl_xor(acc_t[t], off, 64);
        }
        if (lane == 0) {
            double v = 0.0;
            for (int t = 0; t < 4; ++t) {
                double x = acc_t[t] * 0.125;
                double hh = v + (x - v) * 0.5;
                bool s = hh >= 0.5;
                Rb[((size_t)((t * 8 + b) * 512 + n) << 9) + c] = s ? (__bf16)1.0f : (__bf16)0.0f;
                v = s ? 0.0 : hh;
            }
        }
    }
}

__global__ void repair_ret_f(const u64* __restrict__ qm, const u64* __restrict__ km,
                             const u64* __restrict__ vm, const double* __restrict__ pw,
                             const int* __restrict__ ctr, const int* __restrict__ list,
                             float* __restrict__ r) {
    int cnt = ctr[4]; if (cnt > FCAP) cnt = FCAP;
    int wv = (blockIdx.x * blockDim.x + threadIdx.x) >> 6;
    int nw = (gridDim.x * blockDim.x) >> 6;
    int lane = threadIdx.x & 63;
    for (int i = wv; i < cnt; i += nw) {
        int g = list[i];
        int c = g & 511, n = (g >> 9) & 511, b = g >> 18;
        int h = c >> 6, d = c & 63;
        double acc_t[4];
        for (int t = 0; t < 4; ++t) {
            int base = ((t * 8 + b) * 8 + h) * 512;
            u64 qw = qm[base + n];
            double p = 0.0;
            for (int j = 0; j < 8; ++j) {
                int m = j * 64 + lane;
                u64 kk = km[base + m];
                u64 vvm = vm[base + m];
                if ((vvm >> d) & 1ull) {
                    int dist = n - m; if (dist < 0) dist = -dist;
                    p += (double)__popcll(qw & kk) * pw[h * 512 + dist];
                }
            }
            acc_t[t] = p;
        }
        #pragma unroll
        for (int off = 32; off; off >>= 1) {
            #pragma unroll
            for (int t = 0; t < 4; ++t) acc_t[t] += __shfl_xor(acc_t[t], off, 64);
        }
        if (lane == 0) {
            double v = 0.0;
            for (int t = 0; t < 4; ++t) {
                double x = acc_t[t] * 0.125;
                double hh = v + (x - v) * 0.5;
                bool s = hh >= 0.5;
                r[((size_t)((t * 8 + b) * 512 + n) << 9) + c] = s ? 1.0f : 0.0f;
                v = s ? 0.0 : hh;
            }
        }
    }
}

// ---------------------------------------------------------------------------
// Fused final LIF: in-place on d_out (p-GEMM output), flags slot 3.
__global__ void final_lif_flag(float* __restrict__ Y, int* __restrict__ ctr,
                               int* __restrict__ list) {
    int g = blockIdx.x * TPB + threadIdx.x;
    int c = g & 511, n = (g >> 9) & 511, b = g >> 18;
    double v = 0.0;
    bool flag = false;
    for (int t = 0; t < 4; ++t) {
        size_t idx = ((size_t)((t * 8 + b) * 512 + n) << 9) + c;
        float y = Y[idx];
        double hh = v + ((double)y - v) * 0.5;
        flag |= fabs(hh - 1.0) < MARGIN;
        bool s = hh >= 1.0;
        Y[idx] = s ? 1.0f : 0.0f;
        v = s ? 0.0 : hh;
    }
    if (flag) {
        int idx = atomicAdd(ctr + 3, 1);
        if (idx < FCAP) list[idx] = g;
    }
}

// fallback pair
__global__ void final_flag(const float* __restrict__ Y, int* __restrict__ ctr,
                           int* __restrict__ list) {
    int g = blockIdx.x * TPB + threadIdx.x;
    int c = g & 511, n = (g >> 9) & 511, b = g >> 18;
    double v = 0.0;
    bool flag = false;
    for (int t = 0; t < 4; ++t) {
        float y = Y[((size_t)((t * 8 + b) * 512 + n) << 9) + c];
        double hh = v + ((double)y - v) * 0.5;
        flag |= fabs(hh - 1.0) < MARGIN;
        bool s = hh >= 1.0;
        v = s ? 0.0 : hh;
    }
    if (flag) {
        int idx = atomicAdd(ctr + 3, 1);
        if (idx < FCAP) list[idx] = g;
    }
}

__global__ void final_write(const float* __restrict__ Y, float* __restrict__ out) {
    int g = blockIdx.x * TPB + threadIdx.x;
    int c = g & 511, n = (g >> 9) & 511, b = g >> 18;
    double v = 0.0;
    for (int t = 0; t < 4; ++t) {
        size_t idx = ((size_t)((t * 8 + b) * 512 + n) << 9) + c;
        float y = Y[idx];
        double hh = v + ((double)y - v) * 0.5;
        bool s = hh >= 1.0;
        out[idx] = s ? 1.0f : 0.0f;
        v = s ? 0.0 : hh;
    }
}

// fix_final reading bf16 r (fast path)
__global__ void fix_final_bf(const __bf16* __restrict__ rr, const float* __restrict__ w,
                             const float* __restrict__ bias,
                             const float* __restrict__ bnw, const float* __restrict__ bnb,
                             const float* __restrict__ bnm, const float* __restrict__ bnv,
                             const int* __restrict__ ctr, int* __restrict__ list) {
    int cnt = ctr[3]; if (cnt > FCAP) cnt = FCAP;
    int wv = (blockIdx.x * blockDim.x + threadIdx.x) >> 6;
    int nw = (gridDim.x * blockDim.x) >> 6;
    int lane = threadIdx.x & 63;
    for (int i = wv; i < cnt; i += nw) {
        int g = list[i] & 0x00FFFFFF;
        int c = g & 511, n = (g >> 9) & 511, b = g >> 18;
        const float* wr = w + (size_t)c * 512;
        double dot[4];
        #pragma unroll
        for (int t = 0; t < 4; ++t) {
            const __bf16* xr = rr + ((size_t)((t * 8 + b) * 512 + n) << 9);
            double p = 0.0;
            #pragma unroll
            for (int j = 0; j < 8; ++j)
                p += (double)(float)xr[lane + 64 * j] * (double)wr[lane + 64 * j];
            dot[t] = p;
        }
        #pragma unroll
        for (int off = 32; off; off >>= 1) {
            #pragma unroll
            for (int t = 0; t < 4; ++t)
                dot[t] += __shfl_xor(dot[t], off, 64);
        }
        if (lane == 0) {
            double inv = (double)bnw[c] / sqrt((double)bnv[c] + 1e-5);
            double sh  = (double)bnb[c] - (double)bnm[c] * inv;
            double bs  = (double)bias[c];
            double v = 0.0;
            int sp = 0;
            for (int t = 0; t < 4; ++t) {
                double y = (dot[t] + bs) * inv + sh;
                double hh = v + (y - v) * 0.5;
                bool s = hh >= 1.0;
                sp |= (s ? 1 : 0) << t;
                v = s ? 0.0 : hh;
            }
            list[i] = g | (sp << 24);
        }
    }
}

__global__ void fix_final_f(const float* __restrict__ rr, const float* __restrict__ w,
                            const float* __restrict__ bias,
                            const float* __restrict__ bnw, const float* __restrict__ bnb,
                            const float* __restrict__ bnm, const float* __restrict__ bnv,
                            const int* __restrict__ ctr, int* __restrict__ list) {
    int cnt = ctr[3]; if (cnt > FCAP) cnt = FCAP;
    int wv = (blockIdx.x * blockDim.x + threadIdx.x) >> 6;
    int nw = (gridDim.x * blockDim.x) >> 6;
    int lane = threadIdx.x & 63;
    for (int i = wv; i < cnt; i += nw) {
        int g = list[i] & 0x00FFFFFF;
        int c = g & 511, n = (g >> 9) & 511, b = g >> 18;
        const float* wr = w + (size_t)c * 512;
        double dot[4];
        #pragma unroll
        for (int t = 0; t < 4; ++t) {
            const float* xr = rr + ((size_t)((t * 8 + b) * 512 + n) << 9);
            double p = 0.0;
            #pragma unroll
            for (int j = 0; j < 8; ++j)
                p += (double)xr[lane + 64 * j] * (double)wr[lane + 64 * j];
            dot[t] = p;
        }
        #pragma unroll
        for (int off = 32; off; off >>= 1) {
            #pragma unroll
            for (int t = 0; t < 4; ++t)
                dot[t] += __shfl_xor(dot[t], off, 64);
        }
        if (lane == 0) {
            double inv = (double)bnw[c] / sqrt((double)bnv[c] + 1e-5);
            double sh  = (double)bnb[c] - (double)bnm[c] * inv;
            double bs  = (double)bias[c];
            double v = 0.0;
            int sp = 0;
            for (int t = 0; t < 4; ++t) {
                double y = (dot[t] + bs) * inv + sh;
                double hh = v + (y - v) * 0.5;
                bool s = hh >= 1.0;
                sp |= (s ? 1 : 0) << t;
                v = s ? 0.0 : hh;
            }
            list[i] = g | (sp << 24);
        }
    }
}

__global__ void fix_scatter(const int* __restrict__ ctr, const int* __restrict__ list,
                            float* __restrict__ out) {
    int cnt = ctr[3]; if (cnt > FCAP) cnt = FCAP;
    int i = blockIdx.x * blockDim.x + threadIdx.x;
    if (i >= cnt) return;
    int e = list[i];
    int g = e & 0x00FFFFFF, sp = (e >> 24) & 0xF;
    int c = g & 511, n = (g >> 9) & 511, b = g >> 18;
    for (int t = 0; t < 4; ++t)
        out[((size_t)((t * 8 + b) * 512 + n) << 9) + c] = ((sp >> t) & 1) ? 1.0f : 0.0f;
}

// ---------------------------------------------------------------------------
extern "C" void kernel_launch(void* const* d_in, const int* in_sizes, int n_in,
                              void* d_out, int out_size, void* d_ws, size_t ws_size,
                              hipStream_t stream) {
    const float* x = (const float*)d_in[0];
    const float *w[4], *bi[4], *bnw[4], *bnb[4], *bnm[4], *bnv[4];
    for (int br = 0; br < 4; ++br) {
        int base = 1 + br * 6;
        w[br]   = (const float*)d_in[base + 0];
        bi[br]  = (const float*)d_in[base + 1];
        bnw[br] = (const float*)d_in[base + 2];
        bnb[br] = (const float*)d_in[base + 3];
        bnm[br] = (const float*)d_in[base + 4];
        bnv[br] = (const float*)d_in[base + 5];
    }

    const size_t NX = (size_t)16384 * 512;
    char* p = (char*)d_ws;
    double* pw = (double*)p;  p += 8 * 512 * sizeof(double);
    u64* qm = (u64*)p;        p += 131072 * sizeof(u64);
    u64* km = (u64*)p;        p += 131072 * sizeof(u64);
    u64* vm = (u64*)p;        p += 131072 * sizeof(u64);
    int* ctr = (int*)p;       p += 1024;
    int* list = (int*)p;      p += (size_t)FCAP * sizeof(int);
    float* Y = (float*)p;     p += NX * 4;
    __bf16* Xh = (__bf16*)p;  p += NX * 2;
    __bf16* Xl = (__bf16*)p;  p += NX * 2;
    __bf16* Wsp = (__bf16*)p; p += (size_t)4 * 2 * 262144 * 2;
    size_t need_fast = (size_t)(p - (char*)d_ws);
    int fast = ws_size >= need_fast;

    init_kernel<<<1, 64, 0, stream>>>(pw, ctr);

    dim3 g2(128, 4);
    dim3 gg(128, 8);

    if (fast) {
        split_all<<<8192 + 1024, 256, 0, stream>>>(x, w[0], w[1], w[2], w[3], Xh, Xl, Wsp);
        for (int br = 0; br < 3; ++br) {
            u64* msk = br == 0 ? qm : (br == 1 ? km : vm);
            gemm_bn_mfma2<<<g2, 256, 0, stream>>>(Xh, Xl,
                Wsp + (size_t)br * 524288, Wsp + (size_t)br * 524288 + 262144,
                bi[br], bnw[br], bnb[br], bnm[br], bnv[br], Y, 1);
            lif_mask_flag<<<8192, TPB, 0, stream>>>(Y, msk, ctr, list, br);
            fix_mask<<<128, 256, 0, stream>>>(x, w[br], bi[br], bnw[br], bnb[br],
                                              bnm[br], bnv[br], msk, ctr, list, br);
        }
        // retention: O -> Y; LIF -> bf16 spikes in Xh; exact repair on Xh
        ret_fused2<<<2048, 256, 0, stream>>>(qm, km, vm, pw, Y);
        lif_ret_bf<<<8192, TPB, 0, stream>>>(Y, Xh, ctr, list);
        repair_ret_bf<<<256, 256, 0, stream>>>(qm, km, vm, pw, ctr, list, Xh);
        // p projection from bf16 spikes (exact A) -> d_out; fused final LIF
        gemm_bn_mfma2<<<g2, 256, 0, stream>>>(Xh, Xh,
            Wsp + (size_t)3 * 524288, Wsp + (size_t)3 * 524288 + 262144,
            bi[3], bnw[3], bnb[3], bnm[3], bnv[3], (float*)d_out, 0);
        final_lif_flag<<<8192, TPB, 0, stream>>>((float*)d_out, ctr, list);
        fix_final_bf<<<128, 256, 0, stream>>>(Xh, w[3], bi[3], bnw[3], bnb[3],
                                              bnm[3], bnv[3], ctr, list);
        fix_scatter<<<4096, 256, 0, stream>>>(ctr, list, (float*)d_out);
    } else {
        for (int br = 0; br < 3; ++br) {
            u64* msk = br == 0 ? qm : (br == 1 ? km : vm);
            gemm_bn_mfma<<<gg, 256, 0, stream>>>(x, w[br], bi[br], bnw[br], bnb[br],
                                                 bnm[br], bnv[br], Y);
            lif_mask_flag<<<8192, TPB, 0, stream>>>(Y, msk, ctr, list, br);
            fix_mask<<<128, 256, 0, stream>>>(x, w[br], bi[br], bnw[br], bnb[br],
                                              bnm[br], bnv[br], msk, ctr, list, br);
        }
        float* r = (float*)d_out;
        ret_fused2<<<2048, 256, 0, stream>>>(qm, km, vm, pw, Y);
        lif_ret_f<<<8192, TPB, 0, stream>>>(Y, r, ctr, list);
        repair_ret_f<<<256, 256, 0, stream>>>(qm, km, vm, pw, ctr, list, r);
        gemm_bn_mfma<<<gg, 256, 0, stream>>>(r, w[3], bi[3], bnw[3], bnb[3],
                                             bnm[3], bnv[3], Y);
        final_flag<<<8192, TPB, 0, stream>>>(Y, ctr, list);
        fix_final_f<<<128, 256, 0, stream>>>(r, w[3], bi[3], bnw[3], bnb[3],
                                             bnm[3], bnv[3], ctr, list);
        final_write<<<8192, TPB, 0, stream>>>(Y, (float*)d_out);
        fix_scatter<<<4096, 256, 0, stream>>>(ctr, list, (float*)d_out);
    }
}

// Round 16
// 282.540 us; speedup vs baseline: 1.2968x; 1.1570x over previous
//
#include <hip/hip_runtime.h>
#include <cstdint>

typedef unsigned long long u64;

#define TPB 256
#define MARGIN 5e-4
#define FCAP (1 << 20)

typedef __bf16 bf16x8 __attribute__((ext_vector_type(8)));
typedef __bf16 bf16x4 __attribute__((ext_vector_type(4)));
typedef float f32x4 __attribute__((ext_vector_type(4)));

// ---------------------------------------------------------------------------
__global__ void init_kernel(double* __restrict__ pw, int* __restrict__ ctr) {
    int h = threadIdx.x;
    if (h < 8) {
        double gamma = 1.0 - ldexp(1.0, -5 - h);
        double p = 1.0;
        for (int i = 0; i < 512; ++i) { pw[h * 512 + i] = p; p *= gamma; }
        ctr[h] = 0;
    }
}

// ---------------------------------------------------------------------------
// Combined split. x rows are PERMUTED to m' = (b*512+n)*4 + t so the GEMM's
// accumulator reg index == t (enables in-register LIF in the epilogue).
__global__ void split_all(const float* __restrict__ x,
                          const float* __restrict__ w0, const float* __restrict__ w1,
                          const float* __restrict__ w2, const float* __restrict__ w3,
                          __bf16* __restrict__ Xh, __bf16* __restrict__ Xl,
                          __bf16* __restrict__ Wsp) {
    int blk = blockIdx.x;
    if (blk < 8192) {
        size_t i = (size_t)blk * 1024 + threadIdx.x * 4;
        int m = (int)(i >> 9), c = (int)(i & 511);
        int mp = (m & 4095) * 4 + (m >> 12);
        float4 v = *(const float4*)(x + i);
        bf16x4 h4, l4;
        #pragma unroll
        for (int e = 0; e < 4; ++e) {
            float f = (&v.x)[e];
            __bf16 hh = (__bf16)f;
            h4[e] = hh;
            l4[e] = (__bf16)(f - (float)hh);
        }
        size_t dst = (size_t)mp * 512 + c;
        *(bf16x4*)(Xh + dst) = h4;
        *(bf16x4*)(Xl + dst) = l4;
    } else {
        int wb = blk - 8192;
        int br = wb >> 8;
        const float* ws[4] = {w0, w1, w2, w3};
        const float* src = ws[br];
        __bf16* hi = Wsp + (size_t)br * 524288;
        __bf16* lo = hi + 262144;
        size_t i = (size_t)(wb & 255) * 1024 + threadIdx.x * 4;
        float4 v = *(const float4*)(src + i);
        bf16x4 h4, l4;
        #pragma unroll
        for (int e = 0; e < 4; ++e) {
            float f = (&v.x)[e];
            __bf16 hh = (__bf16)f;
            h4[e] = hh;
            l4[e] = (__bf16)(f - (float)hh);
        }
        *(bf16x4*)(hi + i) = h4;
        *(bf16x4*)(lo + i) = l4;
    }
}

// ---------------------------------------------------------------------------
// Branch GEMM (3-pass split-bf16) + fused BN + LIF + mask/flag epilogue.
// Rows are m' = bn*4 + t; thread reg index == t.
__global__ __launch_bounds__(256) void gemm_lif_mask(
    const __bf16* __restrict__ Ahg, const __bf16* __restrict__ Alg,
    const __bf16* __restrict__ Whg, const __bf16* __restrict__ Wlg,
    const float* __restrict__ bias,
    const float* __restrict__ bnw, const float* __restrict__ bnb,
    const float* __restrict__ bnm, const float* __restrict__ bnv,
    u64* __restrict__ msk, int* __restrict__ ctr, int* __restrict__ list, int slot)
{
    __shared__ __bf16 AhS[128][40];
    __shared__ __bf16 AlS[128][40];
    __shared__ __bf16 WhS[128][40];
    __shared__ __bf16 WlS[128][40];

    const int tid = threadIdx.x;
    const int m0 = blockIdx.x * 128;
    const int d0 = blockIdx.y * 128;
    const int wv = tid >> 6;
    const int wm = wv >> 1;
    const int wd = wv & 1;
    const int lane = tid & 63;
    const int fr = lane & 15;
    const int fg = lane >> 4;
    const int srow = tid >> 1;
    const int sseg = (tid & 1) * 16;

    f32x4 acc[4][4];
    #pragma unroll
    for (int i = 0; i < 4; ++i)
        #pragma unroll
        for (int j = 0; j < 4; ++j)
            acc[i][j] = (f32x4){0.f, 0.f, 0.f, 0.f};

    for (int k0 = 0; k0 < 512; k0 += 32) {
        __syncthreads();
        {
            const __bf16* pa = Ahg + (size_t)(m0 + srow) * 512 + k0 + sseg;
            *(bf16x8*)&AhS[srow][sseg]     = *(const bf16x8*)pa;
            *(bf16x8*)&AhS[srow][sseg + 8] = *(const bf16x8*)(pa + 8);
            const __bf16* pl = Alg + (size_t)(m0 + srow) * 512 + k0 + sseg;
            *(bf16x8*)&AlS[srow][sseg]     = *(const bf16x8*)pl;
            *(bf16x8*)&AlS[srow][sseg + 8] = *(const bf16x8*)(pl + 8);
            const __bf16* pwh = Whg + (size_t)(d0 + srow) * 512 + k0 + sseg;
            const __bf16* pwl = Wlg + (size_t)(d0 + srow) * 512 + k0 + sseg;
            *(bf16x8*)&WhS[srow][sseg]     = *(const bf16x8*)pwh;
            *(bf16x8*)&WhS[srow][sseg + 8] = *(const bf16x8*)(pwh + 8);
            *(bf16x8*)&WlS[srow][sseg]     = *(const bf16x8*)pwl;
            *(bf16x8*)&WlS[srow][sseg + 8] = *(const bf16x8*)(pwl + 8);
        }
        __syncthreads();

        bf16x8 ah[4], bh[4], bl[4];
        #pragma unroll
        for (int i = 0; i < 4; ++i)
            ah[i] = *(const bf16x8*)&AhS[wm * 64 + i * 16 + fr][fg * 8];
        #pragma unroll
        for (int j = 0; j < 4; ++j) {
            bh[j] = *(const bf16x8*)&WhS[wd * 64 + j * 16 + fr][fg * 8];
            bl[j] = *(const bf16x8*)&WlS[wd * 64 + j * 16 + fr][fg * 8];
        }
        #pragma unroll
        for (int i = 0; i < 4; ++i)
            #pragma unroll
            for (int j = 0; j < 4; ++j) {
                acc[i][j] = __builtin_amdgcn_mfma_f32_16x16x32_bf16(ah[i], bh[j], acc[i][j], 0, 0, 0);
                acc[i][j] = __builtin_amdgcn_mfma_f32_16x16x32_bf16(ah[i], bl[j], acc[i][j], 0, 0, 0);
            }
        bf16x8 al[4];
        #pragma unroll
        for (int i = 0; i < 4; ++i)
            al[i] = *(const bf16x8*)&AlS[wm * 64 + i * 16 + fr][fg * 8];
        #pragma unroll
        for (int i = 0; i < 4; ++i)
            #pragma unroll
            for (int j = 0; j < 4; ++j)
                acc[i][j] = __builtin_amdgcn_mfma_f32_16x16x32_bf16(al[i], bh[j], acc[i][j], 0, 0, 0);
    }

    // ---- epilogue: BN + LIF(1.0) + mask ballots + margin flags
    double invj[4], shj[4], bsj[4];
    #pragma unroll
    for (int j = 0; j < 4; ++j) {
        int d = d0 + wd * 64 + j * 16 + fr;
        invj[j] = (double)bnw[d] / sqrt((double)bnv[d] + 1e-5);
        shj[j]  = (double)bnb[d] - (double)bnm[d] * invj[j];
        bsj[j]  = (double)bias[d];
    }
    int hword = (d0 >> 6) + wd;
    int bn0 = blockIdx.x * 32 + wm * 16;

    #pragma unroll
    for (int i = 0; i < 4; ++i) {
        int bn = bn0 + i * 4 + fg;
        int b = bn >> 9, n = bn & 511;
        u64 w[4] = {0ull, 0ull, 0ull, 0ull};
        #pragma unroll
        for (int j = 0; j < 4; ++j) {
            double v = 0.0;
            bool fl = false;
            #pragma unroll
            for (int t = 0; t < 4; ++t) {
                double y = ((double)acc[i][j][t] + bsj[j]) * invj[j] + shj[j];
                double hh = v + (y - v) * 0.5;
                fl |= fabs(hh - 1.0) < MARGIN;
                bool s = hh >= 1.0;
                u64 blt = __ballot(s);
                w[t] |= ((blt >> (fg * 16)) & 0xFFFFull) << (j * 16);
                v = s ? 0.0 : hh;
            }
            if (fl) {
                int d = d0 + wd * 64 + j * 16 + fr;
                int idx = atomicAdd(ctr + slot, 1);
                if (idx < FCAP) list[idx] = (b << 18) | (n << 9) | d;
            }
        }
        if (fr == 0) {
            #pragma unroll
            for (int t = 0; t < 4; ++t)
                msk[((t * 8 + b) * 8 + hword) * 512 + n] = w[t];
        }
    }
}

// ---------------------------------------------------------------------------
// Final GEMM (2-pass, A exact bf16 spikes in m'=(bn,t) layout) + fused BN +
// final LIF(1.0); writes {0,1} fp32 directly to out (t,b,n,c); flags slot 3.
__global__ __launch_bounds__(256) void gemm_final_lif(
    const __bf16* __restrict__ Ahg,
    const __bf16* __restrict__ Whg, const __bf16* __restrict__ Wlg,
    const float* __restrict__ bias,
    const float* __restrict__ bnw, const float* __restrict__ bnb,
    const float* __restrict__ bnm, const float* __restrict__ bnv,
    float* __restrict__ out, int* __restrict__ ctr, int* __restrict__ list)
{
    __shared__ __bf16 AhS[128][40];
    __shared__ __bf16 WhS[128][40];
    __shared__ __bf16 WlS[128][40];

    const int tid = threadIdx.x;
    const int m0 = blockIdx.x * 128;
    const int d0 = blockIdx.y * 128;
    const int wv = tid >> 6;
    const int wm = wv >> 1;
    const int wd = wv & 1;
    const int lane = tid & 63;
    const int fr = lane & 15;
    const int fg = lane >> 4;
    const int srow = tid >> 1;
    const int sseg = (tid & 1) * 16;

    f32x4 acc[4][4];
    #pragma unroll
    for (int i = 0; i < 4; ++i)
        #pragma unroll
        for (int j = 0; j < 4; ++j)
            acc[i][j] = (f32x4){0.f, 0.f, 0.f, 0.f};

    for (int k0 = 0; k0 < 512; k0 += 32) {
        __syncthreads();
        {
            const __bf16* pa = Ahg + (size_t)(m0 + srow) * 512 + k0 + sseg;
            *(bf16x8*)&AhS[srow][sseg]     = *(const bf16x8*)pa;
            *(bf16x8*)&AhS[srow][sseg + 8] = *(const bf16x8*)(pa + 8);
            const __bf16* pwh = Whg + (size_t)(d0 + srow) * 512 + k0 + sseg;
            const __bf16* pwl = Wlg + (size_t)(d0 + srow) * 512 + k0 + sseg;
            *(bf16x8*)&WhS[srow][sseg]     = *(const bf16x8*)pwh;
            *(bf16x8*)&WhS[srow][sseg + 8] = *(const bf16x8*)(pwh + 8);
            *(bf16x8*)&WlS[srow][sseg]     = *(const bf16x8*)pwl;
            *(bf16x8*)&WlS[srow][sseg + 8] = *(const bf16x8*)(pwl + 8);
        }
        __syncthreads();

        bf16x8 ah[4], bh[4], bl[4];
        #pragma unroll
        for (int i = 0; i < 4; ++i)
            ah[i] = *(const bf16x8*)&AhS[wm * 64 + i * 16 + fr][fg * 8];
        #pragma unroll
        for (int j = 0; j < 4; ++j) {
            bh[j] = *(const bf16x8*)&WhS[wd * 64 + j * 16 + fr][fg * 8];
            bl[j] = *(const bf16x8*)&WlS[wd * 64 + j * 16 + fr][fg * 8];
        }
        #pragma unroll
        for (int i = 0; i < 4; ++i)
            #pragma unroll
            for (int j = 0; j < 4; ++j) {
                acc[i][j] = __builtin_amdgcn_mfma_f32_16x16x32_bf16(ah[i], bh[j], acc[i][j], 0, 0, 0);
                acc[i][j] = __builtin_amdgcn_mfma_f32_16x16x32_bf16(ah[i], bl[j], acc[i][j], 0, 0, 0);
            }
    }

    double invj[4], shj[4], bsj[4];
    #pragma unroll
    for (int j = 0; j < 4; ++j) {
        int d = d0 + wd * 64 + j * 16 + fr;
        invj[j] = (double)bnw[d] / sqrt((double)bnv[d] + 1e-5);
        shj[j]  = (double)bnb[d] - (double)bnm[d] * invj[j];
        bsj[j]  = (double)bias[d];
    }
    int bn0 = blockIdx.x * 32 + wm * 16;

    #pragma unroll
    for (int i = 0; i < 4; ++i) {
        int bn = bn0 + i * 4 + fg;
        int b = bn >> 9, n = bn & 511;
        #pragma unroll
        for (int j = 0; j < 4; ++j) {
            int d = d0 + wd * 64 + j * 16 + fr;
            double v = 0.0;
            bool fl = false;
            #pragma unroll
            for (int t = 0; t < 4; ++t) {
                double y = ((double)acc[i][j][t] + bsj[j]) * invj[j] + shj[j];
                double hh = v + (y - v) * 0.5;
                fl |= fabs(hh - 1.0) < MARGIN;
                bool s = hh >= 1.0;
                out[((size_t)((t * 8 + b) * 512 + n) << 9) + d] = s ? 1.0f : 0.0f;
                v = s ? 0.0 : hh;
            }
            if (fl) {
                int idx = atomicAdd(ctr + 3, 1);
                if (idx < FCAP) list[idx] = (b << 18) | (n << 9) | d;
            }
        }
    }
}

// ---------------------------------------------------------------------------
// Exact fp64 repair of flagged branch neurons (reads original x layout).
__global__ void fix_mask(const float* __restrict__ x, const float* __restrict__ w,
                         const float* __restrict__ bias,
                         const float* __restrict__ bnw, const float* __restrict__ bnb,
                         const float* __restrict__ bnm, const float* __restrict__ bnv,
                         u64* __restrict__ msk, const int* __restrict__ ctr,
                         const int* __restrict__ list, int slot) {
    int cnt = ctr[slot]; if (cnt > FCAP) cnt = FCAP;
    int wv = (blockIdx.x * blockDim.x + threadIdx.x) >> 6;
    int nw = (gridDim.x * blockDim.x) >> 6;
    int lane = threadIdx.x & 63;
    for (int i = wv; i < cnt; i += nw) {
        int g = list[i];
        int c = g & 511, n = (g >> 9) & 511, b = g >> 18;
        int h = c >> 6;
        const float* wr = w + (size_t)c * 512;
        double dot[4];
        #pragma unroll
        for (int t = 0; t < 4; ++t) {
            const float* xr = x + ((size_t)((t * 8 + b) * 512 + n) << 9);
            double p = 0.0;
            #pragma unroll
            for (int j = 0; j < 8; ++j)
                p += (double)xr[lane + 64 * j] * (double)wr[lane + 64 * j];
            dot[t] = p;
        }
        #pragma unroll
        for (int off = 32; off; off >>= 1) {
            #pragma unroll
            for (int t = 0; t < 4; ++t)
                dot[t] += __shfl_xor(dot[t], off, 64);
        }
        if (lane == 0) {
            double inv = (double)bnw[c] / sqrt((double)bnv[c] + 1e-5);
            double sh  = (double)bnb[c] - (double)bnm[c] * inv;
            double bs  = (double)bias[c];
            double v = 0.0;
            u64 bit = 1ull << (c & 63);
            for (int t = 0; t < 4; ++t) {
                double y = (dot[t] + bs) * inv + sh;
                double hh = v + (y - v) * 0.5;
                bool s = hh >= 1.0;
                u64* wp_ = &msk[((t * 8 + b) * 8 + h) * 512 + n];
                if (s) atomicOr(wp_, bit); else atomicAnd(wp_, ~bit);
                v = s ? 0.0 : hh;
            }
        }
    }
}

// ---------------------------------------------------------------------------
// Fused retention v2 (R15-proven).
__global__ __launch_bounds__(256) void ret_fused2(
    const u64* __restrict__ qm, const u64* __restrict__ km,
    const u64* __restrict__ vm, const double* __restrict__ pw,
    float* __restrict__ O)
{
    int bid = blockIdx.x;
    int tbh = bid >> 3;
    int n0 = (bid & 7) * 64;
    int h = tbh & 7;
    int tb = tbh >> 3;
    int tid = threadIdx.x;
    int wv = tid >> 6, lane = tid & 63, fr = lane & 15, fg = lane >> 4;
    int wn = wv * 16;

    __shared__ __bf16 Ks[64][72];
    __shared__ u64 VsTg[16][66];
    __shared__ u64 ShTg[4][16][17];
    __shared__ u64 SlTg[4][16][17];
    __shared__ u64 vmc[64];
    __shared__ float pwf[512];

    int base = tbh * 512;
    for (int i = tid; i < 512; i += 256) pwf[i] = (float)pw[h * 512 + i] * 0.125f;

    union U8 { u64 q[2]; bf16x8 v; };

    u64 qw = qm[base + n0 + wn + fr];
    bf16x8 qf[2];
    #pragma unroll
    for (int ks = 0; ks < 2; ++ks) {
        int e0 = ks * 32 + fg * 8;
        u64 plo = 0, phi = 0;
        #pragma unroll
        for (int e = 0; e < 4; ++e) {
            if ((qw >> (e0 + e)) & 1ull)     plo |= 0x3F80ull << (16 * e);
            if ((qw >> (e0 + 4 + e)) & 1ull) phi |= 0x3F80ull << (16 * e);
        }
        U8 u; u.q[0] = plo; u.q[1] = phi; qf[ks] = u.v;
    }

    f32x4 acc_o[4];
    #pragma unroll
    for (int j = 0; j < 4; ++j) acc_o[j] = (f32x4){0.f, 0.f, 0.f, 0.f};

    int nglob = n0 + wn + fr;

    for (int mc = 0; mc < 8; ++mc) {
        __syncthreads();
        {
            int row = tid >> 2, q4 = (tid & 3) * 16;
            u64 kw = km[base + mc * 64 + row];
            #pragma unroll
            for (int s = 0; s < 4; ++s) {
                int e0 = q4 + s * 4;
                u64 pk = 0;
                #pragma unroll
                for (int e = 0; e < 4; ++e)
                    if ((kw >> (e0 + e)) & 1ull) pk |= 0x3F80ull << (16 * e);
                *(u64*)&Ks[row][e0] = pk;
            }
        }
        if (tid < 64) vmc[tid] = vm[base + mc * 64 + tid];
        __syncthreads();
        {
            #pragma unroll
            for (int c = 0; c < 4; ++c) {
                int mg = wv * 4 + c;
                u64 pk = 0;
                #pragma unroll
                for (int e = 0; e < 4; ++e)
                    if ((vmc[mg * 4 + e] >> lane) & 1ull) pk |= 0x3F80ull << (16 * e);
                VsTg[mg][lane] = pk;
            }
        }
        f32x4 accs[4];
        #pragma unroll
        for (int j = 0; j < 4; ++j) accs[j] = (f32x4){0.f, 0.f, 0.f, 0.f};
        #pragma unroll
        for (int ks = 0; ks < 2; ++ks) {
            #pragma unroll
            for (int j = 0; j < 4; ++j) {
                bf16x8 ka = *(const bf16x8*)&Ks[j * 16 + fr][ks * 32 + fg * 8];
                accs[j] = __builtin_amdgcn_mfma_f32_16x16x32_bf16(ka, qf[ks], accs[j], 0, 0, 0);
            }
        }
        #pragma unroll
        for (int j = 0; j < 4; ++j) {
            u64 ph = 0, pl = 0;
            #pragma unroll
            for (int reg = 0; reg < 4; ++reg) {
                int m = mc * 64 + j * 16 + fg * 4 + reg;
                int dist = nglob - m; if (dist < 0) dist = -dist;
                float a = accs[j][reg] * pwf[dist];
                __bf16 hp = (__bf16)a;
                __bf16 lp = (__bf16)(a - (float)hp);
                ph |= (u64)__builtin_bit_cast(unsigned short, hp) << (16 * reg);
                pl |= (u64)__builtin_bit_cast(unsigned short, lp) << (16 * reg);
            }
            ShTg[wv][j * 4 + fg][fr] = ph;
            SlTg[wv][j * 4 + fg][fr] = pl;
        }
        __syncthreads();
        #pragma unroll
        for (int ks2 = 0; ks2 < 2; ++ks2) {
            int mga = ks2 * 8 + fg * 2;
            U8 ua, ul;
            ua.q[0] = ShTg[wv][mga][fr];  ua.q[1] = ShTg[wv][mga + 1][fr];
            ul.q[0] = SlTg[wv][mga][fr];  ul.q[1] = SlTg[wv][mga + 1][fr];
            #pragma unroll
            for (int j2 = 0; j2 < 4; ++j2) {
                U8 uv;
                uv.q[0] = VsTg[mga][j2 * 16 + fr];
                uv.q[1] = VsTg[mga + 1][j2 * 16 + fr];
                acc_o[j2] = __builtin_amdgcn_mfma_f32_16x16x32_bf16(ua.v, uv.v, acc_o[j2], 0, 0, 0);
                acc_o[j2] = __builtin_amdgcn_mfma_f32_16x16x32_bf16(ul.v, uv.v, acc_o[j2], 0, 0, 0);
            }
        }
    }

    #pragma unroll
    for (int j2 = 0; j2 < 4; ++j2) {
        int c = h * 64 + j2 * 16 + fr;
        #pragma unroll
        for (int reg = 0; reg < 4; ++reg) {
            int n = n0 + wn + fg * 4 + reg;
            O[((size_t)(tb * 512 + n) << 9) + c] = acc_o[j2][reg];
        }
    }
}

// ---------------------------------------------------------------------------
// Retention LIF: reads O (t,b,n,c); writes bf16 spikes in PERMUTED (bn,t)
// layout to Rb; relative-margin flag (slot 4).
__global__ void lif_ret_bf2(const float* __restrict__ Y, __bf16* __restrict__ Rb,
                            int* __restrict__ ctr, int* __restrict__ list) {
    int g = blockIdx.x * TPB + threadIdx.x;
    int c = g & 511, n = (g >> 9) & 511, b = g >> 18;
    size_t pbase = ((size_t)(b * 512 + n) * 4) * 512 + c;
    double v = 0.0, eb = 0.0;
    bool flag = false;
    for (int t = 0; t < 4; ++t) {
        size_t idx = ((size_t)((t * 8 + b) * 512 + n) << 9) + c;
        double x = (double)Y[idx];
        double hh = v + (x - v) * 0.5;
        eb = 0.5 * eb + 0.5 * (fabs(x) * 1e-4);
        flag |= fabs(hh - 0.5) <= eb + 1e-9;
        bool s = hh >= 0.5;
        Rb[pbase + (size_t)t * 512] = s ? (__bf16)1.0f : (__bf16)0.0f;
        v = s ? 0.0 : hh;
        if (s) eb = 0.0;
    }
    if (flag) {
        int i2 = atomicAdd(ctr + 4, 1);
        if (i2 < FCAP) list[i2] = g;
    }
}

// Exact fp64 repair of flagged retention neurons; writes permuted Rb.
__global__ void repair_ret_bf2(const u64* __restrict__ qm, const u64* __restrict__ km,
                               const u64* __restrict__ vm, const double* __restrict__ pw,
                               const int* __restrict__ ctr, const int* __restrict__ list,
                               __bf16* __restrict__ Rb) {
    int cnt = ctr[4]; if (cnt > FCAP) cnt = FCAP;
    int wv = (blockIdx.x * blockDim.x + threadIdx.x) >> 6;
    int nw = (gridDim.x * blockDim.x) >> 6;
    int lane = threadIdx.x & 63;
    for (int i = wv; i < cnt; i += nw) {
        int g = list[i];
        int c = g & 511, n = (g >> 9) & 511, b = g >> 18;
        int h = c >> 6, d = c & 63;
        double acc_t[4];
        for (int t = 0; t < 4; ++t) {
            int base = ((t * 8 + b) * 8 + h) * 512;
            u64 qw = qm[base + n];
            double p = 0.0;
            for (int j = 0; j < 8; ++j) {
                int m = j * 64 + lane;
                u64 kk = km[base + m];
                u64 vvm = vm[base + m];
                if ((vvm >> d) & 1ull) {
                    int dist = n - m; if (dist < 0) dist = -dist;
                    p += (double)__popcll(qw & kk) * pw[h * 512 + dist];
                }
            }
            acc_t[t] = p;
        }
        #pragma unroll
        for (int off = 32; off; off >>= 1) {
            #pragma unroll
            for (int t = 0; t < 4; ++t) acc_t[t] += __shfl_xor(acc_t[t], off, 64);
        }
        if (lane == 0) {
            double v = 0.0;
            size_t pbase = ((size_t)(b * 512 + n) * 4) * 512 + c;
            for (int t = 0; t < 4; ++t) {
                double x = acc_t[t] * 0.125;
                double hh = v + (x - v) * 0.5;
                bool s = hh >= 0.5;
                Rb[pbase + (size_t)t * 512] = s ? (__bf16)1.0f : (__bf16)0.0f;
                v = s ? 0.0 : hh;
            }
        }
    }
}

// ---------------------------------------------------------------------------
// Exact fp64 repair of flagged FINAL neurons; reads permuted Rb; writes d_out.
__global__ void fix_final_direct(const __bf16* __restrict__ rr, const float* __restrict__ w,
                                 const float* __restrict__ bias,
                                 const float* __restrict__ bnw, const float* __restrict__ bnb,
                                 const float* __restrict__ bnm, const float* __restrict__ bnv,
                                 const int* __restrict__ ctr, const int* __restrict__ list,
                                 float* __restrict__ out) {
    int cnt = ctr[3]; if (cnt > FCAP) cnt = FCAP;
    int wv = (blockIdx.x * blockDim.x + threadIdx.x) >> 6;
    int nw = (gridDim.x * blockDim.x) >> 6;
    int lane = threadIdx.x & 63;
    for (int i = wv; i < cnt; i += nw) {
        int g = list[i];
        int c = g & 511, n = (g >> 9) & 511, b = g >> 18;
        const float* wr = w + (size_t)c * 512;
        double dot[4];
        #pragma unroll
        for (int t = 0; t < 4; ++t) {
            const __bf16* xr = rr + ((size_t)(b * 512 + n) * 4 + t) * 512;
            double p = 0.0;
            #pragma unroll
            for (int j = 0; j < 8; ++j)
                p += (double)(float)xr[lane + 64 * j] * (double)wr[lane + 64 * j];
            dot[t] = p;
        }
        #pragma unroll
        for (int off = 32; off; off >>= 1) {
            #pragma unroll
            for (int t = 0; t < 4; ++t)
                dot[t] += __shfl_xor(dot[t], off, 64);
        }
        if (lane == 0) {
            double inv = (double)bnw[c] / sqrt((double)bnv[c] + 1e-5);
            double sh  = (double)bnb[c] - (double)bnm[c] * inv;
            double bs  = (double)bias[c];
            double v = 0.0;
            for (int t = 0; t < 4; ++t) {
                double y = (dot[t] + bs) * inv + sh;
                double hh = v + (y - v) * 0.5;
                bool s = hh >= 1.0;
                out[((size_t)((t * 8 + b) * 512 + n) << 9) + c] = s ? 1.0f : 0.0f;
                v = s ? 0.0 : hh;
            }
        }
    }
}

// ===========================================================================
// Fallback path kernels (R15-proven, used when ws is too small)
// ===========================================================================
__global__ __launch_bounds__(256) void gemm_bn_mfma(
    const float* __restrict__ A, const float* __restrict__ W,
    const float* __restrict__ bias,
    const float* __restrict__ bnw, const float* __restrict__ bnb,
    const float* __restrict__ bnm, const float* __restrict__ bnv,
    float* __restrict__ out)
{
    __shared__ __bf16 Ah[128][36];
    __shared__ __bf16 Al[128][36];
    __shared__ __bf16 Wh[64][36];
    __shared__ __bf16 Wl[64][36];

    const int tid = threadIdx.x;
    const int m0 = blockIdx.x * 128;
    const int d0 = blockIdx.y * 64;
    const int wv = tid >> 6;
    const int wm = wv >> 1;
    const int wd = wv & 1;
    const int lane = tid & 63;
    const int fr = lane & 15;
    const int fg = lane >> 4;
    const int srow = tid >> 3;
    const int scol = (tid & 7) * 4;

    f32x4 acc[4][2];
    #pragma unroll
    for (int i = 0; i < 4; ++i)
        #pragma unroll
        for (int j = 0; j < 2; ++j)
            acc[i][j] = (f32x4){0.f, 0.f, 0.f, 0.f};

    for (int k0 = 0; k0 < 512; k0 += 32) {
        __syncthreads();
        #pragma unroll
        for (int rep = 0; rep < 4; ++rep) {
            int row = srow + 32 * rep;
            float4 va = *(const float4*)(A + (size_t)(m0 + row) * 512 + k0 + scol);
            #pragma unroll
            for (int e = 0; e < 4; ++e) {
                float f = (&va.x)[e];
                __bf16 h = (__bf16)f;
                Ah[row][scol + e] = h;
                Al[row][scol + e] = (__bf16)(f - (float)h);
            }
        }
        #pragma unroll
        for (int rep = 0; rep < 2; ++rep) {
            int row = srow + 32 * rep;
            float4 vw = *(const float4*)(W + (size_t)(d0 + row) * 512 + k0 + scol);
            #pragma unroll
            for (int e = 0; e < 4; ++e) {
                float f = (&vw.x)[e];
                __bf16 h = (__bf16)f;
                Wh[row][scol + e] = h;
                Wl[row][scol + e] = (__bf16)(f - (float)h);
            }
        }
        __syncthreads();

        union FU { bf16x8 v8; struct { __bf16 a[4], b[4]; } s; };
        bf16x8 ah[4], al[4], bh[2], bl[2];
        #pragma unroll
        for (int i = 0; i < 4; ++i) {
            int row = wm * 64 + i * 16 + fr;
            FU u1, u2;
            *(double*)&u1.s.a[0] = *(const double*)&Ah[row][fg * 8];
            *(double*)&u1.s.b[0] = *(const double*)&Ah[row][fg * 8 + 4];
            *(double*)&u2.s.a[0] = *(const double*)&Al[row][fg * 8];
            *(double*)&u2.s.b[0] = *(const double*)&Al[row][fg * 8 + 4];
            ah[i] = u1.v8; al[i] = u2.v8;
        }
        #pragma unroll
        for (int j = 0; j < 2; ++j) {
            int row = wd * 32 + j * 16 + fr;
            FU u1, u2;
            *(double*)&u1.s.a[0] = *(const double*)&Wh[row][fg * 8];
            *(double*)&u1.s.b[0] = *(const double*)&Wh[row][fg * 8 + 4];
            *(double*)&u2.s.a[0] = *(const double*)&Wl[row][fg * 8];
            *(double*)&u2.s.b[0] = *(const double*)&Wl[row][fg * 8 + 4];
            bh[j] = u1.v8; bl[j] = u2.v8;
        }
        #pragma unroll
        for (int i = 0; i < 4; ++i)
            #pragma unroll
            for (int j = 0; j < 2; ++j) {
                acc[i][j] = __builtin_amdgcn_mfma_f32_16x16x32_bf16(ah[i], bh[j], acc[i][j], 0, 0, 0);
                acc[i][j] = __builtin_amdgcn_mfma_f32_16x16x32_bf16(ah[i], bl[j], acc[i][j], 0, 0, 0);
                acc[i][j] = __builtin_amdgcn_mfma_f32_16x16x32_bf16(al[i], bh[j], acc[i][j], 0, 0, 0);
            }
    }

    #pragma unroll
    for (int j = 0; j < 2; ++j) {
        int d = d0 + wd * 32 + j * 16 + fr;
        double inv = (double)bnw[d] / sqrt((double)bnv[d] + 1e-5);
        double sh  = (double)bnb[d] - (double)bnm[d] * inv;
        double bs  = (double)bias[d];
        #pragma unroll
        for (int i = 0; i < 4; ++i) {
            #pragma unroll
            for (int reg = 0; reg < 4; ++reg) {
                int m = m0 + wm * 64 + i * 16 + fg * 4 + reg;
                out[(size_t)m * 512 + d] = (float)(((double)acc[i][j][reg] + bs) * inv + sh);
            }
        }
    }
}

__global__ void lif_mask_flag(const float* __restrict__ Y, u64* __restrict__ msk,
                              int* __restrict__ ctr, int* __restrict__ list, int slot) {
    int g = blockIdx.x * TPB + threadIdx.x;
    int c = g & 511, n = (g >> 9) & 511, b = g >> 18;
    int h = c >> 6;
    int lane = threadIdx.x & 63;
    double v = 0.0;
    bool flag = false;
    for (int t = 0; t < 4; ++t) {
        float y = Y[((size_t)((t * 8 + b) * 512 + n) << 9) + c];
        double hh = v + ((double)y - v) * 0.5;
        flag |= fabs(hh - 1.0) < MARGIN;
        bool s = hh >= 1.0;
        u64 mk = __ballot(s);
        if (lane == 0) msk[((t * 8 + b) * 8 + h) * 512 + n] = mk;
        v = s ? 0.0 : hh;
    }
    if (flag) {
        int idx = atomicAdd(ctr + slot, 1);
        if (idx < FCAP) list[idx] = g;
    }
}

__global__ void lif_ret_f(const float* __restrict__ Y, float* __restrict__ R,
                          int* __restrict__ ctr, int* __restrict__ list) {
    int g = blockIdx.x * TPB + threadIdx.x;
    int c = g & 511, n = (g >> 9) & 511, b = g >> 18;
    double v = 0.0, eb = 0.0;
    bool flag = false;
    for (int t = 0; t < 4; ++t) {
        size_t idx = ((size_t)((t * 8 + b) * 512 + n) << 9) + c;
        double x = (double)Y[idx];
        double hh = v + (x - v) * 0.5;
        eb = 0.5 * eb + 0.5 * (fabs(x) * 1e-4);
        flag |= fabs(hh - 0.5) <= eb + 1e-9;
        bool s = hh >= 0.5;
        R[idx] = s ? 1.0f : 0.0f;
        v = s ? 0.0 : hh;
        if (s) eb = 0.0;
    }
    if (flag) {
        int i2 = atomicAdd(ctr + 4, 1);
        if (i2 < FCAP) list[i2] = g;
    }
}

__global__ void repair_ret_f(const u64* __restrict__ qm, const u64* __restrict__ km,
                             const u64* __restrict__ vm, const double* __restrict__ pw,
                             const int* __restrict__ ctr, const int* __restrict__ list,
                             float* __restrict__ r) {
    int cnt = ctr[4]; if (cnt > FCAP) cnt = FCAP;
    int wv = (blockIdx.x * blockDim.x + threadIdx.x) >> 6;
    int nw = (gridDim.x * blockDim.x) >> 6;
    int lane = threadIdx.x & 63;
    for (int i = wv; i < cnt; i += nw) {
        int g = list[i];
        int c = g & 511, n = (g >> 9) & 511, b = g >> 18;
        int h = c >> 6, d = c & 63;
        double acc_t[4];
        for (int t = 0; t < 4; ++t) {
            int base = ((t * 8 + b) * 8 + h) * 512;
            u64 qw = qm[base + n];
            double p = 0.0;
            for (int j = 0; j < 8; ++j) {
                int m = j * 64 + lane;
                u64 kk = km[base + m];
                u64 vvm = vm[base + m];
                if ((vvm >> d) & 1ull) {
                    int dist = n - m; if (dist < 0) dist = -dist;
                    p += (double)__popcll(qw & kk) * pw[h * 512 + dist];
                }
            }
            acc_t[t] = p;
        }
        #pragma unroll
        for (int off = 32; off; off >>= 1) {
            #pragma unroll
            for (int t = 0; t < 4; ++t) acc_t[t] += __shfl_xor(acc_t[t], off, 64);
        }
        if (lane == 0) {
            double v = 0.0;
            for (int t = 0; t < 4; ++t) {
                double x = acc_t[t] * 0.125;
                double hh = v + (x - v) * 0.5;
                bool s = hh >= 0.5;
                r[((size_t)((t * 8 + b) * 512 + n) << 9) + c] = s ? 1.0f : 0.0f;
                v = s ? 0.0 : hh;
            }
        }
    }
}

__global__ void final_flag(const float* __restrict__ Y, int* __restrict__ ctr,
                           int* __restrict__ list) {
    int g = blockIdx.x * TPB + threadIdx.x;
    int c = g & 511, n = (g >> 9) & 511, b = g >> 18;
    double v = 0.0;
    bool flag = false;
    for (int t = 0; t < 4; ++t) {
        float y = Y[((size_t)((t * 8 + b) * 512 + n) << 9) + c];
        double hh = v + ((double)y - v) * 0.5;
        flag |= fabs(hh - 1.0) < MARGIN;
        bool s = hh >= 1.0;
        v = s ? 0.0 : hh;
    }
    if (flag) {
        int idx = atomicAdd(ctr + 3, 1);
        if (idx < FCAP) list[idx] = g;
    }
}

__global__ void fix_final_f(const float* __restrict__ rr, const float* __restrict__ w,
                            const float* __restrict__ bias,
                            const float* __restrict__ bnw, const float* __restrict__ bnb,
                            const float* __restrict__ bnm, const float* __restrict__ bnv,
                            const int* __restrict__ ctr, int* __restrict__ list) {
    int cnt = ctr[3]; if (cnt > FCAP) cnt = FCAP;
    int wv = (blockIdx.x * blockDim.x + threadIdx.x) >> 6;
    int nw = (gridDim.x * blockDim.x) >> 6;
    int lane = threadIdx.x & 63;
    for (int i = wv; i < cnt; i += nw) {
        int g = list[i] & 0x00FFFFFF;
        int c = g & 511, n = (g >> 9) & 511, b = g >> 18;
        const float* wr = w + (size_t)c * 512;
        double dot[4];
        #pragma unroll
        for (int t = 0; t < 4; ++t) {
            const float* xr = rr + ((size_t)((t * 8 + b) * 512 + n) << 9);
            double p = 0.0;
            #pragma unroll
            for (int j = 0; j < 8; ++j)
                p += (double)xr[lane + 64 * j] * (double)wr[lane + 64 * j];
            dot[t] = p;
        }
        #pragma unroll
        for (int off = 32; off; off >>= 1) {
            #pragma unroll
            for (int t = 0; t < 4; ++t)
                dot[t] += __shfl_xor(dot[t], off, 64);
        }
        if (lane == 0) {
            double inv = (double)bnw[c] / sqrt((double)bnv[c] + 1e-5);
            double sh  = (double)bnb[c] - (double)bnm[c] * inv;
            double bs  = (double)bias[c];
            double v = 0.0;
            int sp = 0;
            for (int t = 0; t < 4; ++t) {
                double y = (dot[t] + bs) * inv + sh;
                double hh = v + (y - v) * 0.5;
                bool s = hh >= 1.0;
                sp |= (s ? 1 : 0) << t;
                v = s ? 0.0 : hh;
            }
            list[i] = g | (sp << 24);
        }
    }
}

__global__ void final_write(const float* __restrict__ Y, float* __restrict__ out) {
    int g = blockIdx.x * TPB + threadIdx.x;
    int c = g & 511, n = (g >> 9) & 511, b = g >> 18;
    double v = 0.0;
    for (int t = 0; t < 4; ++t) {
        size_t idx = ((size_t)((t * 8 + b) * 512 + n) << 9) + c;
        float y = Y[idx];
        double hh = v + ((double)y - v) * 0.5;
        bool s = hh >= 1.0;
        out[idx] = s ? 1.0f : 0.0f;
        v = s ? 0.0 : hh;
    }
}

__global__ void fix_scatter(const int* __restrict__ ctr, const int* __restrict__ list,
                            float* __restrict__ out) {
    int cnt = ctr[3]; if (cnt > FCAP) cnt = FCAP;
    int i = blockIdx.x * blockDim.x + threadIdx.x;
    if (i >= cnt) return;
    int e = list[i];
    int g = e & 0x00FFFFFF, sp = (e >> 24) & 0xF;
    int c = g & 511, n = (g >> 9) & 511, b = g >> 18;
    for (int t = 0; t < 4; ++t)
        out[((size_t)((t * 8 + b) * 512 + n) << 9) + c] = ((sp >> t) & 1) ? 1.0f : 0.0f;
}

// ---------------------------------------------------------------------------
extern "C" void kernel_launch(void* const* d_in, const int* in_sizes, int n_in,
                              void* d_out, int out_size, void* d_ws, size_t ws_size,
                              hipStream_t stream) {
    const float* x = (const float*)d_in[0];
    const float *w[4], *bi[4], *bnw[4], *bnb[4], *bnm[4], *bnv[4];
    for (int br = 0; br < 4; ++br) {
        int base = 1 + br * 6;
        w[br]   = (const float*)d_in[base + 0];
        bi[br]  = (const float*)d_in[base + 1];
        bnw[br] = (const float*)d_in[base + 2];
        bnb[br] = (const float*)d_in[base + 3];
        bnm[br] = (const float*)d_in[base + 4];
        bnv[br] = (const float*)d_in[base + 5];
    }

    const size_t NX = (size_t)16384 * 512;
    char* p = (char*)d_ws;
    double* pw = (double*)p;  p += 8 * 512 * sizeof(double);
    u64* qm = (u64*)p;        p += 131072 * sizeof(u64);
    u64* km = (u64*)p;        p += 131072 * sizeof(u64);
    u64* vm = (u64*)p;        p += 131072 * sizeof(u64);
    int* ctr = (int*)p;       p += 1024;
    int* list = (int*)p;      p += (size_t)FCAP * sizeof(int);
    float* Y = (float*)p;     p += NX * 4;
    __bf16* Xh = (__bf16*)p;  p += NX * 2;
    __bf16* Xl = (__bf16*)p;  p += NX * 2;
    __bf16* Wsp = (__bf16*)p; p += (size_t)4 * 2 * 262144 * 2;
    size_t need_fast = (size_t)(p - (char*)d_ws);
    int fast = ws_size >= need_fast;

    init_kernel<<<1, 64, 0, stream>>>(pw, ctr);

    dim3 g2(128, 4);
    dim3 gg(128, 8);

    if (fast) {
        split_all<<<8192 + 1024, 256, 0, stream>>>(x, w[0], w[1], w[2], w[3], Xh, Xl, Wsp);
        for (int br = 0; br < 3; ++br) {
            u64* msk = br == 0 ? qm : (br == 1 ? km : vm);
            gemm_lif_mask<<<g2, 256, 0, stream>>>(Xh, Xl,
                Wsp + (size_t)br * 524288, Wsp + (size_t)br * 524288 + 262144,
                bi[br], bnw[br], bnb[br], bnm[br], bnv[br], msk, ctr, list, br);
            fix_mask<<<128, 256, 0, stream>>>(x, w[br], bi[br], bnw[br], bnb[br],
                                              bnm[br], bnv[br], msk, ctr, list, br);
        }
        // retention -> Y; LIF -> bf16 spikes (permuted) in Xh; exact repair
        ret_fused2<<<2048, 256, 0, stream>>>(qm, km, vm, pw, Y);
        lif_ret_bf2<<<8192, TPB, 0, stream>>>(Y, Xh, ctr, list);
        repair_ret_bf2<<<256, 256, 0, stream>>>(qm, km, vm, pw, ctr, list, Xh);
        // p projection + fused final LIF -> d_out; exact repair direct
        gemm_final_lif<<<g2, 256, 0, stream>>>(Xh,
            Wsp + (size_t)3 * 524288, Wsp + (size_t)3 * 524288 + 262144,
            bi[3], bnw[3], bnb[3], bnm[3], bnv[3], (float*)d_out, ctr, list);
        fix_final_direct<<<128, 256, 0, stream>>>(Xh, w[3], bi[3], bnw[3], bnb[3],
                                                  bnm[3], bnv[3], ctr, list, (float*)d_out);
    } else {
        for (int br = 0; br < 3; ++br) {
            u64* msk = br == 0 ? qm : (br == 1 ? km : vm);
            gemm_bn_mfma<<<gg, 256, 0, stream>>>(x, w[br], bi[br], bnw[br], bnb[br],
                                                 bnm[br], bnv[br], Y);
            lif_mask_flag<<<8192, TPB, 0, stream>>>(Y, msk, ctr, list, br);
            fix_mask<<<128, 256, 0, stream>>>(x, w[br], bi[br], bnw[br], bnb[br],
                                              bnm[br], bnv[br], msk, ctr, list, br);
        }
        float* r = (float*)d_out;
        ret_fused2<<<2048, 256, 0, stream>>>(qm, km, vm, pw, Y);
        lif_ret_f<<<8192, TPB, 0, stream>>>(Y, r, ctr, list);
        repair_ret_f<<<256, 256, 0, stream>>>(qm, km, vm, pw, ctr, list, r);
        gemm_bn_mfma<<<gg, 256, 0, stream>>>(r, w[3], bi[3], bnw[3], bnb[3],
                                             bnm[3], bnv[3], Y);
        final_flag<<<8192, TPB, 0, stream>>>(Y, ctr, list);
        fix_final_f<<<128, 256, 0, stream>>>(r, w[3], bi[3], bnw[3], bnb[3],
                                             bnm[3], bnv[3], ctr, list);
        final_write<<<8192, TPB, 0, stream>>>(Y, (float*)d_out);
        fix_scatter<<<4096, 256, 0, stream>>>(ctr, list, (float*)d_out);
    }
}

// Round 17
// 277.379 us; speedup vs baseline: 1.3209x; 1.0186x over previous
//
#include <hip/hip_runtime.h>
#include <cstdint>

typedef unsigned long long u64;

#define TPB 256
#define MARGIN 5e-4
#define FCAP (1 << 20)

typedef __bf16 bf16x8 __attribute__((ext_vector_type(8)));
typedef __bf16 bf16x4 __attribute__((ext_vector_type(4)));
typedef float f32x4 __attribute__((ext_vector_type(4)));

typedef __attribute__((address_space(1))) void GV;
typedef __attribute__((address_space(3))) void LV;
typedef __attribute__((address_space(3))) char LC;

#define GLD(gsrc, ldst) __builtin_amdgcn_global_load_lds( \
    (GV*)(void*)(gsrc), (LV*)(ldst), 16, 0, 0)

// ---------------------------------------------------------------------------
__global__ void init_kernel(double* __restrict__ pw, int* __restrict__ ctr) {
    int h = threadIdx.x;
    if (h < 8) {
        double gamma = 1.0 - ldexp(1.0, -5 - h);
        double p = 1.0;
        for (int i = 0; i < 512; ++i) { pw[h * 512 + i] = p; p *= gamma; }
        ctr[h] = 0;
    }
}

// ---------------------------------------------------------------------------
// Combined split. x rows PERMUTED to m' = (b*512+n)*4 + t (reg index == t).
__global__ void split_all(const float* __restrict__ x,
                          const float* __restrict__ w0, const float* __restrict__ w1,
                          const float* __restrict__ w2, const float* __restrict__ w3,
                          __bf16* __restrict__ Xh, __bf16* __restrict__ Xl,
                          __bf16* __restrict__ Wsp) {
    int blk = blockIdx.x;
    if (blk < 8192) {
        size_t i = (size_t)blk * 1024 + threadIdx.x * 4;
        int m = (int)(i >> 9), c = (int)(i & 511);
        int mp = (m & 4095) * 4 + (m >> 12);
        float4 v = *(const float4*)(x + i);
        bf16x4 h4, l4;
        #pragma unroll
        for (int e = 0; e < 4; ++e) {
            float f = (&v.x)[e];
            __bf16 hh = (__bf16)f;
            h4[e] = hh;
            l4[e] = (__bf16)(f - (float)hh);
        }
        size_t dst = (size_t)mp * 512 + c;
        *(bf16x4*)(Xh + dst) = h4;
        *(bf16x4*)(Xl + dst) = l4;
    } else {
        int wb = blk - 8192;
        int br = wb >> 8;
        const float* ws[4] = {w0, w1, w2, w3};
        const float* src = ws[br];
        __bf16* hi = Wsp + (size_t)br * 524288;
        __bf16* lo = hi + 262144;
        size_t i = (size_t)(wb & 255) * 1024 + threadIdx.x * 4;
        float4 v = *(const float4*)(src + i);
        bf16x4 h4, l4;
        #pragma unroll
        for (int e = 0; e < 4; ++e) {
            float f = (&v.x)[e];
            __bf16 hh = (__bf16)f;
            h4[e] = hh;
            l4[e] = (__bf16)(f - (float)hh);
        }
        *(bf16x4*)(hi + i) = h4;
        *(bf16x4*)(lo + i) = l4;
    }
}

// ---------------------------------------------------------------------------
// Branch GEMM (3-pass) via global_load_lds staging (linear LDS, source-swizzle
// col16' = col16 ^ ((row>>1)&3)) + fused BN/LIF/mask epilogue.
__global__ __launch_bounds__(256) void gemm_lif_mask(
    const __bf16* __restrict__ Ahg, const __bf16* __restrict__ Alg,
    const __bf16* __restrict__ Whg, const __bf16* __restrict__ Wlg,
    const float* __restrict__ bias,
    const float* __restrict__ bnw, const float* __restrict__ bnb,
    const float* __restrict__ bnm, const float* __restrict__ bnv,
    u64* __restrict__ msk, int* __restrict__ ctr, int* __restrict__ list, int slot)
{
    __shared__ __bf16 AhS[128][32];
    __shared__ __bf16 AlS[128][32];
    __shared__ __bf16 WhS[128][32];
    __shared__ __bf16 WlS[128][32];

    const int tid = threadIdx.x;
    const int m0 = blockIdx.x * 128;
    const int d0 = blockIdx.y * 128;
    const int wv = tid >> 6;
    const int wm = wv >> 1;
    const int wd = wv & 1;
    const int lane = tid & 63;
    const int fr = lane & 15;
    const int fg = lane >> 4;

    // gload source addressing (per-lane, constant across k0)
    const int lr   = lane >> 2;                      // row within 16-row chunk
    const int csrc = (lane & 3) ^ ((lane >> 3) & 3); // swizzled col16 source
    const int rA0  = wv * 32 + lr;                   // chunk q=0 row
    const __bf16* gAh0 = Ahg + (size_t)(m0 + rA0) * 512 + csrc * 8;
    const __bf16* gAh1 = gAh0 + (size_t)16 * 512;
    const __bf16* gAl0 = Alg + (size_t)(m0 + rA0) * 512 + csrc * 8;
    const __bf16* gAl1 = gAl0 + (size_t)16 * 512;
    const __bf16* gWh0 = Whg + (size_t)(d0 + rA0) * 512 + csrc * 8;
    const __bf16* gWh1 = gWh0 + (size_t)16 * 512;
    const __bf16* gWl0 = Wlg + (size_t)(d0 + rA0) * 512 + csrc * 8;
    const __bf16* gWl1 = gWl0 + (size_t)16 * 512;

    unsigned ldsOff = __builtin_amdgcn_readfirstlane((unsigned)(wv * 2048));
    LC* lAh = (LC*)(LV*)&AhS[0][0] + ldsOff;
    LC* lAl = (LC*)(LV*)&AlS[0][0] + ldsOff;
    LC* lWh = (LC*)(LV*)&WhS[0][0] + ldsOff;
    LC* lWl = (LC*)(LV*)&WlS[0][0] + ldsOff;

    // frag read byte offset within row (swizzled), constant per lane
    const int fcol = (fg ^ ((fr >> 1) & 3)) * 16;

    f32x4 acc[4][4];
    #pragma unroll
    for (int i = 0; i < 4; ++i)
        #pragma unroll
        for (int j = 0; j < 4; ++j)
            acc[i][j] = (f32x4){0.f, 0.f, 0.f, 0.f};

    for (int k0 = 0; k0 < 512; k0 += 32) {
        __syncthreads();
        GLD(gAh0 + k0, lAh); GLD(gAh1 + k0, lAh + 1024);
        GLD(gAl0 + k0, lAl); GLD(gAl1 + k0, lAl + 1024);
        GLD(gWh0 + k0, lWh); GLD(gWh1 + k0, lWh + 1024);
        GLD(gWl0 + k0, lWl); GLD(gWl1 + k0, lWl + 1024);
        __syncthreads();

        bf16x8 ah[4], bh[4], bl[4];
        #pragma unroll
        for (int i = 0; i < 4; ++i) {
            int row = wm * 64 + i * 16 + fr;
            ah[i] = *(const bf16x8*)((const char*)&AhS[0][0] + row * 64 + fcol);
        }
        #pragma unroll
        for (int j = 0; j < 4; ++j) {
            int row = wd * 64 + j * 16 + fr;
            bh[j] = *(const bf16x8*)((const char*)&WhS[0][0] + row * 64 + fcol);
            bl[j] = *(const bf16x8*)((const char*)&WlS[0][0] + row * 64 + fcol);
        }
        #pragma unroll
        for (int i = 0; i < 4; ++i)
            #pragma unroll
            for (int j = 0; j < 4; ++j) {
                acc[i][j] = __builtin_amdgcn_mfma_f32_16x16x32_bf16(ah[i], bh[j], acc[i][j], 0, 0, 0);
                acc[i][j] = __builtin_amdgcn_mfma_f32_16x16x32_bf16(ah[i], bl[j], acc[i][j], 0, 0, 0);
            }
        bf16x8 al[4];
        #pragma unroll
        for (int i = 0; i < 4; ++i) {
            int row = wm * 64 + i * 16 + fr;
            al[i] = *(const bf16x8*)((const char*)&AlS[0][0] + row * 64 + fcol);
        }
        #pragma unroll
        for (int i = 0; i < 4; ++i)
            #pragma unroll
            for (int j = 0; j < 4; ++j)
                acc[i][j] = __builtin_amdgcn_mfma_f32_16x16x32_bf16(al[i], bh[j], acc[i][j], 0, 0, 0);
    }

    // ---- epilogue: BN + LIF(1.0) + mask ballots + margin flags (R16-proven)
    double invj[4], shj[4], bsj[4];
    #pragma unroll
    for (int j = 0; j < 4; ++j) {
        int d = d0 + wd * 64 + j * 16 + fr;
        invj[j] = (double)bnw[d] / sqrt((double)bnv[d] + 1e-5);
        shj[j]  = (double)bnb[d] - (double)bnm[d] * invj[j];
        bsj[j]  = (double)bias[d];
    }
    int hword = (d0 >> 6) + wd;
    int bn0 = blockIdx.x * 32 + wm * 16;

    #pragma unroll
    for (int i = 0; i < 4; ++i) {
        int bn = bn0 + i * 4 + fg;
        int b = bn >> 9, n = bn & 511;
        u64 w[4] = {0ull, 0ull, 0ull, 0ull};
        #pragma unroll
        for (int j = 0; j < 4; ++j) {
            double v = 0.0;
            bool fl = false;
            #pragma unroll
            for (int t = 0; t < 4; ++t) {
                double y = ((double)acc[i][j][t] + bsj[j]) * invj[j] + shj[j];
                double hh = v + (y - v) * 0.5;
                fl |= fabs(hh - 1.0) < MARGIN;
                bool s = hh >= 1.0;
                u64 blt = __ballot(s);
                w[t] |= ((blt >> (fg * 16)) & 0xFFFFull) << (j * 16);
                v = s ? 0.0 : hh;
            }
            if (fl) {
                int d = d0 + wd * 64 + j * 16 + fr;
                int idx = atomicAdd(ctr + slot, 1);
                if (idx < FCAP) list[idx] = (b << 18) | (n << 9) | d;
            }
        }
        if (fr == 0) {
            #pragma unroll
            for (int t = 0; t < 4; ++t)
                msk[((t * 8 + b) * 8 + hword) * 512 + n] = w[t];
        }
    }
}

// ---------------------------------------------------------------------------
// Final GEMM (2-pass, A exact) via global_load_lds + fused final LIF -> out.
__global__ __launch_bounds__(256) void gemm_final_lif(
    const __bf16* __restrict__ Ahg,
    const __bf16* __restrict__ Whg, const __bf16* __restrict__ Wlg,
    const float* __restrict__ bias,
    const float* __restrict__ bnw, const float* __restrict__ bnb,
    const float* __restrict__ bnm, const float* __restrict__ bnv,
    float* __restrict__ out, int* __restrict__ ctr, int* __restrict__ list)
{
    __shared__ __bf16 AhS[128][32];
    __shared__ __bf16 WhS[128][32];
    __shared__ __bf16 WlS[128][32];

    const int tid = threadIdx.x;
    const int m0 = blockIdx.x * 128;
    const int d0 = blockIdx.y * 128;
    const int wv = tid >> 6;
    const int wm = wv >> 1;
    const int wd = wv & 1;
    const int lane = tid & 63;
    const int fr = lane & 15;
    const int fg = lane >> 4;

    const int lr   = lane >> 2;
    const int csrc = (lane & 3) ^ ((lane >> 3) & 3);
    const int rA0  = wv * 32 + lr;
    const __bf16* gAh0 = Ahg + (size_t)(m0 + rA0) * 512 + csrc * 8;
    const __bf16* gAh1 = gAh0 + (size_t)16 * 512;
    const __bf16* gWh0 = Whg + (size_t)(d0 + rA0) * 512 + csrc * 8;
    const __bf16* gWh1 = gWh0 + (size_t)16 * 512;
    const __bf16* gWl0 = Wlg + (size_t)(d0 + rA0) * 512 + csrc * 8;
    const __bf16* gWl1 = gWl0 + (size_t)16 * 512;

    unsigned ldsOff = __builtin_amdgcn_readfirstlane((unsigned)(wv * 2048));
    LC* lAh = (LC*)(LV*)&AhS[0][0] + ldsOff;
    LC* lWh = (LC*)(LV*)&WhS[0][0] + ldsOff;
    LC* lWl = (LC*)(LV*)&WlS[0][0] + ldsOff;

    const int fcol = (fg ^ ((fr >> 1) & 3)) * 16;

    f32x4 acc[4][4];
    #pragma unroll
    for (int i = 0; i < 4; ++i)
        #pragma unroll
        for (int j = 0; j < 4; ++j)
            acc[i][j] = (f32x4){0.f, 0.f, 0.f, 0.f};

    for (int k0 = 0; k0 < 512; k0 += 32) {
        __syncthreads();
        GLD(gAh0 + k0, lAh); GLD(gAh1 + k0, lAh + 1024);
        GLD(gWh0 + k0, lWh); GLD(gWh1 + k0, lWh + 1024);
        GLD(gWl0 + k0, lWl); GLD(gWl1 + k0, lWl + 1024);
        __syncthreads();

        bf16x8 ah[4], bh[4], bl[4];
        #pragma unroll
        for (int i = 0; i < 4; ++i) {
            int row = wm * 64 + i * 16 + fr;
            ah[i] = *(const bf16x8*)((const char*)&AhS[0][0] + row * 64 + fcol);
        }
        #pragma unroll
        for (int j = 0; j < 4; ++j) {
            int row = wd * 64 + j * 16 + fr;
            bh[j] = *(const bf16x8*)((const char*)&WhS[0][0] + row * 64 + fcol);
            bl[j] = *(const bf16x8*)((const char*)&WlS[0][0] + row * 64 + fcol);
        }
        #pragma unroll
        for (int i = 0; i < 4; ++i)
            #pragma unroll
            for (int j = 0; j < 4; ++j) {
                acc[i][j] = __builtin_amdgcn_mfma_f32_16x16x32_bf16(ah[i], bh[j], acc[i][j], 0, 0, 0);
                acc[i][j] = __builtin_amdgcn_mfma_f32_16x16x32_bf16(ah[i], bl[j], acc[i][j], 0, 0, 0);
            }
    }

    double invj[4], shj[4], bsj[4];
    #pragma unroll
    for (int j = 0; j < 4; ++j) {
        int d = d0 + wd * 64 + j * 16 + fr;
        invj[j] = (double)bnw[d] / sqrt((double)bnv[d] + 1e-5);
        shj[j]  = (double)bnb[d] - (double)bnm[d] * invj[j];
        bsj[j]  = (double)bias[d];
    }
    int bn0 = blockIdx.x * 32 + wm * 16;

    #pragma unroll
    for (int i = 0; i < 4; ++i) {
        int bn = bn0 + i * 4 + fg;
        int b = bn >> 9, n = bn & 511;
        #pragma unroll
        for (int j = 0; j < 4; ++j) {
            int d = d0 + wd * 64 + j * 16 + fr;
            double v = 0.0;
            bool fl = false;
            #pragma unroll
            for (int t = 0; t < 4; ++t) {
                double y = ((double)acc[i][j][t] + bsj[j]) * invj[j] + shj[j];
                double hh = v + (y - v) * 0.5;
                fl |= fabs(hh - 1.0) < MARGIN;
                bool s = hh >= 1.0;
                out[((size_t)((t * 8 + b) * 512 + n) << 9) + d] = s ? 1.0f : 0.0f;
                v = s ? 0.0 : hh;
            }
            if (fl) {
                int idx = atomicAdd(ctr + 3, 1);
                if (idx < FCAP) list[idx] = (b << 18) | (n << 9) | d;
            }
        }
    }
}

// ---------------------------------------------------------------------------
// Exact fp64 repair of flagged branch neurons (reads original x layout).
__global__ void fix_mask(const float* __restrict__ x, const float* __restrict__ w,
                         const float* __restrict__ bias,
                         const float* __restrict__ bnw, const float* __restrict__ bnb,
                         const float* __restrict__ bnm, const float* __restrict__ bnv,
                         u64* __restrict__ msk, const int* __restrict__ ctr,
                         const int* __restrict__ list, int slot) {
    int cnt = ctr[slot]; if (cnt > FCAP) cnt = FCAP;
    int wv = (blockIdx.x * blockDim.x + threadIdx.x) >> 6;
    int nw = (gridDim.x * blockDim.x) >> 6;
    int lane = threadIdx.x & 63;
    for (int i = wv; i < cnt; i += nw) {
        int g = list[i];
        int c = g & 511, n = (g >> 9) & 511, b = g >> 18;
        int h = c >> 6;
        const float* wr = w + (size_t)c * 512;
        double dot[4];
        #pragma unroll
        for (int t = 0; t < 4; ++t) {
            const float* xr = x + ((size_t)((t * 8 + b) * 512 + n) << 9);
            double p = 0.0;
            #pragma unroll
            for (int j = 0; j < 8; ++j)
                p += (double)xr[lane + 64 * j] * (double)wr[lane + 64 * j];
            dot[t] = p;
        }
        #pragma unroll
        for (int off = 32; off; off >>= 1) {
            #pragma unroll
            for (int t = 0; t < 4; ++t)
                dot[t] += __shfl_xor(dot[t], off, 64);
        }
        if (lane == 0) {
            double inv = (double)bnw[c] / sqrt((double)bnv[c] + 1e-5);
            double sh  = (double)bnb[c] - (double)bnm[c] * inv;
            double bs  = (double)bias[c];
            double v = 0.0;
            u64 bit = 1ull << (c & 63);
            for (int t = 0; t < 4; ++t) {
                double y = (dot[t] + bs) * inv + sh;
                double hh = v + (y - v) * 0.5;
                bool s = hh >= 1.0;
                u64* wp_ = &msk[((t * 8 + b) * 8 + h) * 512 + n];
                if (s) atomicOr(wp_, bit); else atomicAnd(wp_, ~bit);
                v = s ? 0.0 : hh;
            }
        }
    }
}

// ---------------------------------------------------------------------------
// Fused retention v2 (R15-proven) with truncation-based S-split.
__global__ __launch_bounds__(256) void ret_fused2(
    const u64* __restrict__ qm, const u64* __restrict__ km,
    const u64* __restrict__ vm, const double* __restrict__ pw,
    float* __restrict__ O)
{
    int bid = blockIdx.x;
    int tbh = bid >> 3;
    int n0 = (bid & 7) * 64;
    int h = tbh & 7;
    int tb = tbh >> 3;
    int tid = threadIdx.x;
    int wv = tid >> 6, lane = tid & 63, fr = lane & 15, fg = lane >> 4;
    int wn = wv * 16;

    __shared__ __bf16 Ks[64][72];
    __shared__ u64 VsTg[16][66];
    __shared__ u64 ShTg[4][16][17];
    __shared__ u64 SlTg[4][16][17];
    __shared__ u64 vmc[64];
    __shared__ float pwf[512];

    int base = tbh * 512;
    for (int i = tid; i < 512; i += 256) pwf[i] = (float)pw[h * 512 + i] * 0.125f;

    union U8 { u64 q[2]; bf16x8 v; };

    u64 qw = qm[base + n0 + wn + fr];
    bf16x8 qf[2];
    #pragma unroll
    for (int ks = 0; ks < 2; ++ks) {
        int e0 = ks * 32 + fg * 8;
        u64 plo = 0, phi = 0;
        #pragma unroll
        for (int e = 0; e < 4; ++e) {
            if ((qw >> (e0 + e)) & 1ull)     plo |= 0x3F80ull << (16 * e);
            if ((qw >> (e0 + 4 + e)) & 1ull) phi |= 0x3F80ull << (16 * e);
        }
        U8 u; u.q[0] = plo; u.q[1] = phi; qf[ks] = u.v;
    }

    f32x4 acc_o[4];
    #pragma unroll
    for (int j = 0; j < 4; ++j) acc_o[j] = (f32x4){0.f, 0.f, 0.f, 0.f};

    int nglob = n0 + wn + fr;

    for (int mc = 0; mc < 8; ++mc) {
        __syncthreads();
        {
            int row = tid >> 2, q4 = (tid & 3) * 16;
            u64 kw = km[base + mc * 64 + row];
            #pragma unroll
            for (int s = 0; s < 4; ++s) {
                int e0 = q4 + s * 4;
                u64 pk = 0;
                #pragma unroll
                for (int e = 0; e < 4; ++e)
                    if ((kw >> (e0 + e)) & 1ull) pk |= 0x3F80ull << (16 * e);
                *(u64*)&Ks[row][e0] = pk;
            }
        }
        if (tid < 64) vmc[tid] = vm[base + mc * 64 + tid];
        __syncthreads();
        {
            #pragma unroll
            for (int c = 0; c < 4; ++c) {
                int mg = wv * 4 + c;
                u64 pk = 0;
                #pragma unroll
                for (int e = 0; e < 4; ++e)
                    if ((vmc[mg * 4 + e] >> lane) & 1ull) pk |= 0x3F80ull << (16 * e);
                VsTg[mg][lane] = pk;
            }
        }
        f32x4 accs[4];
        #pragma unroll
        for (int j = 0; j < 4; ++j) accs[j] = (f32x4){0.f, 0.f, 0.f, 0.f};
        #pragma unroll
        for (int ks = 0; ks < 2; ++ks) {
            #pragma unroll
            for (int j = 0; j < 4; ++j) {
                bf16x8 ka = *(const bf16x8*)&Ks[j * 16 + fr][ks * 32 + fg * 8];
                accs[j] = __builtin_amdgcn_mfma_f32_16x16x32_bf16(ka, qf[ks], accs[j], 0, 0, 0);
            }
        }
        // scale + truncation split + pack
        #pragma unroll
        for (int j = 0; j < 4; ++j) {
            u64 ph = 0, pl = 0;
            #pragma unroll
            for (int reg = 0; reg < 4; ++reg) {
                int m = mc * 64 + j * 16 + fg * 4 + reg;
                int dist = nglob - m; if (dist < 0) dist = -dist;
                float a = accs[j][reg] * pwf[dist];
                unsigned ab = __builtin_bit_cast(unsigned, a);
                unsigned hb = ab & 0xFFFF0000u;
                float lp = a - __builtin_bit_cast(float, hb);
                __bf16 lpb = (__bf16)lp;
                ph |= (u64)(ab >> 16) << (16 * reg);
                pl |= (u64)__builtin_bit_cast(unsigned short, lpb) << (16 * reg);
            }
            ShTg[wv][j * 4 + fg][fr] = ph;
            SlTg[wv][j * 4 + fg][fr] = pl;
        }
        __syncthreads();
        #pragma unroll
        for (int ks2 = 0; ks2 < 2; ++ks2) {
            int mga = ks2 * 8 + fg * 2;
            U8 ua, ul;
            ua.q[0] = ShTg[wv][mga][fr];  ua.q[1] = ShTg[wv][mga + 1][fr];
            ul.q[0] = SlTg[wv][mga][fr];  ul.q[1] = SlTg[wv][mga + 1][fr];
            #pragma unroll
            for (int j2 = 0; j2 < 4; ++j2) {
                U8 uv;
                uv.q[0] = VsTg[mga][j2 * 16 + fr];
                uv.q[1] = VsTg[mga + 1][j2 * 16 + fr];
                acc_o[j2] = __builtin_amdgcn_mfma_f32_16x16x32_bf16(ua.v, uv.v, acc_o[j2], 0, 0, 0);
                acc_o[j2] = __builtin_amdgcn_mfma_f32_16x16x32_bf16(ul.v, uv.v, acc_o[j2], 0, 0, 0);
            }
        }
    }

    #pragma unroll
    for (int j2 = 0; j2 < 4; ++j2) {
        int c = h * 64 + j2 * 16 + fr;
        #pragma unroll
        for (int reg = 0; reg < 4; ++reg) {
            int n = n0 + wn + fg * 4 + reg;
            O[((size_t)(tb * 512 + n) << 9) + c] = acc_o[j2][reg];
        }
    }
}

// ---------------------------------------------------------------------------
// Retention LIF: reads O (t,b,n,c); writes bf16 spikes (permuted) + flag.
__global__ void lif_ret_bf2(const float* __restrict__ Y, __bf16* __restrict__ Rb,
                            int* __restrict__ ctr, int* __restrict__ list) {
    int g = blockIdx.x * TPB + threadIdx.x;
    int c = g & 511, n = (g >> 9) & 511, b = g >> 18;
    size_t pbase = ((size_t)(b * 512 + n) * 4) * 512 + c;
    double v = 0.0, eb = 0.0;
    bool flag = false;
    for (int t = 0; t < 4; ++t) {
        size_t idx = ((size_t)((t * 8 + b) * 512 + n) << 9) + c;
        double x = (double)Y[idx];
        double hh = v + (x - v) * 0.5;
        eb = 0.5 * eb + 0.5 * (fabs(x) * 1e-4);
        flag |= fabs(hh - 0.5) <= eb + 1e-9;
        bool s = hh >= 0.5;
        Rb[pbase + (size_t)t * 512] = s ? (__bf16)1.0f : (__bf16)0.0f;
        v = s ? 0.0 : hh;
        if (s) eb = 0.0;
    }
    if (flag) {
        int i2 = atomicAdd(ctr + 4, 1);
        if (i2 < FCAP) list[i2] = g;
    }
}

// Exact fp64 repair of flagged retention neurons; writes permuted Rb.
__global__ void repair_ret_bf2(const u64* __restrict__ qm, const u64* __restrict__ km,
                               const u64* __restrict__ vm, const double* __restrict__ pw,
                               const int* __restrict__ ctr, const int* __restrict__ list,
                               __bf16* __restrict__ Rb) {
    int cnt = ctr[4]; if (cnt > FCAP) cnt = FCAP;
    int wv = (blockIdx.x * blockDim.x + threadIdx.x) >> 6;
    int nw = (gridDim.x * blockDim.x) >> 6;
    int lane = threadIdx.x & 63;
    for (int i = wv; i < cnt; i += nw) {
        int g = list[i];
        int c = g & 511, n = (g >> 9) & 511, b = g >> 18;
        int h = c >> 6, d = c & 63;
        double acc_t[4];
        for (int t = 0; t < 4; ++t) {
            int base = ((t * 8 + b) * 8 + h) * 512;
            u64 qw = qm[base + n];
            double p = 0.0;
            for (int j = 0; j < 8; ++j) {
                int m = j * 64 + lane;
                u64 kk = km[base + m];
                u64 vvm = vm[base + m];
                if ((vvm >> d) & 1ull) {
                    int dist = n - m; if (dist < 0) dist = -dist;
                    p += (double)__popcll(qw & kk) * pw[h * 512 + dist];
                }
            }
            acc_t[t] = p;
        }
        #pragma unroll
        for (int off = 32; off; off >>= 1) {
            #pragma unroll
            for (int t = 0; t < 4; ++t) acc_t[t] += __shfl_xor(acc_t[t], off, 64);
        }
        if (lane == 0) {
            double v = 0.0;
            size_t pbase = ((size_t)(b * 512 + n) * 4) * 512 + c;
            for (int t = 0; t < 4; ++t) {
                double x = acc_t[t] * 0.125;
                double hh = v + (x - v) * 0.5;
                bool s = hh >= 0.5;
                Rb[pbase + (size_t)t * 512] = s ? (__bf16)1.0f : (__bf16)0.0f;
                v = s ? 0.0 : hh;
            }
        }
    }
}

// ---------------------------------------------------------------------------
// Exact fp64 repair of flagged FINAL neurons; reads permuted Rb; writes d_out.
__global__ void fix_final_direct(const __bf16* __restrict__ rr, const float* __restrict__ w,
                                 const float* __restrict__ bias,
                                 const float* __restrict__ bnw, const float* __restrict__ bnb,
                                 const float* __restrict__ bnm, const float* __restrict__ bnv,
                                 const int* __restrict__ ctr, const int* __restrict__ list,
                                 float* __restrict__ out) {
    int cnt = ctr[3]; if (cnt > FCAP) cnt = FCAP;
    int wv = (blockIdx.x * blockDim.x + threadIdx.x) >> 6;
    int nw = (gridDim.x * blockDim.x) >> 6;
    int lane = threadIdx.x & 63;
    for (int i = wv; i < cnt; i += nw) {
        int g = list[i];
        int c = g & 511, n = (g >> 9) & 511, b = g >> 18;
        const float* wr = w + (size_t)c * 512;
        double dot[4];
        #pragma unroll
        for (int t = 0; t < 4; ++t) {
            const __bf16* xr = rr + ((size_t)(b * 512 + n) * 4 + t) * 512;
            double p = 0.0;
            #pragma unroll
            for (int j = 0; j < 8; ++j)
                p += (double)(float)xr[lane + 64 * j] * (double)wr[lane + 64 * j];
            dot[t] = p;
        }
        #pragma unroll
        for (int off = 32; off; off >>= 1) {
            #pragma unroll
            for (int t = 0; t < 4; ++t)
                dot[t] += __shfl_xor(dot[t], off, 64);
        }
        if (lane == 0) {
            double inv = (double)bnw[c] / sqrt((double)bnv[c] + 1e-5);
            double sh  = (double)bnb[c] - (double)bnm[c] * inv;
            double bs  = (double)bias[c];
            double v = 0.0;
            for (int t = 0; t < 4; ++t) {
                double y = (dot[t] + bs) * inv + sh;
                double hh = v + (y - v) * 0.5;
                bool s = hh >= 1.0;
                out[((size_t)((t * 8 + b) * 512 + n) << 9) + c] = s ? 1.0f : 0.0f;
                v = s ? 0.0 : hh;
            }
        }
    }
}

// ===========================================================================
// Fallback path kernels (R15-proven, used when ws is too small)
// ===========================================================================
__global__ __launch_bounds__(256) void gemm_bn_mfma(
    const float* __restrict__ A, const float* __restrict__ W,
    const float* __restrict__ bias,
    const float* __restrict__ bnw, const float* __restrict__ bnb,
    const float* __restrict__ bnm, const float* __restrict__ bnv,
    float* __restrict__ out)
{
    __shared__ __bf16 Ah[128][36];
    __shared__ __bf16 Al[128][36];
    __shared__ __bf16 Wh[64][36];
    __shared__ __bf16 Wl[64][36];

    const int tid = threadIdx.x;
    const int m0 = blockIdx.x * 128;
    const int d0 = blockIdx.y * 64;
    const int wv = tid >> 6;
    const int wm = wv >> 1;
    const int wd = wv & 1;
    const int lane = tid & 63;
    const int fr = lane & 15;
    const int fg = lane >> 4;
    const int srow = tid >> 3;
    const int scol = (tid & 7) * 4;

    f32x4 acc[4][2];
    #pragma unroll
    for (int i = 0; i < 4; ++i)
        #pragma unroll
        for (int j = 0; j < 2; ++j)
            acc[i][j] = (f32x4){0.f, 0.f, 0.f, 0.f};

    for (int k0 = 0; k0 < 512; k0 += 32) {
        __syncthreads();
        #pragma unroll
        for (int rep = 0; rep < 4; ++rep) {
            int row = srow + 32 * rep;
            float4 va = *(const float4*)(A + (size_t)(m0 + row) * 512 + k0 + scol);
            #pragma unroll
            for (int e = 0; e < 4; ++e) {
                float f = (&va.x)[e];
                __bf16 h = (__bf16)f;
                Ah[row][scol + e] = h;
                Al[row][scol + e] = (__bf16)(f - (float)h);
            }
        }
        #pragma unroll
        for (int rep = 0; rep < 2; ++rep) {
            int row = srow + 32 * rep;
            float4 vw = *(const float4*)(W + (size_t)(d0 + row) * 512 + k0 + scol);
            #pragma unroll
            for (int e = 0; e < 4; ++e) {
                float f = (&vw.x)[e];
                __bf16 h = (__bf16)f;
                Wh[row][scol + e] = h;
                Wl[row][scol + e] = (__bf16)(f - (float)h);
            }
        }
        __syncthreads();

        union FU { bf16x8 v8; struct { __bf16 a[4], b[4]; } s; };
        bf16x8 ah[4], al[4], bh[2], bl[2];
        #pragma unroll
        for (int i = 0; i < 4; ++i) {
            int row = wm * 64 + i * 16 + fr;
            FU u1, u2;
            *(double*)&u1.s.a[0] = *(const double*)&Ah[row][fg * 8];
            *(double*)&u1.s.b[0] = *(const double*)&Ah[row][fg * 8 + 4];
            *(double*)&u2.s.a[0] = *(const double*)&Al[row][fg * 8];
            *(double*)&u2.s.b[0] = *(const double*)&Al[row][fg * 8 + 4];
            ah[i] = u1.v8; al[i] = u2.v8;
        }
        #pragma unroll
        for (int j = 0; j < 2; ++j) {
            int row = wd * 32 + j * 16 + fr;
            FU u1, u2;
            *(double*)&u1.s.a[0] = *(const double*)&Wh[row][fg * 8];
            *(double*)&u1.s.b[0] = *(const double*)&Wh[row][fg * 8 + 4];
            *(double*)&u2.s.a[0] = *(const double*)&Wl[row][fg * 8];
            *(double*)&u2.s.b[0] = *(const double*)&Wl[row][fg * 8 + 4];
            bh[j] = u1.v8; bl[j] = u2.v8;
        }
        #pragma unroll
        for (int i = 0; i < 4; ++i)
            #pragma unroll
            for (int j = 0; j < 2; ++j) {
                acc[i][j] = __builtin_amdgcn_mfma_f32_16x16x32_bf16(ah[i], bh[j], acc[i][j], 0, 0, 0);
                acc[i][j] = __builtin_amdgcn_mfma_f32_16x16x32_bf16(ah[i], bl[j], acc[i][j], 0, 0, 0);
                acc[i][j] = __builtin_amdgcn_mfma_f32_16x16x32_bf16(al[i], bh[j], acc[i][j], 0, 0, 0);
            }
    }

    #pragma unroll
    for (int j = 0; j < 2; ++j) {
        int d = d0 + wd * 32 + j * 16 + fr;
        double inv = (double)bnw[d] / sqrt((double)bnv[d] + 1e-5);
        double sh  = (double)bnb[d] - (double)bnm[d] * inv;
        double bs  = (double)bias[d];
        #pragma unroll
        for (int i = 0; i < 4; ++i) {
            #pragma unroll
            for (int reg = 0; reg < 4; ++reg) {
                int m = m0 + wm * 64 + i * 16 + fg * 4 + reg;
                out[(size_t)m * 512 + d] = (float)(((double)acc[i][j][reg] + bs) * inv + sh);
            }
        }
    }
}

__global__ void lif_mask_flag(const float* __restrict__ Y, u64* __restrict__ msk,
                              int* __restrict__ ctr, int* __restrict__ list, int slot) {
    int g = blockIdx.x * TPB + threadIdx.x;
    int c = g & 511, n = (g >> 9) & 511, b = g >> 18;
    int h = c >> 6;
    int lane = threadIdx.x & 63;
    double v = 0.0;
    bool flag = false;
    for (int t = 0; t < 4; ++t) {
        float y = Y[((size_t)((t * 8 + b) * 512 + n) << 9) + c];
        double hh = v + ((double)y - v) * 0.5;
        flag |= fabs(hh - 1.0) < MARGIN;
        bool s = hh >= 1.0;
        u64 mk = __ballot(s);
        if (lane == 0) msk[((t * 8 + b) * 8 + h) * 512 + n] = mk;
        v = s ? 0.0 : hh;
    }
    if (flag) {
        int idx = atomicAdd(ctr + slot, 1);
        if (idx < FCAP) list[idx] = g;
    }
}

__global__ void lif_ret_f(const float* __restrict__ Y, float* __restrict__ R,
                          int* __restrict__ ctr, int* __restrict__ list) {
    int g = blockIdx.x * TPB + threadIdx.x;
    int c = g & 511, n = (g >> 9) & 511, b = g >> 18;
    double v = 0.0, eb = 0.0;
    bool flag = false;
    for (int t = 0; t < 4; ++t) {
        size_t idx = ((size_t)((t * 8 + b) * 512 + n) << 9) + c;
        double x = (double)Y[idx];
        double hh = v + (x - v) * 0.5;
        eb = 0.5 * eb + 0.5 * (fabs(x) * 1e-4);
        flag |= fabs(hh - 0.5) <= eb + 1e-9;
        bool s = hh >= 0.5;
        R[idx] = s ? 1.0f : 0.0f;
        v = s ? 0.0 : hh;
        if (s) eb = 0.0;
    }
    if (flag) {
        int i2 = atomicAdd(ctr + 4, 1);
        if (i2 < FCAP) list[i2] = g;
    }
}

__global__ void repair_ret_f(const u64* __restrict__ qm, const u64* __restrict__ km,
                             const u64* __restrict__ vm, const double* __restrict__ pw,
                             const int* __restrict__ ctr, const int* __restrict__ list,
                             float* __restrict__ r) {
    int cnt = ctr[4]; if (cnt > FCAP) cnt = FCAP;
    int wv = (blockIdx.x * blockDim.x + threadIdx.x) >> 6;
    int nw = (gridDim.x * blockDim.x) >> 6;
    int lane = threadIdx.x & 63;
    for (int i = wv; i < cnt; i += nw) {
        int g = list[i];
        int c = g & 511, n = (g >> 9) & 511, b = g >> 18;
        int h = c >> 6, d = c & 63;
        double acc_t[4];
        for (int t = 0; t < 4; ++t) {
            int base = ((t * 8 + b) * 8 + h) * 512;
            u64 qw = qm[base + n];
            double p = 0.0;
            for (int j = 0; j < 8; ++j) {
                int m = j * 64 + lane;
                u64 kk = km[base + m];
                u64 vvm = vm[base + m];
                if ((vvm >> d) & 1ull) {
                    int dist = n - m; if (dist < 0) dist = -dist;
                    p += (double)__popcll(qw & kk) * pw[h * 512 + dist];
                }
            }
            acc_t[t] = p;
        }
        #pragma unroll
        for (int off = 32; off; off >>= 1) {
            #pragma unroll
            for (int t = 0; t < 4; ++t) acc_t[t] += __shfl_xor(acc_t[t], off, 64);
        }
        if (lane == 0) {
            double v = 0.0;
            for (int t = 0; t < 4; ++t) {
                double x = acc_t[t] * 0.125;
                double hh = v + (x - v) * 0.5;
                bool s = hh >= 0.5;
                r[((size_t)((t * 8 + b) * 512 + n) << 9) + c] = s ? 1.0f : 0.0f;
                v = s ? 0.0 : hh;
            }
        }
    }
}

__global__ void final_flag(const float* __restrict__ Y, int* __restrict__ ctr,
                           int* __restrict__ list) {
    int g = blockIdx.x * TPB + threadIdx.x;
    int c = g & 511, n = (g >> 9) & 511, b = g >> 18;
    double v = 0.0;
    bool flag = false;
    for (int t = 0; t < 4; ++t) {
        float y = Y[((size_t)((t * 8 + b) * 512 + n) << 9) + c];
        double hh = v + ((double)y - v) * 0.5;
        flag |= fabs(hh - 1.0) < MARGIN;
        bool s = hh >= 1.0;
        v = s ? 0.0 : hh;
    }
    if (flag) {
        int idx = atomicAdd(ctr + 3, 1);
        if (idx < FCAP) list[idx] = g;
    }
}

__global__ void fix_final_f(const float* __restrict__ rr, const float* __restrict__ w,
                            const float* __restrict__ bias,
                            const float* __restrict__ bnw, const float* __restrict__ bnb,
                            const float* __restrict__ bnm, const float* __restrict__ bnv,
                            const int* __restrict__ ctr, int* __restrict__ list) {
    int cnt = ctr[3]; if (cnt > FCAP) cnt = FCAP;
    int wv = (blockIdx.x * blockDim.x + threadIdx.x) >> 6;
    int nw = (gridDim.x * blockDim.x) >> 6;
    int lane = threadIdx.x & 63;
    for (int i = wv; i < cnt; i += nw) {
        int g = list[i] & 0x00FFFFFF;
        int c = g & 511, n = (g >> 9) & 511, b = g >> 18;
        const float* wr = w + (size_t)c * 512;
        double dot[4];
        #pragma unroll
        for (int t = 0; t < 4; ++t) {
            const float* xr = rr + ((size_t)((t * 8 + b) * 512 + n) << 9);
            double p = 0.0;
            #pragma unroll
            for (int j = 0; j < 8; ++j)
                p += (double)xr[lane + 64 * j] * (double)wr[lane + 64 * j];
            dot[t] = p;
        }
        #pragma unroll
        for (int off = 32; off; off >>= 1) {
            #pragma unroll
            for (int t = 0; t < 4; ++t)
                dot[t] += __shfl_xor(dot[t], off, 64);
        }
        if (lane == 0) {
            double inv = (double)bnw[c] / sqrt((double)bnv[c] + 1e-5);
            double sh  = (double)bnb[c] - (double)bnm[c] * inv;
            double bs  = (double)bias[c];
            double v = 0.0;
            int sp = 0;
            for (int t = 0; t < 4; ++t) {
                double y = (dot[t] + bs) * inv + sh;
                double hh = v + (y - v) * 0.5;
                bool s = hh >= 1.0;
                sp |= (s ? 1 : 0) << t;
                v = s ? 0.0 : hh;
            }
            list[i] = g | (sp << 24);
        }
    }
}

__global__ void final_write(const float* __restrict__ Y, float* __restrict__ out) {
    int g = blockIdx.x * TPB + threadIdx.x;
    int c = g & 511, n = (g >> 9) & 511, b = g >> 18;
    double v = 0.0;
    for (int t = 0; t < 4; ++t) {
        size_t idx = ((size_t)((t * 8 + b) * 512 + n) << 9) + c;
        float y = Y[idx];
        double hh = v + ((double)y - v) * 0.5;
        bool s = hh >= 1.0;
        out[idx] = s ? 1.0f : 0.0f;
        v = s ? 0.0 : hh;
    }
}

__global__ void fix_scatter(const int* __restrict__ ctr, const int* __restrict__ list,
                            float* __restrict__ out) {
    int cnt = ctr[3]; if (cnt > FCAP) cnt = FCAP;
    int i = blockIdx.x * blockDim.x + threadIdx.x;
    if (i >= cnt) return;
    int e = list[i];
    int g = e & 0x00FFFFFF, sp = (e >> 24) & 0xF;
    int c = g & 511, n = (g >> 9) & 511, b = g >> 18;
    for (int t = 0; t < 4; ++t)
        out[((size_t)((t * 8 + b) * 512 + n) << 9) + c] = ((sp >> t) & 1) ? 1.0f : 0.0f;
}

// ---------------------------------------------------------------------------
extern "C" void kernel_launch(void* const* d_in, const int* in_sizes, int n_in,
                              void* d_out, int out_size, void* d_ws, size_t ws_size,
                              hipStream_t stream) {
    const float* x = (const float*)d_in[0];
    const float *w[4], *bi[4], *bnw[4], *bnb[4], *bnm[4], *bnv[4];
    for (int br = 0; br < 4; ++br) {
        int base = 1 + br * 6;
        w[br]   = (const float*)d_in[base + 0];
        bi[br]  = (const float*)d_in[base + 1];
        bnw[br] = (const float*)d_in[base + 2];
        bnb[br] = (const float*)d_in[base + 3];
        bnm[br] = (const float*)d_in[base + 4];
        bnv[br] = (const float*)d_in[base + 5];
    }

    const size_t NX = (size_t)16384 * 512;
    char* p = (char*)d_ws;
    double* pw = (double*)p;  p += 8 * 512 * sizeof(double);
    u64* qm = (u64*)p;        p += 131072 * sizeof(u64);
    u64* km = (u64*)p;        p += 131072 * sizeof(u64);
    u64* vm = (u64*)p;        p += 131072 * sizeof(u64);
    int* ctr = (int*)p;       p += 1024;
    int* list = (int*)p;      p += (size_t)FCAP * sizeof(int);
    float* Y = (float*)p;     p += NX * 4;
    __bf16* Xh = (__bf16*)p;  p += NX * 2;
    __bf16* Xl = (__bf16*)p;  p += NX * 2;
    __bf16* Wsp = (__bf16*)p; p += (size_t)4 * 2 * 262144 * 2;
    size_t need_fast = (size_t)(p - (char*)d_ws);
    int fast = ws_size >= need_fast;

    init_kernel<<<1, 64, 0, stream>>>(pw, ctr);

    dim3 g2(128, 4);
    dim3 gg(128, 8);

    if (fast) {
        split_all<<<8192 + 1024, 256, 0, stream>>>(x, w[0], w[1], w[2], w[3], Xh, Xl, Wsp);
        for (int br = 0; br < 3; ++br) {
            u64* msk = br == 0 ? qm : (br == 1 ? km : vm);
            gemm_lif_mask<<<g2, 256, 0, stream>>>(Xh, Xl,
                Wsp + (size_t)br * 524288, Wsp + (size_t)br * 524288 + 262144,
                bi[br], bnw[br], bnb[br], bnm[br], bnv[br], msk, ctr, list, br);
            fix_mask<<<128, 256, 0, stream>>>(x, w[br], bi[br], bnw[br], bnb[br],
                                              bnm[br], bnv[br], msk, ctr, list, br);
        }
        // retention -> Y; LIF -> bf16 spikes (permuted) in Xh; exact repair
        ret_fused2<<<2048, 256, 0, stream>>>(qm, km, vm, pw, Y);
        lif_ret_bf2<<<8192, TPB, 0, stream>>>(Y, Xh, ctr, list);
        repair_ret_bf2<<<256, 256, 0, stream>>>(qm, km, vm, pw, ctr, list, Xh);
        // p projection + fused final LIF -> d_out; exact repair direct
        gemm_final_lif<<<g2, 256, 0, stream>>>(Xh,
            Wsp + (size_t)3 * 524288, Wsp + (size_t)3 * 524288 + 262144,
            bi[3], bnw[3], bnb[3], bnm[3], bnv[3], (float*)d_out, ctr, list);
        fix_final_direct<<<128, 256, 0, stream>>>(Xh, w[3], bi[3], bnw[3], bnb[3],
                                                  bnm[3], bnv[3], ctr, list, (float*)d_out);
    } else {
        for (int br = 0; br < 3; ++br) {
            u64* msk = br == 0 ? qm : (br == 1 ? km : vm);
            gemm_bn_mfma<<<gg, 256, 0, stream>>>(x, w[br], bi[br], bnw[br], bnb[br],
                                                 bnm[br], bnv[br], Y);
            lif_mask_flag<<<8192, TPB, 0, stream>>>(Y, msk, ctr, list, br);
            fix_mask<<<128, 256, 0, stream>>>(x, w[br], bi[br], bnw[br], bnb[br],
                                              bnm[br], bnv[br], msk, ctr, list, br);
        }
        float* r = (float*)d_out;
        ret_fused2<<<2048, 256, 0, stream>>>(qm, km, vm, pw, Y);
        lif_ret_f<<<8192, TPB, 0, stream>>>(Y, r, ctr, list);
        repair_ret_f<<<256, 256, 0, stream>>>(qm, km, vm, pw, ctr, list, r);
        gemm_bn_mfma<<<gg, 256, 0, stream>>>(r, w[3], bi[3], bnw[3], bnb[3],
                                             bnm[3], bnv[3], Y);
        final_flag<<<8192, TPB, 0, stream>>>(Y, ctr, list);
        fix_final_f<<<128, 256, 0, stream>>>(r, w[3], bi[3], bnw[3], bnb[3],
                                             bnm[3], bnv[3], ctr, list);
        final_write<<<8192, TPB, 0, stream>>>(Y, (float*)d_out);
        fix_scatter<<<4096, 256, 0, stream>>>(ctr, list, (float*)d_out);
    }
}

// Round 18
// 277.216 us; speedup vs baseline: 1.3217x; 1.0006x over previous
//
#include <hip/hip_runtime.h>
#include <cstdint>

typedef unsigned long long u64;

#define TPB 256
#define MARGIN 5e-4
#define FCAP (1 << 20)

typedef __bf16 bf16x8 __attribute__((ext_vector_type(8)));
typedef __bf16 bf16x4 __attribute__((ext_vector_type(4)));
typedef float f32x4 __attribute__((ext_vector_type(4)));

typedef __attribute__((address_space(1))) void GV;
typedef __attribute__((address_space(3))) void LV;
typedef __attribute__((address_space(3))) char LC;

#define GLD(gsrc, ldst) __builtin_amdgcn_global_load_lds( \
    (GV*)(void*)(gsrc), (LV*)(ldst), 16, 0, 0)

// ---------------------------------------------------------------------------
__global__ void init_kernel(double* __restrict__ pw, int* __restrict__ ctr) {
    int h = threadIdx.x;
    if (h < 8) {
        double gamma = 1.0 - ldexp(1.0, -5 - h);
        double p = 1.0;
        for (int i = 0; i < 512; ++i) { pw[h * 512 + i] = p; p *= gamma; }
        ctr[h] = 0;
    }
}

// ---------------------------------------------------------------------------
// Combined split. x rows PERMUTED to m' = (b*512+n)*4 + t (reg index == t).
__global__ void split_all(const float* __restrict__ x,
                          const float* __restrict__ w0, const float* __restrict__ w1,
                          const float* __restrict__ w2, const float* __restrict__ w3,
                          __bf16* __restrict__ Xh, __bf16* __restrict__ Xl,
                          __bf16* __restrict__ Wsp) {
    int blk = blockIdx.x;
    if (blk < 8192) {
        size_t i = (size_t)blk * 1024 + threadIdx.x * 4;
        int m = (int)(i >> 9), c = (int)(i & 511);
        int mp = (m & 4095) * 4 + (m >> 12);
        float4 v = *(const float4*)(x + i);
        bf16x4 h4, l4;
        #pragma unroll
        for (int e = 0; e < 4; ++e) {
            float f = (&v.x)[e];
            __bf16 hh = (__bf16)f;
            h4[e] = hh;
            l4[e] = (__bf16)(f - (float)hh);
        }
        size_t dst = (size_t)mp * 512 + c;
        *(bf16x4*)(Xh + dst) = h4;
        *(bf16x4*)(Xl + dst) = l4;
    } else {
        int wb = blk - 8192;
        int br = wb >> 8;
        const float* ws[4] = {w0, w1, w2, w3};
        const float* src = ws[br];
        __bf16* hi = Wsp + (size_t)br * 524288;
        __bf16* lo = hi + 262144;
        size_t i = (size_t)(wb & 255) * 1024 + threadIdx.x * 4;
        float4 v = *(const float4*)(src + i);
        bf16x4 h4, l4;
        #pragma unroll
        for (int e = 0; e < 4; ++e) {
            float f = (&v.x)[e];
            __bf16 hh = (__bf16)f;
            h4[e] = hh;
            l4[e] = (__bf16)(f - (float)hh);
        }
        *(bf16x4*)(hi + i) = h4;
        *(bf16x4*)(lo + i) = l4;
    }
}

// ---------------------------------------------------------------------------
// Branch GEMM (3-pass) via global_load_lds staging (linear LDS, source-swizzle
// col16' = col16 ^ ((row>>1)&3)) + fused BN/LIF/mask epilogue.
__global__ __launch_bounds__(256) void gemm_lif_mask(
    const __bf16* __restrict__ Ahg, const __bf16* __restrict__ Alg,
    const __bf16* __restrict__ Whg, const __bf16* __restrict__ Wlg,
    const float* __restrict__ bias,
    const float* __restrict__ bnw, const float* __restrict__ bnb,
    const float* __restrict__ bnm, const float* __restrict__ bnv,
    u64* __restrict__ msk, int* __restrict__ ctr, int* __restrict__ list, int slot)
{
    __shared__ __bf16 AhS[128][32];
    __shared__ __bf16 AlS[128][32];
    __shared__ __bf16 WhS[128][32];
    __shared__ __bf16 WlS[128][32];

    const int tid = threadIdx.x;
    const int m0 = blockIdx.x * 128;
    const int d0 = blockIdx.y * 128;
    const int wv = tid >> 6;
    const int wm = wv >> 1;
    const int wd = wv & 1;
    const int lane = tid & 63;
    const int fr = lane & 15;
    const int fg = lane >> 4;

    // gload source addressing (per-lane, constant across k0)
    const int lr   = lane >> 2;                      // row within 16-row chunk
    const int csrc = (lane & 3) ^ ((lane >> 3) & 3); // swizzled col16 source
    const int rA0  = wv * 32 + lr;                   // chunk q=0 row
    const __bf16* gAh0 = Ahg + (size_t)(m0 + rA0) * 512 + csrc * 8;
    const __bf16* gAh1 = gAh0 + (size_t)16 * 512;
    const __bf16* gAl0 = Alg + (size_t)(m0 + rA0) * 512 + csrc * 8;
    const __bf16* gAl1 = gAl0 + (size_t)16 * 512;
    const __bf16* gWh0 = Whg + (size_t)(d0 + rA0) * 512 + csrc * 8;
    const __bf16* gWh1 = gWh0 + (size_t)16 * 512;
    const __bf16* gWl0 = Wlg + (size_t)(d0 + rA0) * 512 + csrc * 8;
    const __bf16* gWl1 = gWl0 + (size_t)16 * 512;

    unsigned ldsOff = __builtin_amdgcn_readfirstlane((unsigned)(wv * 2048));
    LC* lAh = (LC*)(LV*)&AhS[0][0] + ldsOff;
    LC* lAl = (LC*)(LV*)&AlS[0][0] + ldsOff;
    LC* lWh = (LC*)(LV*)&WhS[0][0] + ldsOff;
    LC* lWl = (LC*)(LV*)&WlS[0][0] + ldsOff;

    // frag read byte offset within row (swizzled), constant per lane
    const int fcol = (fg ^ ((fr >> 1) & 3)) * 16;

    f32x4 acc[4][4];
    #pragma unroll
    for (int i = 0; i < 4; ++i)
        #pragma unroll
        for (int j = 0; j < 4; ++j)
            acc[i][j] = (f32x4){0.f, 0.f, 0.f, 0.f};

    for (int k0 = 0; k0 < 512; k0 += 32) {
        __syncthreads();
        GLD(gAh0 + k0, lAh); GLD(gAh1 + k0, lAh + 1024);
        GLD(gAl0 + k0, lAl); GLD(gAl1 + k0, lAl + 1024);
        GLD(gWh0 + k0, lWh); GLD(gWh1 + k0, lWh + 1024);
        GLD(gWl0 + k0, lWl); GLD(gWl1 + k0, lWl + 1024);
        __syncthreads();

        bf16x8 ah[4], bh[4], bl[4];
        #pragma unroll
        for (int i = 0; i < 4; ++i) {
            int row = wm * 64 + i * 16 + fr;
            ah[i] = *(const bf16x8*)((const char*)&AhS[0][0] + row * 64 + fcol);
        }
        #pragma unroll
        for (int j = 0; j < 4; ++j) {
            int row = wd * 64 + j * 16 + fr;
            bh[j] = *(const bf16x8*)((const char*)&WhS[0][0] + row * 64 + fcol);
            bl[j] = *(const bf16x8*)((const char*)&WlS[0][0] + row * 64 + fcol);
        }
        #pragma unroll
        for (int i = 0; i < 4; ++i)
            #pragma unroll
            for (int j = 0; j < 4; ++j) {
                acc[i][j] = __builtin_amdgcn_mfma_f32_16x16x32_bf16(ah[i], bh[j], acc[i][j], 0, 0, 0);
                acc[i][j] = __builtin_amdgcn_mfma_f32_16x16x32_bf16(ah[i], bl[j], acc[i][j], 0, 0, 0);
            }
        bf16x8 al[4];
        #pragma unroll
        for (int i = 0; i < 4; ++i) {
            int row = wm * 64 + i * 16 + fr;
            al[i] = *(const bf16x8*)((const char*)&AlS[0][0] + row * 64 + fcol);
        }
        #pragma unroll
        for (int i = 0; i < 4; ++i)
            #pragma unroll
            for (int j = 0; j < 4; ++j)
                acc[i][j] = __builtin_amdgcn_mfma_f32_16x16x32_bf16(al[i], bh[j], acc[i][j], 0, 0, 0);
    }

    // ---- epilogue: BN + LIF(1.0) + mask ballots + margin flags (R16-proven)
    double invj[4], shj[4], bsj[4];
    #pragma unroll
    for (int j = 0; j < 4; ++j) {
        int d = d0 + wd * 64 + j * 16 + fr;
        invj[j] = (double)bnw[d] / sqrt((double)bnv[d] + 1e-5);
        shj[j]  = (double)bnb[d] - (double)bnm[d] * invj[j];
        bsj[j]  = (double)bias[d];
    }
    int hword = (d0 >> 6) + wd;
    int bn0 = blockIdx.x * 32 + wm * 16;

    #pragma unroll
    for (int i = 0; i < 4; ++i) {
        int bn = bn0 + i * 4 + fg;
        int b = bn >> 9, n = bn & 511;
        u64 w[4] = {0ull, 0ull, 0ull, 0ull};
        #pragma unroll
        for (int j = 0; j < 4; ++j) {
            double v = 0.0;
            bool fl = false;
            #pragma unroll
            for (int t = 0; t < 4; ++t) {
                double y = ((double)acc[i][j][t] + bsj[j]) * invj[j] + shj[j];
                double hh = v + (y - v) * 0.5;
                fl |= fabs(hh - 1.0) < MARGIN;
                bool s = hh >= 1.0;
                u64 blt = __ballot(s);
                w[t] |= ((blt >> (fg * 16)) & 0xFFFFull) << (j * 16);
                v = s ? 0.0 : hh;
            }
            if (fl) {
                int d = d0 + wd * 64 + j * 16 + fr;
                int idx = atomicAdd(ctr + slot, 1);
                if (idx < FCAP) list[idx] = (b << 18) | (n << 9) | d;
            }
        }
        if (fr == 0) {
            #pragma unroll
            for (int t = 0; t < 4; ++t)
                msk[((t * 8 + b) * 8 + hword) * 512 + n] = w[t];
        }
    }
}

// ---------------------------------------------------------------------------
// Final GEMM (2-pass, A exact) via global_load_lds + fused final LIF -> out.
__global__ __launch_bounds__(256) void gemm_final_lif(
    const __bf16* __restrict__ Ahg,
    const __bf16* __restrict__ Whg, const __bf16* __restrict__ Wlg,
    const float* __restrict__ bias,
    const float* __restrict__ bnw, const float* __restrict__ bnb,
    const float* __restrict__ bnm, const float* __restrict__ bnv,
    float* __restrict__ out, int* __restrict__ ctr, int* __restrict__ list)
{
    __shared__ __bf16 AhS[128][32];
    __shared__ __bf16 WhS[128][32];
    __shared__ __bf16 WlS[128][32];

    const int tid = threadIdx.x;
    const int m0 = blockIdx.x * 128;
    const int d0 = blockIdx.y * 128;
    const int wv = tid >> 6;
    const int wm = wv >> 1;
    const int wd = wv & 1;
    const int lane = tid & 63;
    const int fr = lane & 15;
    const int fg = lane >> 4;

    const int lr   = lane >> 2;
    const int csrc = (lane & 3) ^ ((lane >> 3) & 3);
    const int rA0  = wv * 32 + lr;
    const __bf16* gAh0 = Ahg + (size_t)(m0 + rA0) * 512 + csrc * 8;
    const __bf16* gAh1 = gAh0 + (size_t)16 * 512;
    const __bf16* gWh0 = Whg + (size_t)(d0 + rA0) * 512 + csrc * 8;
    const __bf16* gWh1 = gWh0 + (size_t)16 * 512;
    const __bf16* gWl0 = Wlg + (size_t)(d0 + rA0) * 512 + csrc * 8;
    const __bf16* gWl1 = gWl0 + (size_t)16 * 512;

    unsigned ldsOff = __builtin_amdgcn_readfirstlane((unsigned)(wv * 2048));
    LC* lAh = (LC*)(LV*)&AhS[0][0] + ldsOff;
    LC* lWh = (LC*)(LV*)&WhS[0][0] + ldsOff;
    LC* lWl = (LC*)(LV*)&WlS[0][0] + ldsOff;

    const int fcol = (fg ^ ((fr >> 1) & 3)) * 16;

    f32x4 acc[4][4];
    #pragma unroll
    for (int i = 0; i < 4; ++i)
        #pragma unroll
        for (int j = 0; j < 4; ++j)
            acc[i][j] = (f32x4){0.f, 0.f, 0.f, 0.f};

    for (int k0 = 0; k0 < 512; k0 += 32) {
        __syncthreads();
        GLD(gAh0 + k0, lAh); GLD(gAh1 + k0, lAh + 1024);
        GLD(gWh0 + k0, lWh); GLD(gWh1 + k0, lWh + 1024);
        GLD(gWl0 + k0, lWl); GLD(gWl1 + k0, lWl + 1024);
        __syncthreads();

        bf16x8 ah[4], bh[4], bl[4];
        #pragma unroll
        for (int i = 0; i < 4; ++i) {
            int row = wm * 64 + i * 16 + fr;
            ah[i] = *(const bf16x8*)((const char*)&AhS[0][0] + row * 64 + fcol);
        }
        #pragma unroll
        for (int j = 0; j < 4; ++j) {
            int row = wd * 64 + j * 16 + fr;
            bh[j] = *(const bf16x8*)((const char*)&WhS[0][0] + row * 64 + fcol);
            bl[j] = *(const bf16x8*)((const char*)&WlS[0][0] + row * 64 + fcol);
        }
        #pragma unroll
        for (int i = 0; i < 4; ++i)
            #pragma unroll
            for (int j = 0; j < 4; ++j) {
                acc[i][j] = __builtin_amdgcn_mfma_f32_16x16x32_bf16(ah[i], bh[j], acc[i][j], 0, 0, 0);
                acc[i][j] = __builtin_amdgcn_mfma_f32_16x16x32_bf16(ah[i], bl[j], acc[i][j], 0, 0, 0);
            }
    }

    double invj[4], shj[4], bsj[4];
    #pragma unroll
    for (int j = 0; j < 4; ++j) {
        int d = d0 + wd * 64 + j * 16 + fr;
        invj[j] = (double)bnw[d] / sqrt((double)bnv[d] + 1e-5);
        shj[j]  = (double)bnb[d] - (double)bnm[d] * invj[j];
        bsj[j]  = (double)bias[d];
    }
    int bn0 = blockIdx.x * 32 + wm * 16;

    #pragma unroll
    for (int i = 0; i < 4; ++i) {
        int bn = bn0 + i * 4 + fg;
        int b = bn >> 9, n = bn & 511;
        #pragma unroll
        for (int j = 0; j < 4; ++j) {
            int d = d0 + wd * 64 + j * 16 + fr;
            double v = 0.0;
            bool fl = false;
            #pragma unroll
            for (int t = 0; t < 4; ++t) {
                double y = ((double)acc[i][j][t] + bsj[j]) * invj[j] + shj[j];
                double hh = v + (y - v) * 0.5;
                fl |= fabs(hh - 1.0) < MARGIN;
                bool s = hh >= 1.0;
                out[((size_t)((t * 8 + b) * 512 + n) << 9) + d] = s ? 1.0f : 0.0f;
                v = s ? 0.0 : hh;
            }
            if (fl) {
                int idx = atomicAdd(ctr + 3, 1);
                if (idx < FCAP) list[idx] = (b << 18) | (n << 9) | d;
            }
        }
    }
}

// ---------------------------------------------------------------------------
// Exact fp64 repair of flagged branch neurons (reads original x layout).
__global__ void fix_mask(const float* __restrict__ x, const float* __restrict__ w,
                         const float* __restrict__ bias,
                         const float* __restrict__ bnw, const float* __restrict__ bnb,
                         const float* __restrict__ bnm, const float* __restrict__ bnv,
                         u64* __restrict__ msk, const int* __restrict__ ctr,
                         const int* __restrict__ list, int slot) {
    int cnt = ctr[slot]; if (cnt > FCAP) cnt = FCAP;
    int wv = (blockIdx.x * blockDim.x + threadIdx.x) >> 6;
    int nw = (gridDim.x * blockDim.x) >> 6;
    int lane = threadIdx.x & 63;
    for (int i = wv; i < cnt; i += nw) {
        int g = list[i];
        int c = g & 511, n = (g >> 9) & 511, b = g >> 18;
        int h = c >> 6;
        const float* wr = w + (size_t)c * 512;
        double dot[4];
        #pragma unroll
        for (int t = 0; t < 4; ++t) {
            const float* xr = x + ((size_t)((t * 8 + b) * 512 + n) << 9);
            double p = 0.0;
            #pragma unroll
            for (int j = 0; j < 8; ++j)
                p += (double)xr[lane + 64 * j] * (double)wr[lane + 64 * j];
            dot[t] = p;
        }
        #pragma unroll
        for (int off = 32; off; off >>= 1) {
            #pragma unroll
            for (int t = 0; t < 4; ++t)
                dot[t] += __shfl_xor(dot[t], off, 64);
        }
        if (lane == 0) {
            double inv = (double)bnw[c] / sqrt((double)bnv[c] + 1e-5);
            double sh  = (double)bnb[c] - (double)bnm[c] * inv;
            double bs  = (double)bias[c];
            double v = 0.0;
            u64 bit = 1ull << (c & 63);
            for (int t = 0; t < 4; ++t) {
                double y = (dot[t] + bs) * inv + sh;
                double hh = v + (y - v) * 0.5;
                bool s = hh >= 1.0;
                u64* wp_ = &msk[((t * 8 + b) * 8 + h) * 512 + n];
                if (s) atomicOr(wp_, bit); else atomicAnd(wp_, ~bit);
                v = s ? 0.0 : hh;
            }
        }
    }
}

// ---------------------------------------------------------------------------
// Fused retention v2 (R15-proven) with truncation-based S-split.
__global__ __launch_bounds__(256) void ret_fused2(
    const u64* __restrict__ qm, const u64* __restrict__ km,
    const u64* __restrict__ vm, const double* __restrict__ pw,
    float* __restrict__ O)
{
    int bid = blockIdx.x;
    int tbh = bid >> 3;
    int n0 = (bid & 7) * 64;
    int h = tbh & 7;
    int tb = tbh >> 3;
    int tid = threadIdx.x;
    int wv = tid >> 6, lane = tid & 63, fr = lane & 15, fg = lane >> 4;
    int wn = wv * 16;

    __shared__ __bf16 Ks[64][72];
    __shared__ u64 VsTg[16][66];
    __shared__ u64 ShTg[4][16][17];
    __shared__ u64 SlTg[4][16][17];
    __shared__ u64 vmc[64];
    __shared__ float pwf[512];

    int base = tbh * 512;
    for (int i = tid; i < 512; i += 256) pwf[i] = (float)pw[h * 512 + i] * 0.125f;

    union U8 { u64 q[2]; bf16x8 v; };

    u64 qw = qm[base + n0 + wn + fr];
    bf16x8 qf[2];
    #pragma unroll
    for (int ks = 0; ks < 2; ++ks) {
        int e0 = ks * 32 + fg * 8;
        u64 plo = 0, phi = 0;
        #pragma unroll
        for (int e = 0; e < 4; ++e) {
            if ((qw >> (e0 + e)) & 1ull)     plo |= 0x3F80ull << (16 * e);
            if ((qw >> (e0 + 4 + e)) & 1ull) phi |= 0x3F80ull << (16 * e);
        }
        U8 u; u.q[0] = plo; u.q[1] = phi; qf[ks] = u.v;
    }

    f32x4 acc_o[4];
    #pragma unroll
    for (int j = 0; j < 4; ++j) acc_o[j] = (f32x4){0.f, 0.f, 0.f, 0.f};

    int nglob = n0 + wn + fr;

    for (int mc = 0; mc < 8; ++mc) {
        __syncthreads();
        {
            int row = tid >> 2, q4 = (tid & 3) * 16;
            u64 kw = km[base + mc * 64 + row];
            #pragma unroll
            for (int s = 0; s < 4; ++s) {
                int e0 = q4 + s * 4;
                u64 pk = 0;
                #pragma unroll
                for (int e = 0; e < 4; ++e)
                    if ((kw >> (e0 + e)) & 1ull) pk |= 0x3F80ull << (16 * e);
                *(u64*)&Ks[row][e0] = pk;
            }
        }
        if (tid < 64) vmc[tid] = vm[base + mc * 64 + tid];
        __syncthreads();
        {
            #pragma unroll
            for (int c = 0; c < 4; ++c) {
                int mg = wv * 4 + c;
                u64 pk = 0;
                #pragma unroll
                for (int e = 0; e < 4; ++e)
                    if ((vmc[mg * 4 + e] >> lane) & 1ull) pk |= 0x3F80ull << (16 * e);
                VsTg[mg][lane] = pk;
            }
        }
        f32x4 accs[4];
        #pragma unroll
        for (int j = 0; j < 4; ++j) accs[j] = (f32x4){0.f, 0.f, 0.f, 0.f};
        #pragma unroll
        for (int ks = 0; ks < 2; ++ks) {
            #pragma unroll
            for (int j = 0; j < 4; ++j) {
                bf16x8 ka = *(const bf16x8*)&Ks[j * 16 + fr][ks * 32 + fg * 8];
                accs[j] = __builtin_amdgcn_mfma_f32_16x16x32_bf16(ka, qf[ks], accs[j], 0, 0, 0);
            }
        }
        // scale + truncation split + pack
        #pragma unroll
        for (int j = 0; j < 4; ++j) {
            u64 ph = 0, pl = 0;
            #pragma unroll
            for (int reg = 0; reg < 4; ++reg) {
                int m = mc * 64 + j * 16 + fg * 4 + reg;
                int dist = nglob - m; if (dist < 0) dist = -dist;
                float a = accs[j][reg] * pwf[dist];
                unsigned ab = __builtin_bit_cast(unsigned, a);
                unsigned hb = ab & 0xFFFF0000u;
                float lp = a - __builtin_bit_cast(float, hb);
                __bf16 lpb = (__bf16)lp;
                ph |= (u64)(ab >> 16) << (16 * reg);
                pl |= (u64)__builtin_bit_cast(unsigned short, lpb) << (16 * reg);
            }
            ShTg[wv][j * 4 + fg][fr] = ph;
            SlTg[wv][j * 4 + fg][fr] = pl;
        }
        __syncthreads();
        #pragma unroll
        for (int ks2 = 0; ks2 < 2; ++ks2) {
            int mga = ks2 * 8 + fg * 2;
            U8 ua, ul;
            ua.q[0] = ShTg[wv][mga][fr];  ua.q[1] = ShTg[wv][mga + 1][fr];
            ul.q[0] = SlTg[wv][mga][fr];  ul.q[1] = SlTg[wv][mga + 1][fr];
            #pragma unroll
            for (int j2 = 0; j2 < 4; ++j2) {
                U8 uv;
                uv.q[0] = VsTg[mga][j2 * 16 + fr];
                uv.q[1] = VsTg[mga + 1][j2 * 16 + fr];
                acc_o[j2] = __builtin_amdgcn_mfma_f32_16x16x32_bf16(ua.v, uv.v, acc_o[j2], 0, 0, 0);
                acc_o[j2] = __builtin_amdgcn_mfma_f32_16x16x32_bf16(ul.v, uv.v, acc_o[j2], 0, 0, 0);
            }
        }
    }

    #pragma unroll
    for (int j2 = 0; j2 < 4; ++j2) {
        int c = h * 64 + j2 * 16 + fr;
        #pragma unroll
        for (int reg = 0; reg < 4; ++reg) {
            int n = n0 + wn + fg * 4 + reg;
            O[((size_t)(tb * 512 + n) << 9) + c] = acc_o[j2][reg];
        }
    }
}

// ---------------------------------------------------------------------------
// Retention LIF: reads O (t,b,n,c); writes bf16 spikes (permuted) + flag.
__global__ void lif_ret_bf2(const float* __restrict__ Y, __bf16* __restrict__ Rb,
                            int* __restrict__ ctr, int* __restrict__ list) {
    int g = blockIdx.x * TPB + threadIdx.x;
    int c = g & 511, n = (g >> 9) & 511, b = g >> 18;
    size_t pbase = ((size_t)(b * 512 + n) * 4) * 512 + c;
    double v = 0.0, eb = 0.0;
    bool flag = false;
    for (int t = 0; t < 4; ++t) {
        size_t idx = ((size_t)((t * 8 + b) * 512 + n) << 9) + c;
        double x = (double)Y[idx];
        double hh = v + (x - v) * 0.5;
        eb = 0.5 * eb + 0.5 * (fabs(x) * 1e-4);
        flag |= fabs(hh - 0.5) <= eb + 1e-9;
        bool s = hh >= 0.5;
        Rb[pbase + (size_t)t * 512] = s ? (__bf16)1.0f : (__bf16)0.0f;
        v = s ? 0.0 : hh;
        if (s) eb = 0.0;
    }
    if (flag) {
        int i2 = atomicAdd(ctr + 4, 1);
        if (i2 < FCAP) list[i2] = g;
    }
}

// Exact fp64 repair of flagged retention neurons; writes permuted Rb.
__global__ void repair_ret_bf2(const u64* __restrict__ qm, const u64* __restrict__ km,
                               const u64* __restrict__ vm, const double* __restrict__ pw,
                               const int* __restrict__ ctr, const int* __restrict__ list,
                               __bf16* __restrict__ Rb) {
    int cnt = ctr[4]; if (cnt > FCAP) cnt = FCAP;
    int wv = (blockIdx.x * blockDim.x + threadIdx.x) >> 6;
    int nw = (gridDim.x * blockDim.x) >> 6;
    int lane = threadIdx.x & 63;
    for (int i = wv; i < cnt; i += nw) {
        int g = list[i];
        int c = g & 511, n = (g >> 9) & 511, b = g >> 18;
        int h = c >> 6, d = c & 63;
        double acc_t[4];
        for (int t = 0; t < 4; ++t) {
            int base = ((t * 8 + b) * 8 + h) * 512;
            u64 qw = qm[base + n];
            double p = 0.0;
            for (int j = 0; j < 8; ++j) {
                int m = j * 64 + lane;
                u64 kk = km[base + m];
                u64 vvm = vm[base + m];
                if ((vvm >> d) & 1ull) {
                    int dist = n - m; if (dist < 0) dist = -dist;
                    p += (double)__popcll(qw & kk) * pw[h * 512 + dist];
                }
            }
            acc_t[t] = p;
        }
        #pragma unroll
        for (int off = 32; off; off >>= 1) {
            #pragma unroll
            for (int t = 0; t < 4; ++t) acc_t[t] += __shfl_xor(acc_t[t], off, 64);
        }
        if (lane == 0) {
            double v = 0.0;
            size_t pbase = ((size_t)(b * 512 + n) * 4) * 512 + c;
            for (int t = 0; t < 4; ++t) {
                double x = acc_t[t] * 0.125;
                double hh = v + (x - v) * 0.5;
                bool s = hh >= 0.5;
                Rb[pbase + (size_t)t * 512] = s ? (__bf16)1.0f : (__bf16)0.0f;
                v = s ? 0.0 : hh;
            }
        }
    }
}

// ---------------------------------------------------------------------------
// Exact fp64 repair of flagged FINAL neurons; reads permuted Rb; writes d_out.
__global__ void fix_final_direct(const __bf16* __restrict__ rr, const float* __restrict__ w,
                                 const float* __restrict__ bias,
                                 const float* __restrict__ bnw, const float* __restrict__ bnb,
                                 const float* __restrict__ bnm, const float* __restrict__ bnv,
                                 const int* __restrict__ ctr, const int* __restrict__ list,
                                 float* __restrict__ out) {
    int cnt = ctr[3]; if (cnt > FCAP) cnt = FCAP;
    int wv = (blockIdx.x * blockDim.x + threadIdx.x) >> 6;
    int nw = (gridDim.x * blockDim.x) >> 6;
    int lane = threadIdx.x & 63;
    for (int i = wv; i < cnt; i += nw) {
        int g = list[i];
        int c = g & 511, n = (g >> 9) & 511, b = g >> 18;
        const float* wr = w + (size_t)c * 512;
        double dot[4];
        #pragma unroll
        for (int t = 0; t < 4; ++t) {
            const __bf16* xr = rr + ((size_t)(b * 512 + n) * 4 + t) * 512;
            double p = 0.0;
            #pragma unroll
            for (int j = 0; j < 8; ++j)
                p += (double)(float)xr[lane + 64 * j] * (double)wr[lane + 64 * j];
            dot[t] = p;
        }
        #pragma unroll
        for (int off = 32; off; off >>= 1) {
            #pragma unroll
            for (int t = 0; t < 4; ++t)
                dot[t] += __shfl_xor(dot[t], off, 64);
        }
        if (lane == 0) {
            double inv = (double)bnw[c] / sqrt((double)bnv[c] + 1e-5);
            double sh  = (double)bnb[c] - (double)bnm[c] * inv;
            double bs  = (double)bias[c];
            double v = 0.0;
            for (int t = 0; t < 4; ++t) {
                double y = (dot[t] + bs) * inv + sh;
                double hh = v + (y - v) * 0.5;
                bool s = hh >= 1.0;
                out[((size_t)((t * 8 + b) * 512 + n) << 9) + c] = s ? 1.0f : 0.0f;
                v = s ? 0.0 : hh;
            }
        }
    }
}

// ===========================================================================
// Fallback path kernels (R15-proven, used when ws is too small)
// ===========================================================================
__global__ __launch_bounds__(256) void gemm_bn_mfma(
    const float* __restrict__ A, const float* __restrict__ W,
    const float* __restrict__ bias,
    const float* __restrict__ bnw, const float* __restrict__ bnb,
    const float* __restrict__ bnm, const float* __restrict__ bnv,
    float* __restrict__ out)
{
    __shared__ __bf16 Ah[128][36];
    __shared__ __bf16 Al[128][36];
    __shared__ __bf16 Wh[64][36];
    __shared__ __bf16 Wl[64][36];

    const int tid = threadIdx.x;
    const int m0 = blockIdx.x * 128;
    const int d0 = blockIdx.y * 64;
    const int wv = tid >> 6;
    const int wm = wv >> 1;
    const int wd = wv & 1;
    const int lane = tid & 63;
    const int fr = lane & 15;
    const int fg = lane >> 4;
    const int srow = tid >> 3;
    const int scol = (tid & 7) * 4;

    f32x4 acc[4][2];
    #pragma unroll
    for (int i = 0; i < 4; ++i)
        #pragma unroll
        for (int j = 0; j < 2; ++j)
            acc[i][j] = (f32x4){0.f, 0.f, 0.f, 0.f};

    for (int k0 = 0; k0 < 512; k0 += 32) {
        __syncthreads();
        #pragma unroll
        for (int rep = 0; rep < 4; ++rep) {
            int row = srow + 32 * rep;
            float4 va = *(const float4*)(A + (size_t)(m0 + row) * 512 + k0 + scol);
            #pragma unroll
            for (int e = 0; e < 4; ++e) {
                float f = (&va.x)[e];
                __bf16 h = (__bf16)f;
                Ah[row][scol + e] = h;
                Al[row][scol + e] = (__bf16)(f - (float)h);
            }
        }
        #pragma unroll
        for (int rep = 0; rep < 2; ++rep) {
            int row = srow + 32 * rep;
            float4 vw = *(const float4*)(W + (size_t)(d0 + row) * 512 + k0 + scol);
            #pragma unroll
            for (int e = 0; e < 4; ++e) {
                float f = (&vw.x)[e];
                __bf16 h = (__bf16)f;
                Wh[row][scol + e] = h;
                Wl[row][scol + e] = (__bf16)(f - (float)h);
            }
        }
        __syncthreads();

        union FU { bf16x8 v8; struct { __bf16 a[4], b[4]; } s; };
        bf16x8 ah[4], al[4], bh[2], bl[2];
        #pragma unroll
        for (int i = 0; i < 4; ++i) {
            int row = wm * 64 + i * 16 + fr;
            FU u1, u2;
            *(double*)&u1.s.a[0] = *(const double*)&Ah[row][fg * 8];
            *(double*)&u1.s.b[0] = *(const double*)&Ah[row][fg * 8 + 4];
            *(double*)&u2.s.a[0] = *(const double*)&Al[row][fg * 8];
            *(double*)&u2.s.b[0] = *(const double*)&Al[row][fg * 8 + 4];
            ah[i] = u1.v8; al[i] = u2.v8;
        }
        #pragma unroll
        for (int j = 0; j < 2; ++j) {
            int row = wd * 32 + j * 16 + fr;
            FU u1, u2;
            *(double*)&u1.s.a[0] = *(const double*)&Wh[row][fg * 8];
            *(double*)&u1.s.b[0] = *(const double*)&Wh[row][fg * 8 + 4];
            *(double*)&u2.s.a[0] = *(const double*)&Wl[row][fg * 8];
            *(double*)&u2.s.b[0] = *(const double*)&Wl[row][fg * 8 + 4];
            bh[j] = u1.v8; bl[j] = u2.v8;
        }
        #pragma unroll
        for (int i = 0; i < 4; ++i)
            #pragma unroll
            for (int j = 0; j < 2; ++j) {
                acc[i][j] = __builtin_amdgcn_mfma_f32_16x16x32_bf16(ah[i], bh[j], acc[i][j], 0, 0, 0);
                acc[i][j] = __builtin_amdgcn_mfma_f32_16x16x32_bf16(ah[i], bl[j], acc[i][j], 0, 0, 0);
                acc[i][j] = __builtin_amdgcn_mfma_f32_16x16x32_bf16(al[i], bh[j], acc[i][j], 0, 0, 0);
            }
    }

    #pragma unroll
    for (int j = 0; j < 2; ++j) {
        int d = d0 + wd * 32 + j * 16 + fr;
        double inv = (double)bnw[d] / sqrt((double)bnv[d] + 1e-5);
        double sh  = (double)bnb[d] - (double)bnm[d] * inv;
        double bs  = (double)bias[d];
        #pragma unroll
        for (int i = 0; i < 4; ++i) {
            #pragma unroll
            for (int reg = 0; reg < 4; ++reg) {
                int m = m0 + wm * 64 + i * 16 + fg * 4 + reg;
                out[(size_t)m * 512 + d] = (float)(((double)acc[i][j][reg] + bs) * inv + sh);
            }
        }
    }
}

__global__ void lif_mask_flag(const float* __restrict__ Y, u64* __restrict__ msk,
                              int* __restrict__ ctr, int* __restrict__ list, int slot) {
    int g = blockIdx.x * TPB + threadIdx.x;
    int c = g & 511, n = (g >> 9) & 511, b = g >> 18;
    int h = c >> 6;
    int lane = threadIdx.x & 63;
    double v = 0.0;
    bool flag = false;
    for (int t = 0; t < 4; ++t) {
        float y = Y[((size_t)((t * 8 + b) * 512 + n) << 9) + c];
        double hh = v + ((double)y - v) * 0.5;
        flag |= fabs(hh - 1.0) < MARGIN;
        bool s = hh >= 1.0;
        u64 mk = __ballot(s);
        if (lane == 0) msk[((t * 8 + b) * 8 + h) * 512 + n] = mk;
        v = s ? 0.0 : hh;
    }
    if (flag) {
        int idx = atomicAdd(ctr + slot, 1);
        if (idx < FCAP) list[idx] = g;
    }
}

__global__ void lif_ret_f(const float* __restrict__ Y, float* __restrict__ R,
                          int* __restrict__ ctr, int* __restrict__ list) {
    int g = blockIdx.x * TPB + threadIdx.x;
    int c = g & 511, n = (g >> 9) & 511, b = g >> 18;
    double v = 0.0, eb = 0.0;
    bool flag = false;
    for (int t = 0; t < 4; ++t) {
        size_t idx = ((size_t)((t * 8 + b) * 512 + n) << 9) + c;
        double x = (double)Y[idx];
        double hh = v + (x - v) * 0.5;
        eb = 0.5 * eb + 0.5 * (fabs(x) * 1e-4);
        flag |= fabs(hh - 0.5) <= eb + 1e-9;
        bool s = hh >= 0.5;
        R[idx] = s ? 1.0f : 0.0f;
        v = s ? 0.0 : hh;
        if (s) eb = 0.0;
    }
    if (flag) {
        int i2 = atomicAdd(ctr + 4, 1);
        if (i2 < FCAP) list[i2] = g;
    }
}

__global__ void repair_ret_f(const u64* __restrict__ qm, const u64* __restrict__ km,
                             const u64* __restrict__ vm, const double* __restrict__ pw,
                             const int* __restrict__ ctr, const int* __restrict__ list,
                             float* __restrict__ r) {
    int cnt = ctr[4]; if (cnt > FCAP) cnt = FCAP;
    int wv = (blockIdx.x * blockDim.x + threadIdx.x) >> 6;
    int nw = (gridDim.x * blockDim.x) >> 6;
    int lane = threadIdx.x & 63;
    for (int i = wv; i < cnt; i += nw) {
        int g = list[i];
        int c = g & 511, n = (g >> 9) & 511, b = g >> 18;
        int h = c >> 6, d = c & 63;
        double acc_t[4];
        for (int t = 0; t < 4; ++t) {
            int base = ((t * 8 + b) * 8 + h) * 512;
            u64 qw = qm[base + n];
            double p = 0.0;
            for (int j = 0; j < 8; ++j) {
                int m = j * 64 + lane;
                u64 kk = km[base + m];
                u64 vvm = vm[base + m];
                if ((vvm >> d) & 1ull) {
                    int dist = n - m; if (dist < 0) dist = -dist;
                    p += (double)__popcll(qw & kk) * pw[h * 512 + dist];
                }
            }
            acc_t[t] = p;
        }
        #pragma unroll
        for (int off = 32; off; off >>= 1) {
            #pragma unroll
            for (int t = 0; t < 4; ++t) acc_t[t] += __shfl_xor(acc_t[t], off, 64);
        }
        if (lane == 0) {
            double v = 0.0;
            for (int t = 0; t < 4; ++t) {
                double x = acc_t[t] * 0.125;
                double hh = v + (x - v) * 0.5;
                bool s = hh >= 0.5;
                r[((size_t)((t * 8 + b) * 512 + n) << 9) + c] = s ? 1.0f : 0.0f;
                v = s ? 0.0 : hh;
            }
        }
    }
}

__global__ void final_flag(const float* __restrict__ Y, int* __restrict__ ctr,
                           int* __restrict__ list) {
    int g = blockIdx.x * TPB + threadIdx.x;
    int c = g & 511, n = (g >> 9) & 511, b = g >> 18;
    double v = 0.0;
    bool flag = false;
    for (int t = 0; t < 4; ++t) {
        float y = Y[((size_t)((t * 8 + b) * 512 + n) << 9) + c];
        double hh = v + ((double)y - v) * 0.5;
        flag |= fabs(hh - 1.0) < MARGIN;
        bool s = hh >= 1.0;
        v = s ? 0.0 : hh;
    }
    if (flag) {
        int idx = atomicAdd(ctr + 3, 1);
        if (idx < FCAP) list[idx] = g;
    }
}

__global__ void fix_final_f(const float* __restrict__ rr, const float* __restrict__ w,
                            const float* __restrict__ bias,
                            const float* __restrict__ bnw, const float* __restrict__ bnb,
                            const float* __restrict__ bnm, const float* __restrict__ bnv,
                            const int* __restrict__ ctr, int* __restrict__ list) {
    int cnt = ctr[3]; if (cnt > FCAP) cnt = FCAP;
    int wv = (blockIdx.x * blockDim.x + threadIdx.x) >> 6;
    int nw = (gridDim.x * blockDim.x) >> 6;
    int lane = threadIdx.x & 63;
    for (int i = wv; i < cnt; i += nw) {
        int g = list[i] & 0x00FFFFFF;
        int c = g & 511, n = (g >> 9) & 511, b = g >> 18;
        const float* wr = w + (size_t)c * 512;
        double dot[4];
        #pragma unroll
        for (int t = 0; t < 4; ++t) {
            const float* xr = rr + ((size_t)((t * 8 + b) * 512 + n) << 9);
            double p = 0.0;
            #pragma unroll
            for (int j = 0; j < 8; ++j)
                p += (double)xr[lane + 64 * j] * (double)wr[lane + 64 * j];
            dot[t] = p;
        }
        #pragma unroll
        for (int off = 32; off; off >>= 1) {
            #pragma unroll
            for (int t = 0; t < 4; ++t)
                dot[t] += __shfl_xor(dot[t], off, 64);
        }
        if (lane == 0) {
            double inv = (double)bnw[c] / sqrt((double)bnv[c] + 1e-5);
            double sh  = (double)bnb[c] - (double)bnm[c] * inv;
            double bs  = (double)bias[c];
            double v = 0.0;
            int sp = 0;
            for (int t = 0; t < 4; ++t) {
                double y = (dot[t] + bs) * inv + sh;
                double hh = v + (y - v) * 0.5;
                bool s = hh >= 1.0;
                sp |= (s ? 1 : 0) << t;
                v = s ? 0.0 : hh;
            }
            list[i] = g | (sp << 24);
        }
    }
}

__global__ void final_write(const float* __restrict__ Y, float* __restrict__ out) {
    int g = blockIdx.x * TPB + threadIdx.x;
    int c = g & 511, n = (g >> 9) & 511, b = g >> 18;
    double v = 0.0;
    for (int t = 0; t < 4; ++t) {
        size_t idx = ((size_t)((t * 8 + b) * 512 + n) << 9) + c;
        float y = Y[idx];
        double hh = v + ((double)y - v) * 0.5;
        bool s = hh >= 1.0;
        out[idx] = s ? 1.0f : 0.0f;
        v = s ? 0.0 : hh;
    }
}

__global__ void fix_scatter(const int* __restrict__ ctr, const int* __restrict__ list,
                            float* __restrict__ out) {
    int cnt = ctr[3]; if (cnt > FCAP) cnt = FCAP;
    int i = blockIdx.x * blockDim.x + threadIdx.x;
    if (i >= cnt) return;
    int e = list[i];
    int g = e & 0x00FFFFFF, sp = (e >> 24) & 0xF;
    int c = g & 511, n = (g >> 9) & 511, b = g >> 18;
    for (int t = 0; t < 4; ++t)
        out[((size_t)((t * 8 + b) * 512 + n) << 9) + c] = ((sp >> t) & 1) ? 1.0f : 0.0f;
}

// ---------------------------------------------------------------------------
extern "C" void kernel_launch(void* const* d_in, const int* in_sizes, int n_in,
                              void* d_out, int out_size, void* d_ws, size_t ws_size,
                              hipStream_t stream) {
    const float* x = (const float*)d_in[0];
    const float *w[4], *bi[4], *bnw[4], *bnb[4], *bnm[4], *bnv[4];
    for (int br = 0; br < 4; ++br) {
        int base = 1 + br * 6;
        w[br]   = (const float*)d_in[base + 0];
        bi[br]  = (const float*)d_in[base + 1];
        bnw[br] = (const float*)d_in[base + 2];
        bnb[br] = (const float*)d_in[base + 3];
        bnm[br] = (const float*)d_in[base + 4];
        bnv[br] = (const float*)d_in[base + 5];
    }

    const size_t NX = (size_t)16384 * 512;
    char* p = (char*)d_ws;
    double* pw = (double*)p;  p += 8 * 512 * sizeof(double);
    u64* qm = (u64*)p;        p += 131072 * sizeof(u64);
    u64* km = (u64*)p;        p += 131072 * sizeof(u64);
    u64* vm = (u64*)p;        p += 131072 * sizeof(u64);
    int* ctr = (int*)p;       p += 1024;
    int* list = (int*)p;      p += (size_t)FCAP * sizeof(int);
    float* Y = (float*)p;     p += NX * 4;
    __bf16* Xh = (__bf16*)p;  p += NX * 2;
    __bf16* Xl = (__bf16*)p;  p += NX * 2;
    __bf16* Wsp = (__bf16*)p; p += (size_t)4 * 2 * 262144 * 2;
    size_t need_fast = (size_t)(p - (char*)d_ws);
    int fast = ws_size >= need_fast;

    init_kernel<<<1, 64, 0, stream>>>(pw, ctr);

    dim3 g2(128, 4);
    dim3 gg(128, 8);

    if (fast) {
        split_all<<<8192 + 1024, 256, 0, stream>>>(x, w[0], w[1], w[2], w[3], Xh, Xl, Wsp);
        for (int br = 0; br < 3; ++br) {
            u64* msk = br == 0 ? qm : (br == 1 ? km : vm);
            gemm_lif_mask<<<g2, 256, 0, stream>>>(Xh, Xl,
                Wsp + (size_t)br * 524288, Wsp + (size_t)br * 524288 + 262144,
                bi[br], bnw[br], bnb[br], bnm[br], bnv[br], msk, ctr, list, br);
            fix_mask<<<128, 256, 0, stream>>>(x, w[br], bi[br], bnw[br], bnb[br],
                                              bnm[br], bnv[br], msk, ctr, list, br);
        }
        // retention -> Y; LIF -> bf16 spikes (permuted) in Xh; exact repair
        ret_fused2<<<2048, 256, 0, stream>>>(qm, km, vm, pw, Y);
        lif_ret_bf2<<<8192, TPB, 0, stream>>>(Y, Xh, ctr, list);
        repair_ret_bf2<<<256, 256, 0, stream>>>(qm, km, vm, pw, ctr, list, Xh);
        // p projection + fused final LIF -> d_out; exact repair direct
        gemm_final_lif<<<g2, 256, 0, stream>>>(Xh,
            Wsp + (size_t)3 * 524288, Wsp + (size_t)3 * 524288 + 262144,
            bi[3], bnw[3], bnb[3], bnm[3], bnv[3], (float*)d_out, ctr, list);
        fix_final_direct<<<128, 256, 0, stream>>>(Xh, w[3], bi[3], bnw[3], bnb[3],
                                                  bnm[3], bnv[3], ctr, list, (float*)d_out);
    } else {
        for (int br = 0; br < 3; ++br) {
            u64* msk = br == 0 ? qm : (br == 1 ? km : vm);
            gemm_bn_mfma<<<gg, 256, 0, stream>>>(x, w[br], bi[br], bnw[br], bnb[br],
                                                 bnm[br], bnv[br], Y);
            lif_mask_flag<<<8192, TPB, 0, stream>>>(Y, msk, ctr, list, br);
            fix_mask<<<128, 256, 0, stream>>>(x, w[br], bi[br], bnw[br], bnb[br],
                                              bnm[br], bnv[br], msk, ctr, list, br);
        }
        float* r = (float*)d_out;
        ret_fused2<<<2048, 256, 0, stream>>>(qm, km, vm, pw, Y);
        lif_ret_f<<<8192, TPB, 0, stream>>>(Y, r, ctr, list);
        repair_ret_f<<<256, 256, 0, stream>>>(qm, km, vm, pw, ctr, list, r);
        gemm_bn_mfma<<<gg, 256, 0, stream>>>(r, w[3], bi[3], bnw[3], bnb[3],
                                             bnm[3], bnv[3], Y);
        final_flag<<<8192, TPB, 0, stream>>>(Y, ctr, list);
        fix_final_f<<<128, 256, 0, stream>>>(r, w[3], bi[3], bnw[3], bnb[3],
                                             bnm[3], bnv[3], ctr, list);
        final_write<<<8192, TPB, 0, stream>>>(Y, (float*)d_out);
        fix_scatter<<<4096, 256, 0, stream>>>(ctr, list, (float*)d_out);
    }
}

// Round 19
// 269.568 us; speedup vs baseline: 1.3592x; 1.0284x over previous
//
#include <hip/hip_runtime.h>
#include <cstdint>

typedef unsigned long long u64;

#define TPB 256
#define MARGIN 5e-4
#define FCAP (1 << 20)

typedef __bf16 bf16x8 __attribute__((ext_vector_type(8)));
typedef __bf16 bf16x4 __attribute__((ext_vector_type(4)));
typedef float f32x4 __attribute__((ext_vector_type(4)));

typedef __attribute__((address_space(1))) void GV;
typedef __attribute__((address_space(3))) void LV;
typedef __attribute__((address_space(3))) char LC;

#define GLD(gsrc, ldst) __builtin_amdgcn_global_load_lds( \
    (GV*)(void*)(gsrc), (LV*)(ldst), 16, 0, 0)

// ---------------------------------------------------------------------------
__global__ void init_kernel(double* __restrict__ pw, int* __restrict__ ctr) {
    int h = threadIdx.x;
    if (h < 8) {
        double gamma = 1.0 - ldexp(1.0, -5 - h);
        double p = 1.0;
        for (int i = 0; i < 512; ++i) { pw[h * 512 + i] = p; p *= gamma; }
        ctr[h] = 0;
    }
}

// ---------------------------------------------------------------------------
// Combined split. x rows PERMUTED to m' = (b*512+n)*4 + t (reg index == t).
__global__ void split_all(const float* __restrict__ x,
                          const float* __restrict__ w0, const float* __restrict__ w1,
                          const float* __restrict__ w2, const float* __restrict__ w3,
                          __bf16* __restrict__ Xh, __bf16* __restrict__ Xl,
                          __bf16* __restrict__ Wsp) {
    int blk = blockIdx.x;
    if (blk < 8192) {
        size_t i = (size_t)blk * 1024 + threadIdx.x * 4;
        int m = (int)(i >> 9), c = (int)(i & 511);
        int mp = (m & 4095) * 4 + (m >> 12);
        float4 v = *(const float4*)(x + i);
        bf16x4 h4, l4;
        #pragma unroll
        for (int e = 0; e < 4; ++e) {
            float f = (&v.x)[e];
            __bf16 hh = (__bf16)f;
            h4[e] = hh;
            l4[e] = (__bf16)(f - (float)hh);
        }
        size_t dst = (size_t)mp * 512 + c;
        *(bf16x4*)(Xh + dst) = h4;
        *(bf16x4*)(Xl + dst) = l4;
    } else {
        int wb = blk - 8192;
        int br = wb >> 8;
        const float* ws[4] = {w0, w1, w2, w3};
        const float* src = ws[br];
        __bf16* hi = Wsp + (size_t)br * 524288;
        __bf16* lo = hi + 262144;
        size_t i = (size_t)(wb & 255) * 1024 + threadIdx.x * 4;
        float4 v = *(const float4*)(src + i);
        bf16x4 h4, l4;
        #pragma unroll
        for (int e = 0; e < 4; ++e) {
            float f = (&v.x)[e];
            __bf16 hh = (__bf16)f;
            h4[e] = hh;
            l4[e] = (__bf16)(f - (float)hh);
        }
        *(bf16x4*)(hi + i) = h4;
        *(bf16x4*)(lo + i) = l4;
    }
}

// ---------------------------------------------------------------------------
// Branch GEMM (3-pass) via DOUBLE-BUFFERED global_load_lds staging
// (linear LDS, source-swizzle col16' = col16 ^ ((row>>1)&3)) + fused
// BN/LIF/mask epilogue. Rows are m' = bn*4 + t.
__global__ __launch_bounds__(256) void gemm_lif_mask(
    const __bf16* __restrict__ Ahg, const __bf16* __restrict__ Alg,
    const __bf16* __restrict__ Whg, const __bf16* __restrict__ Wlg,
    const float* __restrict__ bias,
    const float* __restrict__ bnw, const float* __restrict__ bnb,
    const float* __restrict__ bnm, const float* __restrict__ bnv,
    u64* __restrict__ msk, int* __restrict__ ctr, int* __restrict__ list, int slot)
{
    __shared__ __bf16 AhS[2][128][32];   // 8 KB per buffer
    __shared__ __bf16 AlS[2][128][32];
    __shared__ __bf16 WhS[2][128][32];
    __shared__ __bf16 WlS[2][128][32];

    const int tid = threadIdx.x;
    const int m0 = blockIdx.x * 128;
    const int d0 = blockIdx.y * 128;
    const int wv = tid >> 6;
    const int wm = wv >> 1;
    const int wd = wv & 1;
    const int lane = tid & 63;
    const int fr = lane & 15;
    const int fg = lane >> 4;

    const int lr   = lane >> 2;
    const int csrc = (lane & 3) ^ ((lane >> 3) & 3);
    const int rA0  = wv * 32 + lr;
    const __bf16* gAh0 = Ahg + (size_t)(m0 + rA0) * 512 + csrc * 8;
    const __bf16* gAh1 = gAh0 + (size_t)16 * 512;
    const __bf16* gAl0 = Alg + (size_t)(m0 + rA0) * 512 + csrc * 8;
    const __bf16* gAl1 = gAl0 + (size_t)16 * 512;
    const __bf16* gWh0 = Whg + (size_t)(d0 + rA0) * 512 + csrc * 8;
    const __bf16* gWh1 = gWh0 + (size_t)16 * 512;
    const __bf16* gWl0 = Wlg + (size_t)(d0 + rA0) * 512 + csrc * 8;
    const __bf16* gWl1 = gWl0 + (size_t)16 * 512;

    unsigned ldsOff = __builtin_amdgcn_readfirstlane((unsigned)(wv * 2048));
    LC* lAh = (LC*)(LV*)&AhS[0][0][0] + ldsOff;
    LC* lAl = (LC*)(LV*)&AlS[0][0][0] + ldsOff;
    LC* lWh = (LC*)(LV*)&WhS[0][0][0] + ldsOff;
    LC* lWl = (LC*)(LV*)&WlS[0][0][0] + ldsOff;

    const int fcol = (fg ^ ((fr >> 1) & 3)) * 16;

    f32x4 acc[4][4];
    #pragma unroll
    for (int i = 0; i < 4; ++i)
        #pragma unroll
        for (int j = 0; j < 4; ++j)
            acc[i][j] = (f32x4){0.f, 0.f, 0.f, 0.f};

    // prologue: stage k0=0 into buf 0
    GLD(gAh0, lAh); GLD(gAh1, lAh + 1024);
    GLD(gAl0, lAl); GLD(gAl1, lAl + 1024);
    GLD(gWh0, lWh); GLD(gWh1, lWh + 1024);
    GLD(gWl0, lWl); GLD(gWl1, lWl + 1024);

    #pragma unroll
    for (int kk = 0; kk < 16; ++kk) {
        const int k0 = kk * 32;
        const int cur = kk & 1;
        const int nxt = cur ^ 1;
        __syncthreads();   // drains GLDs for buf[cur]; prior reads of buf[nxt] done
        if (kk < 15) {     // issue next tile into buf[nxt], flies under MFMA
            GLD(gAh0 + k0 + 32, lAh + nxt * 8192); GLD(gAh1 + k0 + 32, lAh + nxt * 8192 + 1024);
            GLD(gAl0 + k0 + 32, lAl + nxt * 8192); GLD(gAl1 + k0 + 32, lAl + nxt * 8192 + 1024);
            GLD(gWh0 + k0 + 32, lWh + nxt * 8192); GLD(gWh1 + k0 + 32, lWh + nxt * 8192 + 1024);
            GLD(gWl0 + k0 + 32, lWl + nxt * 8192); GLD(gWl1 + k0 + 32, lWl + nxt * 8192 + 1024);
        }

        bf16x8 ah[4], bh[4], bl[4];
        #pragma unroll
        for (int i = 0; i < 4; ++i) {
            int row = wm * 64 + i * 16 + fr;
            ah[i] = *(const bf16x8*)((const char*)&AhS[cur][0][0] + row * 64 + fcol);
        }
        #pragma unroll
        for (int j = 0; j < 4; ++j) {
            int row = wd * 64 + j * 16 + fr;
            bh[j] = *(const bf16x8*)((const char*)&WhS[cur][0][0] + row * 64 + fcol);
            bl[j] = *(const bf16x8*)((const char*)&WlS[cur][0][0] + row * 64 + fcol);
        }
        #pragma unroll
        for (int i = 0; i < 4; ++i)
            #pragma unroll
            for (int j = 0; j < 4; ++j) {
                acc[i][j] = __builtin_amdgcn_mfma_f32_16x16x32_bf16(ah[i], bh[j], acc[i][j], 0, 0, 0);
                acc[i][j] = __builtin_amdgcn_mfma_f32_16x16x32_bf16(ah[i], bl[j], acc[i][j], 0, 0, 0);
            }
        bf16x8 al[4];
        #pragma unroll
        for (int i = 0; i < 4; ++i) {
            int row = wm * 64 + i * 16 + fr;
            al[i] = *(const bf16x8*)((const char*)&AlS[cur][0][0] + row * 64 + fcol);
        }
        #pragma unroll
        for (int i = 0; i < 4; ++i)
            #pragma unroll
            for (int j = 0; j < 4; ++j)
                acc[i][j] = __builtin_amdgcn_mfma_f32_16x16x32_bf16(al[i], bh[j], acc[i][j], 0, 0, 0);
    }

    // ---- epilogue: BN + LIF(1.0) + mask ballots + margin flags (R16-proven)
    double invj[4], shj[4], bsj[4];
    #pragma unroll
    for (int j = 0; j < 4; ++j) {
        int d = d0 + wd * 64 + j * 16 + fr;
        invj[j] = (double)bnw[d] / sqrt((double)bnv[d] + 1e-5);
        shj[j]  = (double)bnb[d] - (double)bnm[d] * invj[j];
        bsj[j]  = (double)bias[d];
    }
    int hword = (d0 >> 6) + wd;
    int bn0 = blockIdx.x * 32 + wm * 16;

    #pragma unroll
    for (int i = 0; i < 4; ++i) {
        int bn = bn0 + i * 4 + fg;
        int b = bn >> 9, n = bn & 511;
        u64 w[4] = {0ull, 0ull, 0ull, 0ull};
        #pragma unroll
        for (int j = 0; j < 4; ++j) {
            double v = 0.0;
            bool fl = false;
            #pragma unroll
            for (int t = 0; t < 4; ++t) {
                double y = ((double)acc[i][j][t] + bsj[j]) * invj[j] + shj[j];
                double hh = v + (y - v) * 0.5;
                fl |= fabs(hh - 1.0) < MARGIN;
                bool s = hh >= 1.0;
                u64 blt = __ballot(s);
                w[t] |= ((blt >> (fg * 16)) & 0xFFFFull) << (j * 16);
                v = s ? 0.0 : hh;
            }
            if (fl) {
                int d = d0 + wd * 64 + j * 16 + fr;
                int idx = atomicAdd(ctr + slot, 1);
                if (idx < FCAP) list[idx] = (b << 18) | (n << 9) | d;
            }
        }
        if (fr == 0) {
            #pragma unroll
            for (int t = 0; t < 4; ++t)
                msk[((t * 8 + b) * 8 + hword) * 512 + n] = w[t];
        }
    }
}

// ---------------------------------------------------------------------------
// Final GEMM (2-pass, A exact) with double-buffered GLD + fused final LIF.
__global__ __launch_bounds__(256) void gemm_final_lif(
    const __bf16* __restrict__ Ahg,
    const __bf16* __restrict__ Whg, const __bf16* __restrict__ Wlg,
    const float* __restrict__ bias,
    const float* __restrict__ bnw, const float* __restrict__ bnb,
    const float* __restrict__ bnm, const float* __restrict__ bnv,
    float* __restrict__ out, int* __restrict__ ctr, int* __restrict__ list)
{
    __shared__ __bf16 AhS[2][128][32];
    __shared__ __bf16 WhS[2][128][32];
    __shared__ __bf16 WlS[2][128][32];

    const int tid = threadIdx.x;
    const int m0 = blockIdx.x * 128;
    const int d0 = blockIdx.y * 128;
    const int wv = tid >> 6;
    const int wm = wv >> 1;
    const int wd = wv & 1;
    const int lane = tid & 63;
    const int fr = lane & 15;
    const int fg = lane >> 4;

    const int lr   = lane >> 2;
    const int csrc = (lane & 3) ^ ((lane >> 3) & 3);
    const int rA0  = wv * 32 + lr;
    const __bf16* gAh0 = Ahg + (size_t)(m0 + rA0) * 512 + csrc * 8;
    const __bf16* gAh1 = gAh0 + (size_t)16 * 512;
    const __bf16* gWh0 = Whg + (size_t)(d0 + rA0) * 512 + csrc * 8;
    const __bf16* gWh1 = gWh0 + (size_t)16 * 512;
    const __bf16* gWl0 = Wlg + (size_t)(d0 + rA0) * 512 + csrc * 8;
    const __bf16* gWl1 = gWl0 + (size_t)16 * 512;

    unsigned ldsOff = __builtin_amdgcn_readfirstlane((unsigned)(wv * 2048));
    LC* lAh = (LC*)(LV*)&AhS[0][0][0] + ldsOff;
    LC* lWh = (LC*)(LV*)&WhS[0][0][0] + ldsOff;
    LC* lWl = (LC*)(LV*)&WlS[0][0][0] + ldsOff;

    const int fcol = (fg ^ ((fr >> 1) & 3)) * 16;

    f32x4 acc[4][4];
    #pragma unroll
    for (int i = 0; i < 4; ++i)
        #pragma unroll
        for (int j = 0; j < 4; ++j)
            acc[i][j] = (f32x4){0.f, 0.f, 0.f, 0.f};

    GLD(gAh0, lAh); GLD(gAh1, lAh + 1024);
    GLD(gWh0, lWh); GLD(gWh1, lWh + 1024);
    GLD(gWl0, lWl); GLD(gWl1, lWl + 1024);

    #pragma unroll
    for (int kk = 0; kk < 16; ++kk) {
        const int k0 = kk * 32;
        const int cur = kk & 1;
        const int nxt = cur ^ 1;
        __syncthreads();
        if (kk < 15) {
            GLD(gAh0 + k0 + 32, lAh + nxt * 8192); GLD(gAh1 + k0 + 32, lAh + nxt * 8192 + 1024);
            GLD(gWh0 + k0 + 32, lWh + nxt * 8192); GLD(gWh1 + k0 + 32, lWh + nxt * 8192 + 1024);
            GLD(gWl0 + k0 + 32, lWl + nxt * 8192); GLD(gWl1 + k0 + 32, lWl + nxt * 8192 + 1024);
        }

        bf16x8 ah[4], bh[4], bl[4];
        #pragma unroll
        for (int i = 0; i < 4; ++i) {
            int row = wm * 64 + i * 16 + fr;
            ah[i] = *(const bf16x8*)((const char*)&AhS[cur][0][0] + row * 64 + fcol);
        }
        #pragma unroll
        for (int j = 0; j < 4; ++j) {
            int row = wd * 64 + j * 16 + fr;
            bh[j] = *(const bf16x8*)((const char*)&WhS[cur][0][0] + row * 64 + fcol);
            bl[j] = *(const bf16x8*)((const char*)&WlS[cur][0][0] + row * 64 + fcol);
        }
        #pragma unroll
        for (int i = 0; i < 4; ++i)
            #pragma unroll
            for (int j = 0; j < 4; ++j) {
                acc[i][j] = __builtin_amdgcn_mfma_f32_16x16x32_bf16(ah[i], bh[j], acc[i][j], 0, 0, 0);
                acc[i][j] = __builtin_amdgcn_mfma_f32_16x16x32_bf16(ah[i], bl[j], acc[i][j], 0, 0, 0);
            }
    }

    double invj[4], shj[4], bsj[4];
    #pragma unroll
    for (int j = 0; j < 4; ++j) {
        int d = d0 + wd * 64 + j * 16 + fr;
        invj[j] = (double)bnw[d] / sqrt((double)bnv[d] + 1e-5);
        shj[j]  = (double)bnb[d] - (double)bnm[d] * invj[j];
        bsj[j]  = (double)bias[d];
    }
    int bn0 = blockIdx.x * 32 + wm * 16;

    #pragma unroll
    for (int i = 0; i < 4; ++i) {
        int bn = bn0 + i * 4 + fg;
        int b = bn >> 9, n = bn & 511;
        #pragma unroll
        for (int j = 0; j < 4; ++j) {
            int d = d0 + wd * 64 + j * 16 + fr;
            double v = 0.0;
            bool fl = false;
            #pragma unroll
            for (int t = 0; t < 4; ++t) {
                double y = ((double)acc[i][j][t] + bsj[j]) * invj[j] + shj[j];
                double hh = v + (y - v) * 0.5;
                fl |= fabs(hh - 1.0) < MARGIN;
                bool s = hh >= 1.0;
                out[((size_t)((t * 8 + b) * 512 + n) << 9) + d] = s ? 1.0f : 0.0f;
                v = s ? 0.0 : hh;
            }
            if (fl) {
                int idx = atomicAdd(ctr + 3, 1);
                if (idx < FCAP) list[idx] = (b << 18) | (n << 9) | d;
            }
        }
    }
}

// ---------------------------------------------------------------------------
// Exact fp64 repair of flagged branch neurons (reads original x layout).
__global__ void fix_mask(const float* __restrict__ x, const float* __restrict__ w,
                         const float* __restrict__ bias,
                         const float* __restrict__ bnw, const float* __restrict__ bnb,
                         const float* __restrict__ bnm, const float* __restrict__ bnv,
                         u64* __restrict__ msk, const int* __restrict__ ctr,
                         const int* __restrict__ list, int slot) {
    int cnt = ctr[slot]; if (cnt > FCAP) cnt = FCAP;
    int wv = (blockIdx.x * blockDim.x + threadIdx.x) >> 6;
    int nw = (gridDim.x * blockDim.x) >> 6;
    int lane = threadIdx.x & 63;
    for (int i = wv; i < cnt; i += nw) {
        int g = list[i];
        int c = g & 511, n = (g >> 9) & 511, b = g >> 18;
        int h = c >> 6;
        const float* wr = w + (size_t)c * 512;
        double dot[4];
        #pragma unroll
        for (int t = 0; t < 4; ++t) {
            const float* xr = x + ((size_t)((t * 8 + b) * 512 + n) << 9);
            double p = 0.0;
            #pragma unroll
            for (int j = 0; j < 8; ++j)
                p += (double)xr[lane + 64 * j] * (double)wr[lane + 64 * j];
            dot[t] = p;
        }
        #pragma unroll
        for (int off = 32; off; off >>= 1) {
            #pragma unroll
            for (int t = 0; t < 4; ++t)
                dot[t] += __shfl_xor(dot[t], off, 64);
        }
        if (lane == 0) {
            double inv = (double)bnw[c] / sqrt((double)bnv[c] + 1e-5);
            double sh  = (double)bnb[c] - (double)bnm[c] * inv;
            double bs  = (double)bias[c];
            double v = 0.0;
            u64 bit = 1ull << (c & 63);
            for (int t = 0; t < 4; ++t) {
                double y = (dot[t] + bs) * inv + sh;
                double hh = v + (y - v) * 0.5;
                bool s = hh >= 1.0;
                u64* wp_ = &msk[((t * 8 + b) * 8 + h) * 512 + n];
                if (s) atomicOr(wp_, bit); else atomicAnd(wp_, ~bit);
                v = s ? 0.0 : hh;
            }
        }
    }
}

// ---------------------------------------------------------------------------
// Fused retention v2 (R15/R18-proven, truncation split).
__global__ __launch_bounds__(256) void ret_fused2(
    const u64* __restrict__ qm, const u64* __restrict__ km,
    const u64* __restrict__ vm, const double* __restrict__ pw,
    float* __restrict__ O)
{
    int bid = blockIdx.x;
    int tbh = bid >> 3;
    int n0 = (bid & 7) * 64;
    int h = tbh & 7;
    int tb = tbh >> 3;
    int tid = threadIdx.x;
    int wv = tid >> 6, lane = tid & 63, fr = lane & 15, fg = lane >> 4;
    int wn = wv * 16;

    __shared__ __bf16 Ks[64][72];
    __shared__ u64 VsTg[16][66];
    __shared__ u64 ShTg[4][16][17];
    __shared__ u64 SlTg[4][16][17];
    __shared__ u64 vmc[64];
    __shared__ float pwf[512];

    int base = tbh * 512;
    for (int i = tid; i < 512; i += 256) pwf[i] = (float)pw[h * 512 + i] * 0.125f;

    union U8 { u64 q[2]; bf16x8 v; };

    u64 qw = qm[base + n0 + wn + fr];
    bf16x8 qf[2];
    #pragma unroll
    for (int ks = 0; ks < 2; ++ks) {
        int e0 = ks * 32 + fg * 8;
        u64 plo = 0, phi = 0;
        #pragma unroll
        for (int e = 0; e < 4; ++e) {
            if ((qw >> (e0 + e)) & 1ull)     plo |= 0x3F80ull << (16 * e);
            if ((qw >> (e0 + 4 + e)) & 1ull) phi |= 0x3F80ull << (16 * e);
        }
        U8 u; u.q[0] = plo; u.q[1] = phi; qf[ks] = u.v;
    }

    f32x4 acc_o[4];
    #pragma unroll
    for (int j = 0; j < 4; ++j) acc_o[j] = (f32x4){0.f, 0.f, 0.f, 0.f};

    int nglob = n0 + wn + fr;

    for (int mc = 0; mc < 8; ++mc) {
        __syncthreads();
        {
            int row = tid >> 2, q4 = (tid & 3) * 16;
            u64 kw = km[base + mc * 64 + row];
            #pragma unroll
            for (int s = 0; s < 4; ++s) {
                int e0 = q4 + s * 4;
                u64 pk = 0;
                #pragma unroll
                for (int e = 0; e < 4; ++e)
                    if ((kw >> (e0 + e)) & 1ull) pk |= 0x3F80ull << (16 * e);
                *(u64*)&Ks[row][e0] = pk;
            }
        }
        if (tid < 64) vmc[tid] = vm[base + mc * 64 + tid];
        __syncthreads();
        {
            #pragma unroll
            for (int c = 0; c < 4; ++c) {
                int mg = wv * 4 + c;
                u64 pk = 0;
                #pragma unroll
                for (int e = 0; e < 4; ++e)
                    if ((vmc[mg * 4 + e] >> lane) & 1ull) pk |= 0x3F80ull << (16 * e);
                VsTg[mg][lane] = pk;
            }
        }
        f32x4 accs[4];
        #pragma unroll
        for (int j = 0; j < 4; ++j) accs[j] = (f32x4){0.f, 0.f, 0.f, 0.f};
        #pragma unroll
        for (int ks = 0; ks < 2; ++ks) {
            #pragma unroll
            for (int j = 0; j < 4; ++j) {
                bf16x8 ka = *(const bf16x8*)&Ks[j * 16 + fr][ks * 32 + fg * 8];
                accs[j] = __builtin_amdgcn_mfma_f32_16x16x32_bf16(ka, qf[ks], accs[j], 0, 0, 0);
            }
        }
        #pragma unroll
        for (int j = 0; j < 4; ++j) {
            u64 ph = 0, pl = 0;
            #pragma unroll
            for (int reg = 0; reg < 4; ++reg) {
                int m = mc * 64 + j * 16 + fg * 4 + reg;
                int dist = nglob - m; if (dist < 0) dist = -dist;
                float a = accs[j][reg] * pwf[dist];
                unsigned ab = __builtin_bit_cast(unsigned, a);
                unsigned hb = ab & 0xFFFF0000u;
                float lp = a - __builtin_bit_cast(float, hb);
                __bf16 lpb = (__bf16)lp;
                ph |= (u64)(ab >> 16) << (16 * reg);
                pl |= (u64)__builtin_bit_cast(unsigned short, lpb) << (16 * reg);
            }
            ShTg[wv][j * 4 + fg][fr] = ph;
            SlTg[wv][j * 4 + fg][fr] = pl;
        }
        __syncthreads();
        #pragma unroll
        for (int ks2 = 0; ks2 < 2; ++ks2) {
            int mga = ks2 * 8 + fg * 2;
            U8 ua, ul;
            ua.q[0] = ShTg[wv][mga][fr];  ua.q[1] = ShTg[wv][mga + 1][fr];
            ul.q[0] = SlTg[wv][mga][fr];  ul.q[1] = SlTg[wv][mga + 1][fr];
            #pragma unroll
            for (int j2 = 0; j2 < 4; ++j2) {
                U8 uv;
                uv.q[0] = VsTg[mga][j2 * 16 + fr];
                uv.q[1] = VsTg[mga + 1][j2 * 16 + fr];
                acc_o[j2] = __builtin_amdgcn_mfma_f32_16x16x32_bf16(ua.v, uv.v, acc_o[j2], 0, 0, 0);
                acc_o[j2] = __builtin_amdgcn_mfma_f32_16x16x32_bf16(ul.v, uv.v, acc_o[j2], 0, 0, 0);
            }
        }
    }

    #pragma unroll
    for (int j2 = 0; j2 < 4; ++j2) {
        int c = h * 64 + j2 * 16 + fr;
        #pragma unroll
        for (int reg = 0; reg < 4; ++reg) {
            int n = n0 + wn + fg * 4 + reg;
            O[((size_t)(tb * 512 + n) << 9) + c] = acc_o[j2][reg];
        }
    }
}

// ---------------------------------------------------------------------------
// Retention LIF: reads O (t,b,n,c); writes bf16 spikes (permuted) + flag.
__global__ void lif_ret_bf2(const float* __restrict__ Y, __bf16* __restrict__ Rb,
                            int* __restrict__ ctr, int* __restrict__ list) {
    int g = blockIdx.x * TPB + threadIdx.x;
    int c = g & 511, n = (g >> 9) & 511, b = g >> 18;
    size_t pbase = ((size_t)(b * 512 + n) * 4) * 512 + c;
    double v = 0.0, eb = 0.0;
    bool flag = false;
    for (int t = 0; t < 4; ++t) {
        size_t idx = ((size_t)((t * 8 + b) * 512 + n) << 9) + c;
        double x = (double)Y[idx];
        double hh = v + (x - v) * 0.5;
        eb = 0.5 * eb + 0.5 * (fabs(x) * 1e-4);
        flag |= fabs(hh - 0.5) <= eb + 1e-9;
        bool s = hh >= 0.5;
        Rb[pbase + (size_t)t * 512] = s ? (__bf16)1.0f : (__bf16)0.0f;
        v = s ? 0.0 : hh;
        if (s) eb = 0.0;
    }
    if (flag) {
        int i2 = atomicAdd(ctr + 4, 1);
        if (i2 < FCAP) list[i2] = g;
    }
}

// Exact fp64 repair of flagged retention neurons; writes permuted Rb.
__global__ void repair_ret_bf2(const u64* __restrict__ qm, const u64* __restrict__ km,
                               const u64* __restrict__ vm, const double* __restrict__ pw,
                               const int* __restrict__ ctr, const int* __restrict__ list,
                               __bf16* __restrict__ Rb) {
    int cnt = ctr[4]; if (cnt > FCAP) cnt = FCAP;
    int wv = (blockIdx.x * blockDim.x + threadIdx.x) >> 6;
    int nw = (gridDim.x * blockDim.x) >> 6;
    int lane = threadIdx.x & 63;
    for (int i = wv; i < cnt; i += nw) {
        int g = list[i];
        int c = g & 511, n = (g >> 9) & 511, b = g >> 18;
        int h = c >> 6, d = c & 63;
        double acc_t[4];
        for (int t = 0; t < 4; ++t) {
            int base = ((t * 8 + b) * 8 + h) * 512;
            u64 qw = qm[base + n];
            double p = 0.0;
            for (int j = 0; j < 8; ++j) {
                int m = j * 64 + lane;
                u64 kk = km[base + m];
                u64 vvm = vm[base + m];
                if ((vvm >> d) & 1ull) {
                    int dist = n - m; if (dist < 0) dist = -dist;
                    p += (double)__popcll(qw & kk) * pw[h * 512 + dist];
                }
            }
            acc_t[t] = p;
        }
        #pragma unroll
        for (int off = 32; off; off >>= 1) {
            #pragma unroll
            for (int t = 0; t < 4; ++t) acc_t[t] += __shfl_xor(acc_t[t], off, 64);
        }
        if (lane == 0) {
            double v = 0.0;
            size_t pbase = ((size_t)(b * 512 + n) * 4) * 512 + c;
            for (int t = 0; t < 4; ++t) {
                double x = acc_t[t] * 0.125;
                double hh = v + (x - v) * 0.5;
                bool s = hh >= 0.5;
                Rb[pbase + (size_t)t * 512] = s ? (__bf16)1.0f : (__bf16)0.0f;
                v = s ? 0.0 : hh;
            }
        }
    }
}

// ---------------------------------------------------------------------------
// Exact fp64 repair of flagged FINAL neurons; reads permuted Rb; writes d_out.
__global__ void fix_final_direct(const __bf16* __restrict__ rr, const float* __restrict__ w,
                                 const float* __restrict__ bias,
                                 const float* __restrict__ bnw, const float* __restrict__ bnb,
                                 const float* __restrict__ bnm, const float* __restrict__ bnv,
                                 const int* __restrict__ ctr, const int* __restrict__ list,
                                 float* __restrict__ out) {
    int cnt = ctr[3]; if (cnt > FCAP) cnt = FCAP;
    int wv = (blockIdx.x * blockDim.x + threadIdx.x) >> 6;
    int nw = (gridDim.x * blockDim.x) >> 6;
    int lane = threadIdx.x & 63;
    for (int i = wv; i < cnt; i += nw) {
        int g = list[i];
        int c = g & 511, n = (g >> 9) & 511, b = g >> 18;
        const float* wr = w + (size_t)c * 512;
        double dot[4];
        #pragma unroll
        for (int t = 0; t < 4; ++t) {
            const __bf16* xr = rr + ((size_t)(b * 512 + n) * 4 + t) * 512;
            double p = 0.0;
            #pragma unroll
            for (int j = 0; j < 8; ++j)
                p += (double)(float)xr[lane + 64 * j] * (double)wr[lane + 64 * j];
            dot[t] = p;
        }
        #pragma unroll
        for (int off = 32; off; off >>= 1) {
            #pragma unroll
            for (int t = 0; t < 4; ++t)
                dot[t] += __shfl_xor(dot[t], off, 64);
        }
        if (lane == 0) {
            double inv = (double)bnw[c] / sqrt((double)bnv[c] + 1e-5);
            double sh  = (double)bnb[c] - (double)bnm[c] * inv;
            double bs  = (double)bias[c];
            double v = 0.0;
            for (int t = 0; t < 4; ++t) {
                double y = (dot[t] + bs) * inv + sh;
                double hh = v + (y - v) * 0.5;
                bool s = hh >= 1.0;
                out[((size_t)((t * 8 + b) * 512 + n) << 9) + c] = s ? 1.0f : 0.0f;
                v = s ? 0.0 : hh;
            }
        }
    }
}

// ===========================================================================
// Fallback path kernels (R15-proven, used when ws is too small)
// ===========================================================================
__global__ __launch_bounds__(256) void gemm_bn_mfma(
    const float* __restrict__ A, const float* __restrict__ W,
    const float* __restrict__ bias,
    const float* __restrict__ bnw, const float* __restrict__ bnb,
    const float* __restrict__ bnm, const float* __restrict__ bnv,
    float* __restrict__ out)
{
    __shared__ __bf16 Ah[128][36];
    __shared__ __bf16 Al[128][36];
    __shared__ __bf16 Wh[64][36];
    __shared__ __bf16 Wl[64][36];

    const int tid = threadIdx.x;
    const int m0 = blockIdx.x * 128;
    const int d0 = blockIdx.y * 64;
    const int wv = tid >> 6;
    const int wm = wv >> 1;
    const int wd = wv & 1;
    const int lane = tid & 63;
    const int fr = lane & 15;
    const int fg = lane >> 4;
    const int srow = tid >> 3;
    const int scol = (tid & 7) * 4;

    f32x4 acc[4][2];
    #pragma unroll
    for (int i = 0; i < 4; ++i)
        #pragma unroll
        for (int j = 0; j < 2; ++j)
            acc[i][j] = (f32x4){0.f, 0.f, 0.f, 0.f};

    for (int k0 = 0; k0 < 512; k0 += 32) {
        __syncthreads();
        #pragma unroll
        for (int rep = 0; rep < 4; ++rep) {
            int row = srow + 32 * rep;
            float4 va = *(const float4*)(A + (size_t)(m0 + row) * 512 + k0 + scol);
            #pragma unroll
            for (int e = 0; e < 4; ++e) {
                float f = (&va.x)[e];
                __bf16 h = (__bf16)f;
                Ah[row][scol + e] = h;
                Al[row][scol + e] = (__bf16)(f - (float)h);
            }
        }
        #pragma unroll
        for (int rep = 0; rep < 2; ++rep) {
            int row = srow + 32 * rep;
            float4 vw = *(const float4*)(W + (size_t)(d0 + row) * 512 + k0 + scol);
            #pragma unroll
            for (int e = 0; e < 4; ++e) {
                float f = (&vw.x)[e];
                __bf16 h = (__bf16)f;
                Wh[row][scol + e] = h;
                Wl[row][scol + e] = (__bf16)(f - (float)h);
            }
        }
        __syncthreads();

        union FU { bf16x8 v8; struct { __bf16 a[4], b[4]; } s; };
        bf16x8 ah[4], al[4], bh[2], bl[2];
        #pragma unroll
        for (int i = 0; i < 4; ++i) {
            int row = wm * 64 + i * 16 + fr;
            FU u1, u2;
            *(double*)&u1.s.a[0] = *(const double*)&Ah[row][fg * 8];
            *(double*)&u1.s.b[0] = *(const double*)&Ah[row][fg * 8 + 4];
            *(double*)&u2.s.a[0] = *(const double*)&Al[row][fg * 8];
            *(double*)&u2.s.b[0] = *(const double*)&Al[row][fg * 8 + 4];
            ah[i] = u1.v8; al[i] = u2.v8;
        }
        #pragma unroll
        for (int j = 0; j < 2; ++j) {
            int row = wd * 32 + j * 16 + fr;
            FU u1, u2;
            *(double*)&u1.s.a[0] = *(const double*)&Wh[row][fg * 8];
            *(double*)&u1.s.b[0] = *(const double*)&Wh[row][fg * 8 + 4];
            *(double*)&u2.s.a[0] = *(const double*)&Wl[row][fg * 8];
            *(double*)&u2.s.b[0] = *(const double*)&Wl[row][fg * 8 + 4];
            bh[j] = u1.v8; bl[j] = u2.v8;
        }
        #pragma unroll
        for (int i = 0; i < 4; ++i)
            #pragma unroll
            for (int j = 0; j < 2; ++j) {
                acc[i][j] = __builtin_amdgcn_mfma_f32_16x16x32_bf16(ah[i], bh[j], acc[i][j], 0, 0, 0);
                acc[i][j] = __builtin_amdgcn_mfma_f32_16x16x32_bf16(ah[i], bl[j], acc[i][j], 0, 0, 0);
                acc[i][j] = __builtin_amdgcn_mfma_f32_16x16x32_bf16(al[i], bh[j], acc[i][j], 0, 0, 0);
            }
    }

    #pragma unroll
    for (int j = 0; j < 2; ++j) {
        int d = d0 + wd * 32 + j * 16 + fr;
        double inv = (double)bnw[d] / sqrt((double)bnv[d] + 1e-5);
        double sh  = (double)bnb[d] - (double)bnm[d] * inv;
        double bs  = (double)bias[d];
        #pragma unroll
        for (int i = 0; i < 4; ++i) {
            #pragma unroll
            for (int reg = 0; reg < 4; ++reg) {
                int m = m0 + wm * 64 + i * 16 + fg * 4 + reg;
                out[(size_t)m * 512 + d] = (float)(((double)acc[i][j][reg] + bs) * inv + sh);
            }
        }
    }
}

__global__ void lif_mask_flag(const float* __restrict__ Y, u64* __restrict__ msk,
                              int* __restrict__ ctr, int* __restrict__ list, int slot) {
    int g = blockIdx.x * TPB + threadIdx.x;
    int c = g & 511, n = (g >> 9) & 511, b = g >> 18;
    int h = c >> 6;
    int lane = threadIdx.x & 63;
    double v = 0.0;
    bool flag = false;
    for (int t = 0; t < 4; ++t) {
        float y = Y[((size_t)((t * 8 + b) * 512 + n) << 9) + c];
        double hh = v + ((double)y - v) * 0.5;
        flag |= fabs(hh - 1.0) < MARGIN;
        bool s = hh >= 1.0;
        u64 mk = __ballot(s);
        if (lane == 0) msk[((t * 8 + b) * 8 + h) * 512 + n] = mk;
        v = s ? 0.0 : hh;
    }
    if (flag) {
        int idx = atomicAdd(ctr + slot, 1);
        if (idx < FCAP) list[idx] = g;
    }
}

__global__ void lif_ret_f(const float* __restrict__ Y, float* __restrict__ R,
                          int* __restrict__ ctr, int* __restrict__ list) {
    int g = blockIdx.x * TPB + threadIdx.x;
    int c = g & 511, n = (g >> 9) & 511, b = g >> 18;
    double v = 0.0, eb = 0.0;
    bool flag = false;
    for (int t = 0; t < 4; ++t) {
        size_t idx = ((size_t)((t * 8 + b) * 512 + n) << 9) + c;
        double x = (double)Y[idx];
        double hh = v + (x - v) * 0.5;
        eb = 0.5 * eb + 0.5 * (fabs(x) * 1e-4);
        flag |= fabs(hh - 0.5) <= eb + 1e-9;
        bool s = hh >= 0.5;
        R[idx] = s ? 1.0f : 0.0f;
        v = s ? 0.0 : hh;
        if (s) eb = 0.0;
    }
    if (flag) {
        int i2 = atomicAdd(ctr + 4, 1);
        if (i2 < FCAP) list[i2] = g;
    }
}

__global__ void repair_ret_f(const u64* __restrict__ qm, const u64* __restrict__ km,
                             const u64* __restrict__ vm, const double* __restrict__ pw,
                             const int* __restrict__ ctr, const int* __restrict__ list,
                             float* __restrict__ r) {
    int cnt = ctr[4]; if (cnt > FCAP) cnt = FCAP;
    int wv = (blockIdx.x * blockDim.x + threadIdx.x) >> 6;
    int nw = (gridDim.x * blockDim.x) >> 6;
    int lane = threadIdx.x & 63;
    for (int i = wv; i < cnt; i += nw) {
        int g = list[i];
        int c = g & 511, n = (g >> 9) & 511, b = g >> 18;
        int h = c >> 6, d = c & 63;
        double acc_t[4];
        for (int t = 0; t < 4; ++t) {
            int base = ((t * 8 + b) * 8 + h) * 512;
            u64 qw = qm[base + n];
            double p = 0.0;
            for (int j = 0; j < 8; ++j) {
                int m = j * 64 + lane;
                u64 kk = km[base + m];
                u64 vvm = vm[base + m];
                if ((vvm >> d) & 1ull) {
                    int dist = n - m; if (dist < 0) dist = -dist;
                    p += (double)__popcll(qw & kk) * pw[h * 512 + dist];
                }
            }
            acc_t[t] = p;
        }
        #pragma unroll
        for (int off = 32; off; off >>= 1) {
            #pragma unroll
            for (int t = 0; t < 4; ++t) acc_t[t] += __shfl_xor(acc_t[t], off, 64);
        }
        if (lane == 0) {
            double v = 0.0;
            for (int t = 0; t < 4; ++t) {
                double x = acc_t[t] * 0.125;
                double hh = v + (x - v) * 0.5;
                bool s = hh >= 0.5;
                r[((size_t)((t * 8 + b) * 512 + n) << 9) + c] = s ? 1.0f : 0.0f;
                v = s ? 0.0 : hh;
            }
        }
    }
}

__global__ void final_flag(const float* __restrict__ Y, int* __restrict__ ctr,
                           int* __restrict__ list) {
    int g = blockIdx.x * TPB + threadIdx.x;
    int c = g & 511, n = (g >> 9) & 511, b = g >> 18;
    double v = 0.0;
    bool flag = false;
    for (int t = 0; t < 4; ++t) {
        float y = Y[((size_t)((t * 8 + b) * 512 + n) << 9) + c];
        double hh = v + ((double)y - v) * 0.5;
        flag |= fabs(hh - 1.0) < MARGIN;
        bool s = hh >= 1.0;
        v = s ? 0.0 : hh;
    }
    if (flag) {
        int idx = atomicAdd(ctr + 3, 1);
        if (idx < FCAP) list[idx] = g;
    }
}

__global__ void fix_final_f(const float* __restrict__ rr, const float* __restrict__ w,
                            const float* __restrict__ bias,
                            const float* __restrict__ bnw, const float* __restrict__ bnb,
                            const float* __restrict__ bnm, const float* __restrict__ bnv,
                            const int* __restrict__ ctr, int* __restrict__ list) {
    int cnt = ctr[3]; if (cnt > FCAP) cnt = FCAP;
    int wv = (blockIdx.x * blockDim.x + threadIdx.x) >> 6;
    int nw = (gridDim.x * blockDim.x) >> 6;
    int lane = threadIdx.x & 63;
    for (int i = wv; i < cnt; i += nw) {
        int g = list[i] & 0x00FFFFFF;
        int c = g & 511, n = (g >> 9) & 511, b = g >> 18;
        const float* wr = w + (size_t)c * 512;
        double dot[4];
        #pragma unroll
        for (int t = 0; t < 4; ++t) {
            const float* xr = rr + ((size_t)((t * 8 + b) * 512 + n) << 9);
            double p = 0.0;
            #pragma unroll
            for (int j = 0; j < 8; ++j)
                p += (double)xr[lane + 64 * j] * (double)wr[lane + 64 * j];
            dot[t] = p;
        }
        #pragma unroll
        for (int off = 32; off; off >>= 1) {
            #pragma unroll
            for (int t = 0; t < 4; ++t)
                dot[t] += __shfl_xor(dot[t], off, 64);
        }
        if (lane == 0) {
            double inv = (double)bnw[c] / sqrt((double)bnv[c] + 1e-5);
            double sh  = (double)bnb[c] - (double)bnm[c] * inv;
            double bs  = (double)bias[c];
            double v = 0.0;
            int sp = 0;
            for (int t = 0; t < 4; ++t) {
                double y = (dot[t] + bs) * inv + sh;
                double hh = v + (y - v) * 0.5;
                bool s = hh >= 1.0;
                sp |= (s ? 1 : 0) << t;
                v = s ? 0.0 : hh;
            }
            list[i] = g | (sp << 24);
        }
    }
}

__global__ void final_write(const float* __restrict__ Y, float* __restrict__ out) {
    int g = blockIdx.x * TPB + threadIdx.x;
    int c = g & 511, n = (g >> 9) & 511, b = g >> 18;
    double v = 0.0;
    for (int t = 0; t < 4; ++t) {
        size_t idx = ((size_t)((t * 8 + b) * 512 + n) << 9) + c;
        float y = Y[idx];
        double hh = v + ((double)y - v) * 0.5;
        bool s = hh >= 1.0;
        out[idx] = s ? 1.0f : 0.0f;
        v = s ? 0.0 : hh;
    }
}

__global__ void fix_scatter(const int* __restrict__ ctr, const int* __restrict__ list,
                            float* __restrict__ out) {
    int cnt = ctr[3]; if (cnt > FCAP) cnt = FCAP;
    int i = blockIdx.x * blockDim.x + threadIdx.x;
    if (i >= cnt) return;
    int e = list[i];
    int g = e & 0x00FFFFFF, sp = (e >> 24) & 0xF;
    int c = g & 511, n = (g >> 9) & 511, b = g >> 18;
    for (int t = 0; t < 4; ++t)
        out[((size_t)((t * 8 + b) * 512 + n) << 9) + c] = ((sp >> t) & 1) ? 1.0f : 0.0f;
}

// ---------------------------------------------------------------------------
extern "C" void kernel_launch(void* const* d_in, const int* in_sizes, int n_in,
                              void* d_out, int out_size, void* d_ws, size_t ws_size,
                              hipStream_t stream) {
    const float* x = (const float*)d_in[0];
    const float *w[4], *bi[4], *bnw[4], *bnb[4], *bnm[4], *bnv[4];
    for (int br = 0; br < 4; ++br) {
        int base = 1 + br * 6;
        w[br]   = (const float*)d_in[base + 0];
        bi[br]  = (const float*)d_in[base + 1];
        bnw[br] = (const float*)d_in[base + 2];
        bnb[br] = (const float*)d_in[base + 3];
        bnm[br] = (const float*)d_in[base + 4];
        bnv[br] = (const float*)d_in[base + 5];
    }

    const size_t NX = (size_t)16384 * 512;
    char* p = (char*)d_ws;
    double* pw = (double*)p;  p += 8 * 512 * sizeof(double);
    u64* qm = (u64*)p;        p += 131072 * sizeof(u64);
    u64* km = (u64*)p;        p += 131072 * sizeof(u64);
    u64* vm = (u64*)p;        p += 131072 * sizeof(u64);
    int* ctr = (int*)p;       p += 1024;
    int* list = (int*)p;      p += (size_t)FCAP * sizeof(int);
    float* Y = (float*)p;     p += NX * 4;
    __bf16* Xh = (__bf16*)p;  p += NX * 2;
    __bf16* Xl = (__bf16*)p;  p += NX * 2;
    __bf16* Wsp = (__bf16*)p; p += (size_t)4 * 2 * 262144 * 2;
    size_t need_fast = (size_t)(p - (char*)d_ws);
    int fast = ws_size >= need_fast;

    init_kernel<<<1, 64, 0, stream>>>(pw, ctr);

    dim3 g2(128, 4);
    dim3 gg(128, 8);

    if (fast) {
        split_all<<<8192 + 1024, 256, 0, stream>>>(x, w[0], w[1], w[2], w[3], Xh, Xl, Wsp);
        for (int br = 0; br < 3; ++br) {
            u64* msk = br == 0 ? qm : (br == 1 ? km : vm);
            gemm_lif_mask<<<g2, 256, 0, stream>>>(Xh, Xl,
                Wsp + (size_t)br * 524288, Wsp + (size_t)br * 524288 + 262144,
                bi[br], bnw[br], bnb[br], bnm[br], bnv[br], msk, ctr, list, br);
            fix_mask<<<128, 256, 0, stream>>>(x, w[br], bi[br], bnw[br], bnb[br],
                                              bnm[br], bnv[br], msk, ctr, list, br);
        }
        // retention -> Y; LIF -> bf16 spikes (permuted) in Xh; exact repair
        ret_fused2<<<2048, 256, 0, stream>>>(qm, km, vm, pw, Y);
        lif_ret_bf2<<<8192, TPB, 0, stream>>>(Y, Xh, ctr, list);
        repair_ret_bf2<<<256, 256, 0, stream>>>(qm, km, vm, pw, ctr, list, Xh);
        // p projection + fused final LIF -> d_out; exact repair direct
        gemm_final_lif<<<g2, 256, 0, stream>>>(Xh,
            Wsp + (size_t)3 * 524288, Wsp + (size_t)3 * 524288 + 262144,
            bi[3], bnw[3], bnb[3], bnm[3], bnv[3], (float*)d_out, ctr, list);
        fix_final_direct<<<128, 256, 0, stream>>>(Xh, w[3], bi[3], bnw[3], bnb[3],
                                                  bnm[3], bnv[3], ctr, list, (float*)d_out);
    } else {
        for (int br = 0; br < 3; ++br) {
            u64* msk = br == 0 ? qm : (br == 1 ? km : vm);
            gemm_bn_mfma<<<gg, 256, 0, stream>>>(x, w[br], bi[br], bnw[br], bnb[br],
                                                 bnm[br], bnv[br], Y);
            lif_mask_flag<<<8192, TPB, 0, stream>>>(Y, msk, ctr, list, br);
            fix_mask<<<128, 256, 0, stream>>>(x, w[br], bi[br], bnw[br], bnb[br],
                                              bnm[br], bnv[br], msk, ctr, list, br);
        }
        float* r = (float*)d_out;
        ret_fused2<<<2048, 256, 0, stream>>>(qm, km, vm, pw, Y);
        lif_ret_f<<<8192, TPB, 0, stream>>>(Y, r, ctr, list);
        repair_ret_f<<<256, 256, 0, stream>>>(qm, km, vm, pw, ctr, list, r);
        gemm_bn_mfma<<<gg, 256, 0, stream>>>(r, w[3], bi[3], bnw[3], bnb[3],
                                             bnm[3], bnv[3], Y);
        final_flag<<<8192, TPB, 0, stream>>>(Y, ctr, list);
        fix_final_f<<<128, 256, 0, stream>>>(r, w[3], bi[3], bnw[3], bnb[3],
                                             bnm[3], bnv[3], ctr, list);
        final_write<<<8192, TPB, 0, stream>>>(Y, (float*)d_out);
        fix_scatter<<<4096, 256, 0, stream>>>(ctr, list, (float*)d_out);
    }
}